// Round 5
// baseline (606.414 us; speedup 1.0000x reference)
//
#include <hip/hip_runtime.h>
#include <math.h>

// DeepSeek V2 MLA attention — bf16 MFMA GEMMs + split-K flash attention with
// a dynamic work queue (v5). v5: attention V operands are read directly from
// global (vallT is L2-resident and already in MFMA B-fragment layout) into a
// register ping-pong instead of LDS staging; LDS drops 73.5->41 KiB so 3
// blocks/CU fit (was 2); next-tile K chunks are prefetched across the tile
// barrier; s_setprio(1) wraps MFMA clusters.
// B=1 S=2048 E=2048 H=16 DN=128 DR=64 DV=128 R=512 QLR=1536

typedef unsigned short u16;
typedef unsigned int u32;
typedef __bf16 bf16x8 __attribute__((ext_vector_type(8)));
typedef float f32x4 __attribute__((ext_vector_type(4)));
typedef unsigned short u16x8 __attribute__((ext_vector_type(8)));

__device__ __forceinline__ u16 f2b(float f) {  // fp32 -> bf16 RNE
  u32 u = __float_as_uint(f);
  u += 0x7FFFu + ((u >> 16) & 1u);
  return (u16)(u >> 16);
}
__device__ __forceinline__ float b2f(u16 v) {
  return __uint_as_float(((u32)v) << 16);
}

#define GLDS(g, l) __builtin_amdgcn_global_load_lds( \
    (const __attribute__((address_space(1))) u32*)(g), \
    (__attribute__((address_space(3))) u32*)(l), 16, 0, 0)

#define MFMA(a, b, c) __builtin_amdgcn_mfma_f32_16x16x32_bf16(a, b, c, 0, 0, 0)

// s_waitcnt vmcnt(N) (lgkmcnt/expcnt untouched) + s_barrier.
template<int N>
__device__ __forceinline__ void vm_barrier() {
  __builtin_amdgcn_s_waitcnt(0xF70 | N);  // expcnt=7, lgkmcnt=15, vmcnt=N
  __builtin_amdgcn_s_barrier();
}

// items enumerated qt-descending (heavy first): for qt=31..0, kc=0..nkc-1,
// h=0..15.  nkc(qt) = ceil((qt/2+1)/4).  Total = 1280.
#define N_ITEMS 1280
__device__ __forceinline__ int nkc_of(int qt) { return (((qt >> 1) + 1) + 3) >> 2; }

// ---------------- block reduction helper ----------------
__device__ __forceinline__ float block_sum(float v, float* red) {
#pragma unroll
  for (int off = 32; off > 0; off >>= 1) v += __shfl_down(v, off);
  const int lane = threadIdx.x & 63, w = threadIdx.x >> 6;
  if (lane == 0) red[w] = v;
  __syncthreads();
  float r = red[0] + red[1] + red[2] + red[3];
  __syncthreads();
  return r;
}

// ---------------- bf16 MFMA GEMM, 128x128 tile, BK=32, pipelined ------------
// C = A[M,K] @ B[N,K]^T (both row-major bf16). Batched over blockIdx.z.
// OUTK: 0 = fp32 out, 1 = bf16 out, 2 = bf16 transposed out (C[n*ldc+m]).
template<int OUTK>
__global__ __launch_bounds__(256) void gemm_mfma(
    const u16* __restrict__ A, const u16* __restrict__ B, void* __restrict__ Cv,
    int K, int lda, int ldb, int ldc, long sA, long sB, long sC)
{
  __shared__ u16 At[3][4096];  // triple-buffered 128x32 tiles
  __shared__ u16 Bt[3][4096];
  const u16* Ab = A + (long)blockIdx.z * sA;
  const u16* Bb = B + (long)blockIdx.z * sB;
  const int tid = threadIdx.x;
  const int w = tid >> 6, lane = tid & 63;
  const int m0 = blockIdx.y * 128, n0 = blockIdx.x * 128;
  const int wm = (w >> 1) * 64, wn = (w & 1) * 64;
  const int fr = lane & 15, fq = lane >> 4;

  const int c0 = w * 2, c1 = w * 2 + 1;
  const int e0 = (c0 * 64 + lane) * 8, e1 = (c1 * 64 + lane) * 8;
  const int r0 = e0 >> 5, col0 = e0 & 31;
  const int r1 = e1 >> 5, col1 = e1 & 31;

  const int nk = K >> 5;
  auto issue = [&](int kc) {
    const int k0 = kc * 32;
    u16* at = At[kc % 3];
    u16* bt = Bt[kc % 3];
    GLDS(Ab + (long)(m0 + r0) * lda + k0 + col0, at + c0 * 512);
    GLDS(Bb + (long)(n0 + r0) * ldb + k0 + col0, bt + c0 * 512);
    GLDS(Ab + (long)(m0 + r1) * lda + k0 + col1, at + c1 * 512);
    GLDS(Bb + (long)(n0 + r1) * ldb + k0 + col1, bt + c1 * 512);
  };

  f32x4 acc[4][4] = {};
  issue(0);
  issue(1);
  vm_barrier<4>();
  for (int kc = 0; kc < nk; ++kc) {
    if (kc + 2 < nk) issue(kc + 2);
    const u16* at = At[kc % 3];
    const u16* bt = Bt[kc % 3];
    bf16x8 af[4], bfr[4];
#pragma unroll
    for (int i = 0; i < 4; ++i)
      af[i] = *(const bf16x8*)(at + (wm + i * 16 + fr) * 32 + fq * 8);
#pragma unroll
    for (int j = 0; j < 4; ++j)
      bfr[j] = *(const bf16x8*)(bt + (wn + j * 16 + fr) * 32 + fq * 8);
#pragma unroll
    for (int i = 0; i < 4; ++i)
#pragma unroll
      for (int j = 0; j < 4; ++j)
        acc[i][j] = MFMA(af[i], bfr[j], acc[i][j]);
    if (kc + 1 < nk) {
      if (kc + 2 < nk) vm_barrier<4>();
      else vm_barrier<0>();
    }
  }

  if (OUTK == 0) {
    float* C = (float*)Cv + (long)blockIdx.z * sC;
#pragma unroll
    for (int i = 0; i < 4; ++i)
#pragma unroll
      for (int j = 0; j < 4; ++j) {
        long base = (long)(m0 + wm + i * 16 + fq * 4) * ldc + (n0 + wn + j * 16 + fr);
#pragma unroll
        for (int r = 0; r < 4; ++r) C[base + (long)r * ldc] = acc[i][j][r];
      }
  } else if (OUTK == 1) {
    u16* C = (u16*)Cv + (long)blockIdx.z * sC;
#pragma unroll
    for (int i = 0; i < 4; ++i)
#pragma unroll
      for (int j = 0; j < 4; ++j) {
        long base = (long)(m0 + wm + i * 16 + fq * 4) * ldc + (n0 + wn + j * 16 + fr);
#pragma unroll
        for (int r = 0; r < 4; ++r) C[base + (long)r * ldc] = f2b(acc[i][j][r]);
      }
  } else {
    u16* C = (u16*)Cv + (long)blockIdx.z * sC;
#pragma unroll
    for (int i = 0; i < 4; ++i)
#pragma unroll
      for (int j = 0; j < 4; ++j) {
        ushort4 v = { f2b(acc[i][j][0]), f2b(acc[i][j][1]),
                      f2b(acc[i][j][2]), f2b(acc[i][j][3]) };
        *(ushort4*)(C + (long)(n0 + wn + j * 16 + fr) * ldc + (m0 + wm + i * 16 + fq * 4)) = v;
      }
  }
}

// ---------------- counter init ----------------
__global__ void init_ctr(u32* ctr) { *ctr = 0; }

// ---------------- split-K flash attention, dynamic queue ----------------
// 768 persistent blocks (3/CU) pop items (h, qt, kc). Item = q-rows
// [qt*64,+64) of head h vs K-tiles [4kc, min(4kc+4, ktt)). Writes raw-O
// partial (bf16) + per-row (m, l) stats; reduce kernel combines.
// LDS = Ks 24 KiB + Ps 17 KiB = 41 KiB -> 3 blocks/CU. V operands are
// register-loaded directly from vallT (L2-resident, fragment-layout).
__global__ __launch_bounds__(256, 3) void attn_partial(
    const u16* __restrict__ qfb,   // [2048][16*576]
    const u16* __restrict__ kfb,   // [2048][576]
    const u16* __restrict__ vallT, // [16][128][2048]
    u32* __restrict__ ctr,
    u16* __restrict__ pO,          // [N_ITEMS][64][128]
    float* __restrict__ pS)        // [N_ITEMS][64][2]
{
  __shared__ u16 Ks[3][4096];    // K chunks, [row 128][g'=g^(row&3)][8]
  __shared__ u16 Ps[4 * 2176];   // per-wave P, 16 rows x 136 stride
  __shared__ u32 cur;

  const int tid = threadIdx.x;
  const int w = tid >> 6, lane = tid & 63;
  const int fr = lane & 15, fq = lane >> 4;
  const float scale = 0.07216878364870323f;  // (DN+DR)^-0.5
  u16* Psw = Ps + w * 2176;

  const int krow0 = (w * 2) * 16 + (lane >> 2);
  const int krow1 = (w * 2 + 1) * 16 + (lane >> 2);
  const int kg0 = (lane & 3) ^ (krow0 & 3);
  const int kg1 = (lane & 3) ^ (krow1 & 3);

  while (true) {
    if (tid == 0) cur = atomicAdd(ctr, 1u);
    __syncthreads();
    const u32 it = cur;
    if (it >= N_ITEMS) break;

    // decode (qt descending, kc asc, h asc)
    int rem = (int)it, qt = 31, kc = 0, h = 0;
    for (int q = 31; q >= 0; --q) {
      int cnt = nkc_of(q) * 16;
      if (rem < cnt) { qt = q; kc = rem >> 4; h = rem & 15; break; }
      rem -= cnt;
    }
    const int q0 = qt * 64;
    const int ktt = (qt >> 1) + 1;
    const int kt0 = kc * 4, kt1 = min(kt0 + 4, ktt);

    // Q fragments resident (A[m=fr][k=fq*8+j])
    bf16x8 aq[18];
    {
      const u16* qp = qfb + (long)(q0 + w * 16 + fr) * 9216 + h * 576 + fq * 8;
#pragma unroll
      for (int d = 0; d < 18; ++d) aq[d] = *(const bf16x8*)(qp + d * 32);
    }

    float m_run[4], l_run[4];
#pragma unroll
    for (int r = 0; r < 4; ++r) { m_run[r] = -1e30f; l_run[r] = 0.f; }
    f32x4 Oacc[8] = {};
    // per-lane V fragment base: frag(jv,ks) = vlane + k0 + jv*32768 + ks*32
    const u16* vlane = vallT + (long)h * 262144 + (long)fr * 2048 + fq * 8;

    auto issueK = [&](int kt, int c) {
      const int k0i = kt * 128, d0 = c * 32;
      u16* dst = Ks[c % 3];
      GLDS(kfb + (long)(k0i + krow0) * 576 + d0 + kg0 * 8, dst + (w * 2) * 512);
      GLDS(kfb + (long)(k0i + krow1) * 576 + d0 + kg1 * 8, dst + (w * 2 + 1) * 512);
    };

    issueK(kt0, 0);
    issueK(kt0, 1);

    for (int kt = kt0; kt < kt1; ++kt) {
      const int k0 = kt * 128;
      vm_barrier<2>();  // chunk0 landed block-wide (chunk1 in flight)

      f32x4 sc[8] = {};
#pragma unroll
      for (int d = 0; d < 18; ++d) {
        if (d + 2 < 18) issueK(kt, d + 2);
        const u16* kb = Ks[d % 3];
        __builtin_amdgcn_s_setprio(1);
#pragma unroll
        for (int j = 0; j < 8; ++j) {
          const int row = j * 16 + fr;
          bf16x8 b = *(const bf16x8*)(kb + row * 32 + ((fq ^ (row & 3)) * 8));
          sc[j] = MFMA(aq[d], b, sc[j]);
        }
        __builtin_amdgcn_s_setprio(0);
        if (d < 17) {
          if (d + 2 < 18) vm_barrier<2>();
          else vm_barrier<0>();
        }
      }
      // all waves done reading Ks for this tile; Ks bufs may be rewritten
      __builtin_amdgcn_s_barrier();

      // V ks-group 0 into registers (latency hidden under softmax), then
      // prefetch next tile's first two K chunks across the softmax+PV phase.
      const u16* vk = vlane + k0;
      bf16x8 vA[4], vB[4];
#pragma unroll
      for (int q = 0; q < 4; ++q) {
        vA[q] = *(const bf16x8*)(vk + (long)q * 32768);
        vB[q] = *(const bf16x8*)(vk + (long)(q + 4) * 32768);
      }
      if (kt + 1 < kt1) { issueK(kt + 1, 0); issueK(kt + 1, 1); }

      // wave-local online softmax
      const bool diag = (kt == ktt - 1);
#pragma unroll
      for (int r = 0; r < 4; ++r) {
        float mx = m_run[r];
#pragma unroll
        for (int j = 0; j < 8; ++j) {
          float s = sc[j][r] * scale;
          if (diag) {
            const int row = q0 + w * 16 + fq * 4 + r;
            const int col = k0 + j * 16 + fr;
            if (col > row) s = -1e30f;
          }
          sc[j][r] = s;
          mx = fmaxf(mx, s);
        }
        mx = fmaxf(mx, __shfl_xor(mx, 1));
        mx = fmaxf(mx, __shfl_xor(mx, 2));
        mx = fmaxf(mx, __shfl_xor(mx, 4));
        mx = fmaxf(mx, __shfl_xor(mx, 8));
        const float alpha = __expf(m_run[r] - mx);
        m_run[r] = mx;
        float sum = 0.f;
#pragma unroll
        for (int j = 0; j < 8; ++j) {
          float p = __expf(sc[j][r] - mx);
          sc[j][r] = p;
          sum += p;
        }
        sum += __shfl_xor(sum, 1);
        sum += __shfl_xor(sum, 2);
        sum += __shfl_xor(sum, 4);
        sum += __shfl_xor(sum, 8);
        l_run[r] = l_run[r] * alpha + sum;
#pragma unroll
        for (int jv = 0; jv < 8; ++jv) Oacc[jv][r] *= alpha;
#pragma unroll
        for (int j = 0; j < 8; ++j)
          Psw[(fq * 4 + r) * 136 + j * 16 + fr] = f2b(sc[j][r]);
      }

      // PV: O += P @ V^T, V fragments ping-ponged from global (no barrier)
#pragma unroll
      for (int ks = 0; ks < 4; ++ks) {
        bf16x8 ap = *(const bf16x8*)(Psw + fr * 136 + ks * 32 + fq * 8);
        __builtin_amdgcn_s_setprio(1);
#pragma unroll
        for (int q = 0; q < 4; ++q) Oacc[q] = MFMA(ap, vA[q], Oacc[q]);
        __builtin_amdgcn_s_setprio(0);
        if (ks < 3) {
#pragma unroll
          for (int q = 0; q < 4; ++q)
            vA[q] = *(const bf16x8*)(vk + (long)q * 32768 + (ks + 1) * 32);
        }
        __builtin_amdgcn_s_setprio(1);
#pragma unroll
        for (int q = 0; q < 4; ++q) Oacc[q + 4] = MFMA(ap, vB[q], Oacc[q + 4]);
        __builtin_amdgcn_s_setprio(0);
        if (ks < 3) {
#pragma unroll
          for (int q = 0; q < 4; ++q)
            vB[q] = *(const bf16x8*)(vk + (long)(q + 4) * 32768 + (ks + 1) * 32);
        }
      }
    }

    // write partial: raw O (bf16) + per-row stats
    const long po = (long)it * 8192;
#pragma unroll
    for (int r = 0; r < 4; ++r) {
      const int lr = w * 16 + fq * 4 + r;
      if (fr == 0) {
        pS[((long)it * 64 + lr) * 2] = m_run[r];
        pS[((long)it * 64 + lr) * 2 + 1] = l_run[r];
      }
#pragma unroll
      for (int jv = 0; jv < 8; ++jv)
        pO[po + (long)lr * 128 + jv * 16 + fr] = f2b(Oacc[jv][r]);
    }
  }
}

// ---------------- combine partials (log-sum-exp weights) ----------------
__global__ __launch_bounds__(256) void attn_reduce(
    const u16* __restrict__ pO, const float* __restrict__ pS,
    u16* __restrict__ ovb)
{
  const int h = blockIdx.x, qt = blockIdx.y;
  const int ktt = (qt >> 1) + 1;
  const int nkc = (ktt + 3) >> 2;
  int base = 0;
  for (int q = qt + 1; q < 32; ++q) base += nkc_of(q) * 16;
  const int tid = threadIdx.x;
  const int r = tid >> 2, cq = (tid & 3) * 32;

  float m[4], l[4], wgt[4];
  float M = -1e30f;
  for (int i = 0; i < nkc; ++i) {
    const long slot = base + i * 16 + h;
    m[i] = pS[(slot * 64 + r) * 2];
    l[i] = pS[(slot * 64 + r) * 2 + 1];
    M = fmaxf(M, m[i]);
  }
  float L = 0.f;
  for (int i = 0; i < nkc; ++i) { wgt[i] = __expf(m[i] - M); L += l[i] * wgt[i]; }
  const float inv = 1.0f / L;

  u16* orow = ovb + (long)(qt * 64 + r) * 2048 + h * 128 + cq;
  for (int c8 = 0; c8 < 32; c8 += 8) {
    float acc[8] = {};
    for (int i = 0; i < nkc; ++i) {
      const u16x8 v = *(const u16x8*)(pO + ((long)(base + i * 16 + h) * 64 + r) * 128 + cq + c8);
#pragma unroll
      for (int e = 0; e < 8; ++e) acc[e] += b2f(v[e]) * wgt[i];
    }
    u16x8 o;
#pragma unroll
    for (int e = 0; e < 8; ++e) o[e] = f2b(acc[e] * inv);
    *(u16x8*)(orow + c8) = o;
  }
}

// ---------------- conversion / transpose kernels ----------------
__global__ __launch_bounds__(256) void cast_bf16(const float* __restrict__ in,
                                                 u16* __restrict__ out, long n) {
  long i = ((long)blockIdx.x * 256 + threadIdx.x) * 4;
  if (i >= n) return;
  float4 v = *(const float4*)(in + i);
  ushort4 o = { f2b(v.x), f2b(v.y), f2b(v.z), f2b(v.w) };
  *(ushort4*)(out + i) = o;
}

__global__ __launch_bounds__(256) void transpose_cast(const float* __restrict__ in,
    u16* __restrict__ out, int ldi, int ldo, long sIn, long sOut) {
  in += (long)blockIdx.z * sIn;
  out += (long)blockIdx.z * sOut;
  __shared__ u16 t[32][33];
  const int i0 = blockIdx.y * 32, j0 = blockIdx.x * 32;
  const int tx = threadIdx.x & 31, ty = threadIdx.x >> 5;
  for (int r = ty; r < 32; r += 8)
    t[r][tx] = f2b(in[(long)(i0 + r) * ldi + j0 + tx]);
  __syncthreads();
  for (int r = ty; r < 32; r += 8)
    out[(long)(j0 + r) * ldo + i0 + tx] = t[tx][r];
}

// ---------------- RMSNorm fp32 (row stride ldin) -> bf16 ----------------
__global__ __launch_bounds__(256) void rmsnorm_cast(const float* __restrict__ in,
    const float* __restrict__ w, u16* __restrict__ out, int n, int ldin) {
  __shared__ float red[4];
  const float* row = in + (long)blockIdx.x * ldin;
  u16* orow = out + (long)blockIdx.x * n;
  float ss = 0.f;
  for (int i = threadIdx.x; i < n; i += 256) { float v = row[i]; ss += v * v; }
  float tot = block_sum(ss, red);
  float inv = rsqrtf(tot / (float)n + 1e-6f);
  for (int i = threadIdx.x; i < n; i += 256) orow[i] = f2b(row[i] * inv * w[i]);
}

// ---------------- RoPE table (double precision) ----------------
__global__ __launch_bounds__(256) void rope_table(float* tab) {
  int s = blockIdx.x * 8 + (threadIdx.x >> 5), j = threadIdx.x & 31;
  double freq = pow(10000.0, -(double)j / 32.0);
  double ang = (double)s * freq;
  tab[s * 64 + j] = (float)cos(ang);
  tab[s * 64 + 32 + j] = (float)sin(ang);
}

// ---------------- k_full: rmsnorm(ckv) ++ rope(k_pe) -> bf16 ----------------
// ckv points at col 1536 of the fused [2048][2176] f32 buffer.
__global__ __launch_bounds__(256) void build_kfull(const float* __restrict__ ckv,
    const float* __restrict__ lnw, const float* __restrict__ tab, u16* __restrict__ kfb) {
  __shared__ float red[4];
  const int s = blockIdx.x;
  const float* row = ckv + (long)s * 2176;
  float ss = 0.f;
  for (int i = threadIdx.x; i < 512; i += 256) { float v = row[i]; ss += v * v; }
  float tot = block_sum(ss, red);
  float inv = rsqrtf(tot / 512.0f + 1e-6f);
  u16* orow = kfb + (long)s * 576;
  for (int i = threadIdx.x; i < 512; i += 256) orow[i] = f2b(row[i] * inv * lnw[i]);
  if (threadIdx.x < 64) {
    int i = threadIdx.x, j = i & 31;
    float c = tab[s * 64 + j], sn = tab[s * 64 + 32 + j];
    float xv = row[512 + i];
    float rot = (i < 32) ? -row[512 + i + 32] : row[512 + i - 32];
    orow[512 + i] = f2b(xv * c + rot * sn);
  }
}

// ---------------- roped q_pe (bf16 in) into qfb[..., 512:576] ----------------
// grid 2048 x 256 threads: thread (h = t>>4, 4 i's).
__global__ __launch_bounds__(256) void rope_qpe(const u16* __restrict__ qb,
    const float* __restrict__ tab, u16* __restrict__ qfb) {
  const int s = blockIdx.x;
  const int h = threadIdx.x >> 4;
  const int i0 = (threadIdx.x & 15) * 4;
  const u16* src = qb + (long)s * 3072 + h * 192 + 128;
  u16* dst = qfb + (long)s * 9216 + h * 576 + 512;
#pragma unroll
  for (int k = 0; k < 4; ++k) {
    const int i = i0 + k, j = i & 31;
    float c = tab[s * 64 + j], sn = tab[s * 64 + 32 + j];
    float xv = b2f(src[i]);
    float rot = (i < 32) ? -b2f(src[i + 32]) : b2f(src[i - 32]);
    dst[i] = f2b(xv * c + rot * sn);
  }
}

extern "C" void kernel_launch(void* const* d_in, const int* in_sizes, int n_in,
                              void* d_out, int out_size, void* d_ws, size_t ws_size,
                              hipStream_t stream) {
  const float* x      = (const float*)d_in[0];
  const float* w_q_a  = (const float*)d_in[1];
  const float* q_ln   = (const float*)d_in[2];
  const float* w_q_b  = (const float*)d_in[3];
  const float* w_kv_a = (const float*)d_in[4];
  const float* kv_ln  = (const float*)d_in[5];
  const float* w_kv_b = (const float*)d_in[6];
  const float* w_o    = (const float*)d_in[7];
  float* out = (float*)d_out;

  // ---- fixed workspace (bytes) ----
  char* p = (char*)d_ws;
  float* tab   = (float*)p;  p += 524288;      // 2048*64 f32
  u16* wkvbb   = (u16*)p;    p += 4194304;     // 512*4096
  u16* wuvT    = (u16*)p;    p += 2097152;     // 16*128*512
  u16* woT     = (u16*)p;    p += 8388608;     // 2048*2048
  u16* qfb     = (u16*)p;    p += 37748736;    // 2048*9216
  u16* vallT   = (u16*)p;    p += 8388608;     // 16*128*2048
  u16* kfb     = (u16*)p;    p += 2359296;     // 2048*576
  u16* ovb     = (u16*)p;    p += 8388608;     // 2048*2048
  char* tb = p;
  // phase 1 transient:
  u16* xb      = (u16*)tb;                     // 2048*2048            (8.4 MB)
  u16* wabT    = (u16*)(tb + 8388608);         // 2176*2048 (qa++kva transposed)
  float* qac   = (float*)(tb + 17301504);      // 2048*2176 f32 (qa | ckv_kpe)
  u16* qab     = (u16*)(tb + 35127296);        // 2048*1536
  u16* wqbT    = (u16*)(tb + 41418752);        // 3072*1536
  u16* qb      = (u16*)(tb + 50855936);        // 2048*3072  (ends 63.4 MB)
  // phase 2 transient (aliases phase 1, used only after it is dead):
  u16* pO      = (u16*)tb;                     // 1280*64*128 bf16 (21 MB)
  float* pS    = (float*)(tb + 20971520);      // 1280*64*2 f32
  u32* ctr     = (u32*)(tb + 21626880);

  rope_table<<<dim3(256), 256, 0, stream>>>(tab);

  // weight prep
  cast_bf16<<<4096, 256, 0, stream>>>(x, xb, 4194304);
  transpose_cast<<<dim3(48, 64), 256, 0, stream>>>(w_q_a, wabT, 1536, 2048, 0, 0);
  transpose_cast<<<dim3(18, 64), 256, 0, stream>>>(w_kv_a, wabT + 1536 * 2048, 576, 2048, 0, 0);
  transpose_cast<<<dim3(96, 48), 256, 0, stream>>>(w_q_b, wqbT, 3072, 1536, 0, 0);
  cast_bf16<<<2048, 256, 0, stream>>>(w_kv_b, wkvbb, 2097152);
  transpose_cast<<<dim3(4, 16, 16), 256, 0, stream>>>(w_kv_b + 128, wuvT, 4096, 512, 256, 65536);
  transpose_cast<<<dim3(64, 64), 256, 0, stream>>>(w_o, woT, 2048, 2048, 0, 0);

  // fused: [q_a | ckv_kpe] = x @ [w_q_a | w_kv_a]  (f32, ldc 2176)
  gemm_mfma<0><<<dim3(17, 16), 256, 0, stream>>>(
      xb, wabT, qac, 2048, 2048, 2048, 2176, 0, 0, 0);
  rmsnorm_cast<<<2048, 256, 0, stream>>>(qac, q_ln, qab, 1536, 2176);
  build_kfull<<<2048, 256, 0, stream>>>(qac + 1536, kv_ln, tab, kfb);

  // q = q_a @ w_q_b (bf16 out)
  gemm_mfma<1><<<dim3(24, 16), 256, 0, stream>>>(
      qab, wqbT, qb, 1536, 1536, 1536, 3072, 0, 0, 0);

  // q_full[:, h, :512] = q_nope[h] @ w_uk[h]^T (bf16 out, batched over h)
  gemm_mfma<1><<<dim3(4, 16, 16), 256, 0, stream>>>(
      qb, wkvbb, qfb, 128, 3072, 4096, 9216, 192, 256, 576);
  rope_qpe<<<dim3(2048), 256, 0, stream>>>(qb, tab, qfb);

  // vallT[h] = (ckv_n @ w_uv[h])^T  (bf16 transposed out)
  gemm_mfma<2><<<dim3(1, 16, 16), 256, 0, stream>>>(
      kfb, wuvT, vallT, 512, 576, 512, 2048, 0, 65536, 262144);

  // split-K flash attention with dynamic queue (3 blocks/CU)
  init_ctr<<<1, 1, 0, stream>>>(ctr);
  attn_partial<<<dim3(768), 256, 0, stream>>>(qfb, kfb, vallT, ctr, pO, pS);
  attn_reduce<<<dim3(16, 32), 256, 0, stream>>>(pO, pS, ovb);

  // y = o_v @ w_o (f32 out)
  gemm_mfma<0><<<dim3(16, 16), 256, 0, stream>>>(
      ovb, woT, out, 2048, 2048, 2048, 2048, 0, 0, 0);
}

// Round 6
// 591.945 us; speedup vs baseline: 1.0244x; 1.0244x over previous
//
#include <hip/hip_runtime.h>
#include <math.h>

// DeepSeek V2 MLA attention — bf16 MFMA GEMMs + split-K flash attention with
// a dynamic work queue (v6). v6 = v5 + XCD-partitioned queue: v5's
// register-direct V reads thrashed per-XCD L2 (V=8.4MB > 4MB/XCD; FETCH 292MB,
// WRITE 277MB, 278us). Blocks on XCD x (= blockIdx%8) now only process heads
// {x, x+8}, making the per-XCD V working set 1.05MB (+K 2.3MB) => L2-resident.
// 8 independent heavy-first queues (one per XCD), 96 blocks each.
// B=1 S=2048 E=2048 H=16 DN=128 DR=64 DV=128 R=512 QLR=1536

typedef unsigned short u16;
typedef unsigned int u32;
typedef __bf16 bf16x8 __attribute__((ext_vector_type(8)));
typedef float f32x4 __attribute__((ext_vector_type(4)));
typedef unsigned short u16x8 __attribute__((ext_vector_type(8)));

__device__ __forceinline__ u16 f2b(float f) {  // fp32 -> bf16 RNE
  u32 u = __float_as_uint(f);
  u += 0x7FFFu + ((u >> 16) & 1u);
  return (u16)(u >> 16);
}
__device__ __forceinline__ float b2f(u16 v) {
  return __uint_as_float(((u32)v) << 16);
}

#define GLDS(g, l) __builtin_amdgcn_global_load_lds( \
    (const __attribute__((address_space(1))) u32*)(g), \
    (__attribute__((address_space(3))) u32*)(l), 16, 0, 0)

#define MFMA(a, b, c) __builtin_amdgcn_mfma_f32_16x16x32_bf16(a, b, c, 0, 0, 0)

// s_waitcnt vmcnt(N) (lgkmcnt/expcnt untouched) + s_barrier.
template<int N>
__device__ __forceinline__ void vm_barrier() {
  __builtin_amdgcn_s_waitcnt(0xF70 | N);  // expcnt=7, lgkmcnt=15, vmcnt=N
  __builtin_amdgcn_s_barrier();
}

// Per-group (2 heads) items enumerated qt-descending (heavy first):
// for qt=31..0, kc=0..nkc-1, hh=0..1.  nkc(qt) = ceil((qt/2+1)/4).
// Per-group total = 160; global slot = g*160 + local.
#define N_ITEMS_G 160
__device__ __forceinline__ int nkc_of(int qt) { return (((qt >> 1) + 1) + 3) >> 2; }

// ---------------- block reduction helper ----------------
__device__ __forceinline__ float block_sum(float v, float* red) {
#pragma unroll
  for (int off = 32; off > 0; off >>= 1) v += __shfl_down(v, off);
  const int lane = threadIdx.x & 63, w = threadIdx.x >> 6;
  if (lane == 0) red[w] = v;
  __syncthreads();
  float r = red[0] + red[1] + red[2] + red[3];
  __syncthreads();
  return r;
}

// ---------------- bf16 MFMA GEMM, 128x128 tile, BK=32, pipelined ------------
// C = A[M,K] @ B[N,K]^T (both row-major bf16). Batched over blockIdx.z.
// OUTK: 0 = fp32 out, 1 = bf16 out, 2 = bf16 transposed out (C[n*ldc+m]).
template<int OUTK>
__global__ __launch_bounds__(256) void gemm_mfma(
    const u16* __restrict__ A, const u16* __restrict__ B, void* __restrict__ Cv,
    int K, int lda, int ldb, int ldc, long sA, long sB, long sC)
{
  __shared__ u16 At[3][4096];  // triple-buffered 128x32 tiles
  __shared__ u16 Bt[3][4096];
  const u16* Ab = A + (long)blockIdx.z * sA;
  const u16* Bb = B + (long)blockIdx.z * sB;
  const int tid = threadIdx.x;
  const int w = tid >> 6, lane = tid & 63;
  const int m0 = blockIdx.y * 128, n0 = blockIdx.x * 128;
  const int wm = (w >> 1) * 64, wn = (w & 1) * 64;
  const int fr = lane & 15, fq = lane >> 4;

  const int c0 = w * 2, c1 = w * 2 + 1;
  const int e0 = (c0 * 64 + lane) * 8, e1 = (c1 * 64 + lane) * 8;
  const int r0 = e0 >> 5, col0 = e0 & 31;
  const int r1 = e1 >> 5, col1 = e1 & 31;

  const int nk = K >> 5;
  auto issue = [&](int kc) {
    const int k0 = kc * 32;
    u16* at = At[kc % 3];
    u16* bt = Bt[kc % 3];
    GLDS(Ab + (long)(m0 + r0) * lda + k0 + col0, at + c0 * 512);
    GLDS(Bb + (long)(n0 + r0) * ldb + k0 + col0, bt + c0 * 512);
    GLDS(Ab + (long)(m0 + r1) * lda + k0 + col1, at + c1 * 512);
    GLDS(Bb + (long)(n0 + r1) * ldb + k0 + col1, bt + c1 * 512);
  };

  f32x4 acc[4][4] = {};
  issue(0);
  issue(1);
  vm_barrier<4>();
  for (int kc = 0; kc < nk; ++kc) {
    if (kc + 2 < nk) issue(kc + 2);
    const u16* at = At[kc % 3];
    const u16* bt = Bt[kc % 3];
    bf16x8 af[4], bfr[4];
#pragma unroll
    for (int i = 0; i < 4; ++i)
      af[i] = *(const bf16x8*)(at + (wm + i * 16 + fr) * 32 + fq * 8);
#pragma unroll
    for (int j = 0; j < 4; ++j)
      bfr[j] = *(const bf16x8*)(bt + (wn + j * 16 + fr) * 32 + fq * 8);
#pragma unroll
    for (int i = 0; i < 4; ++i)
#pragma unroll
      for (int j = 0; j < 4; ++j)
        acc[i][j] = MFMA(af[i], bfr[j], acc[i][j]);
    if (kc + 1 < nk) {
      if (kc + 2 < nk) vm_barrier<4>();
      else vm_barrier<0>();
    }
  }

  if (OUTK == 0) {
    float* C = (float*)Cv + (long)blockIdx.z * sC;
#pragma unroll
    for (int i = 0; i < 4; ++i)
#pragma unroll
      for (int j = 0; j < 4; ++j) {
        long base = (long)(m0 + wm + i * 16 + fq * 4) * ldc + (n0 + wn + j * 16 + fr);
#pragma unroll
        for (int r = 0; r < 4; ++r) C[base + (long)r * ldc] = acc[i][j][r];
      }
  } else if (OUTK == 1) {
    u16* C = (u16*)Cv + (long)blockIdx.z * sC;
#pragma unroll
    for (int i = 0; i < 4; ++i)
#pragma unroll
      for (int j = 0; j < 4; ++j) {
        long base = (long)(m0 + wm + i * 16 + fq * 4) * ldc + (n0 + wn + j * 16 + fr);
#pragma unroll
        for (int r = 0; r < 4; ++r) C[base + (long)r * ldc] = f2b(acc[i][j][r]);
      }
  } else {
    u16* C = (u16*)Cv + (long)blockIdx.z * sC;
#pragma unroll
    for (int i = 0; i < 4; ++i)
#pragma unroll
      for (int j = 0; j < 4; ++j) {
        ushort4 v = { f2b(acc[i][j][0]), f2b(acc[i][j][1]),
                      f2b(acc[i][j][2]), f2b(acc[i][j][3]) };
        *(ushort4*)(C + (long)(n0 + wn + j * 16 + fr) * ldc + (m0 + wm + i * 16 + fq * 4)) = v;
      }
  }
}

// ---------------- counter init (8 group counters) ----------------
__global__ void init_ctr(u32* ctr) {
  if (threadIdx.x < 8) ctr[threadIdx.x] = 0;
}

// ---------------- split-K flash attention, XCD-partitioned queue ------------
// 768 persistent blocks (3/CU). Block b belongs to group g = b&7 (XCD-aligned
// under the default round-robin dispatch) and only processes heads {g, g+8},
// so its V slices (2 x 524KB) + K (2.3MB) stay resident in that XCD's 4MB L2.
// Item = (hh, qt, kc): q-rows [qt*64,+64) of head g+8*hh vs K-tiles
// [4kc, min(4kc+4, ktt)). Writes raw-O partial (bf16) + per-row (m,l) stats.
// LDS = Ks 24 KiB + Ps 17 KiB = 41 KiB -> 3 blocks/CU. V operands are
// register-loaded directly from vallT (fragment-layout rows).
__global__ __launch_bounds__(256, 3) void attn_partial(
    const u16* __restrict__ qfb,   // [2048][16*576]
    const u16* __restrict__ kfb,   // [2048][576]
    const u16* __restrict__ vallT, // [16][128][2048]
    u32* __restrict__ ctr,         // [8]
    u16* __restrict__ pO,          // [1280][64][128]
    float* __restrict__ pS)        // [1280][64][2]
{
  __shared__ u16 Ks[3][4096];    // K chunks, [row 128][g'=g^(row&3)][8]
  __shared__ u16 Ps[4 * 2176];   // per-wave P, 16 rows x 136 stride
  __shared__ u32 cur;

  const int tid = threadIdx.x;
  const int w = tid >> 6, lane = tid & 63;
  const int fr = lane & 15, fq = lane >> 4;
  const float scale = 0.07216878364870323f;  // (DN+DR)^-0.5
  const int grp = (int)(blockIdx.x & 7);     // XCD-aligned head group
  u16* Psw = Ps + w * 2176;

  const int krow0 = (w * 2) * 16 + (lane >> 2);
  const int krow1 = (w * 2 + 1) * 16 + (lane >> 2);
  const int kg0 = (lane & 3) ^ (krow0 & 3);
  const int kg1 = (lane & 3) ^ (krow1 & 3);

  while (true) {
    if (tid == 0) cur = atomicAdd(&ctr[grp], 1u);
    __syncthreads();
    const u32 it = cur;
    if (it >= N_ITEMS_G) break;

    // decode group-local item (qt descending; within qt: kc asc, hh 0..1)
    int rem = (int)it, qt = 31, kc = 0, hh = 0;
    for (int q = 31; q >= 0; --q) {
      int cnt = nkc_of(q) * 2;
      if (rem < cnt) { qt = q; kc = rem >> 1; hh = rem & 1; break; }
      rem -= cnt;
    }
    const int h = grp + hh * 8;
    const u32 gslot = (u32)grp * N_ITEMS_G + it;   // global partial slot
    const int q0 = qt * 64;
    const int ktt = (qt >> 1) + 1;
    const int kt0 = kc * 4, kt1 = min(kt0 + 4, ktt);

    // Q fragments resident (A[m=fr][k=fq*8+j])
    bf16x8 aq[18];
    {
      const u16* qp = qfb + (long)(q0 + w * 16 + fr) * 9216 + h * 576 + fq * 8;
#pragma unroll
      for (int d = 0; d < 18; ++d) aq[d] = *(const bf16x8*)(qp + d * 32);
    }

    float m_run[4], l_run[4];
#pragma unroll
    for (int r = 0; r < 4; ++r) { m_run[r] = -1e30f; l_run[r] = 0.f; }
    f32x4 Oacc[8] = {};
    // per-lane V fragment base: frag(jv,ks) = vlane + k0 + jv*32768 + ks*32
    const u16* vlane = vallT + (long)h * 262144 + (long)fr * 2048 + fq * 8;

    auto issueK = [&](int kt, int c) {
      const int k0i = kt * 128, d0 = c * 32;
      u16* dst = Ks[c % 3];
      GLDS(kfb + (long)(k0i + krow0) * 576 + d0 + kg0 * 8, dst + (w * 2) * 512);
      GLDS(kfb + (long)(k0i + krow1) * 576 + d0 + kg1 * 8, dst + (w * 2 + 1) * 512);
    };

    issueK(kt0, 0);
    issueK(kt0, 1);

    for (int kt = kt0; kt < kt1; ++kt) {
      const int k0 = kt * 128;
      vm_barrier<2>();  // chunk0 landed block-wide (chunk1 in flight)

      f32x4 sc[8] = {};
#pragma unroll
      for (int d = 0; d < 18; ++d) {
        if (d + 2 < 18) issueK(kt, d + 2);
        const u16* kb = Ks[d % 3];
        __builtin_amdgcn_s_setprio(1);
#pragma unroll
        for (int j = 0; j < 8; ++j) {
          const int row = j * 16 + fr;
          bf16x8 b = *(const bf16x8*)(kb + row * 32 + ((fq ^ (row & 3)) * 8));
          sc[j] = MFMA(aq[d], b, sc[j]);
        }
        __builtin_amdgcn_s_setprio(0);
        if (d < 17) {
          if (d + 2 < 18) vm_barrier<2>();
          else vm_barrier<0>();
        }
      }
      // all waves done reading Ks for this tile; Ks bufs may be rewritten
      __builtin_amdgcn_s_barrier();

      // V ks-group 0 into registers (L2-resident now; latency hidden under
      // softmax), then prefetch next tile's first two K chunks.
      const u16* vk = vlane + k0;
      bf16x8 vA[4], vB[4];
#pragma unroll
      for (int q = 0; q < 4; ++q) {
        vA[q] = *(const bf16x8*)(vk + (long)q * 32768);
        vB[q] = *(const bf16x8*)(vk + (long)(q + 4) * 32768);
      }
      if (kt + 1 < kt1) { issueK(kt + 1, 0); issueK(kt + 1, 1); }

      // wave-local online softmax
      const bool diag = (kt == ktt - 1);
#pragma unroll
      for (int r = 0; r < 4; ++r) {
        float mx = m_run[r];
#pragma unroll
        for (int j = 0; j < 8; ++j) {
          float s = sc[j][r] * scale;
          if (diag) {
            const int row = q0 + w * 16 + fq * 4 + r;
            const int col = k0 + j * 16 + fr;
            if (col > row) s = -1e30f;
          }
          sc[j][r] = s;
          mx = fmaxf(mx, s);
        }
        mx = fmaxf(mx, __shfl_xor(mx, 1));
        mx = fmaxf(mx, __shfl_xor(mx, 2));
        mx = fmaxf(mx, __shfl_xor(mx, 4));
        mx = fmaxf(mx, __shfl_xor(mx, 8));
        const float alpha = __expf(m_run[r] - mx);
        m_run[r] = mx;
        float sum = 0.f;
#pragma unroll
        for (int j = 0; j < 8; ++j) {
          float p = __expf(sc[j][r] - mx);
          sc[j][r] = p;
          sum += p;
        }
        sum += __shfl_xor(sum, 1);
        sum += __shfl_xor(sum, 2);
        sum += __shfl_xor(sum, 4);
        sum += __shfl_xor(sum, 8);
        l_run[r] = l_run[r] * alpha + sum;
#pragma unroll
        for (int jv = 0; jv < 8; ++jv) Oacc[jv][r] *= alpha;
#pragma unroll
        for (int j = 0; j < 8; ++j)
          Psw[(fq * 4 + r) * 136 + j * 16 + fr] = f2b(sc[j][r]);
      }

      // PV: O += P @ V^T, V fragments ping-ponged from global (no barrier)
#pragma unroll
      for (int ks = 0; ks < 4; ++ks) {
        bf16x8 ap = *(const bf16x8*)(Psw + fr * 136 + ks * 32 + fq * 8);
        __builtin_amdgcn_s_setprio(1);
#pragma unroll
        for (int q = 0; q < 4; ++q) Oacc[q] = MFMA(ap, vA[q], Oacc[q]);
        __builtin_amdgcn_s_setprio(0);
        if (ks < 3) {
#pragma unroll
          for (int q = 0; q < 4; ++q)
            vA[q] = *(const bf16x8*)(vk + (long)q * 32768 + (ks + 1) * 32);
        }
        __builtin_amdgcn_s_setprio(1);
#pragma unroll
        for (int q = 0; q < 4; ++q) Oacc[q + 4] = MFMA(ap, vB[q], Oacc[q + 4]);
        __builtin_amdgcn_s_setprio(0);
        if (ks < 3) {
#pragma unroll
          for (int q = 0; q < 4; ++q)
            vB[q] = *(const bf16x8*)(vk + (long)(q + 4) * 32768 + (ks + 1) * 32);
        }
      }
    }

    // write partial: raw O (bf16) + per-row stats
    const long po = (long)gslot * 8192;
#pragma unroll
    for (int r = 0; r < 4; ++r) {
      const int lr = w * 16 + fq * 4 + r;
      if (fr == 0) {
        pS[((long)gslot * 64 + lr) * 2] = m_run[r];
        pS[((long)gslot * 64 + lr) * 2 + 1] = l_run[r];
      }
#pragma unroll
      for (int jv = 0; jv < 8; ++jv)
        pO[po + (long)lr * 128 + jv * 16 + fr] = f2b(Oacc[jv][r]);
    }
  }
}

// ---------------- combine partials (log-sum-exp weights) ----------------
__global__ __launch_bounds__(256) void attn_reduce(
    const u16* __restrict__ pO, const float* __restrict__ pS,
    u16* __restrict__ ovb)
{
  const int h = blockIdx.x, qt = blockIdx.y;
  const int g = h & 7, hh = h >> 3;
  const int ktt = (qt >> 1) + 1;
  const int nkc = (ktt + 3) >> 2;
  int base = g * N_ITEMS_G;
  for (int q = qt + 1; q < 32; ++q) base += nkc_of(q) * 2;
  const int tid = threadIdx.x;
  const int r = tid >> 2, cq = (tid & 3) * 32;

  float m[4], l[4], wgt[4];
  float M = -1e30f;
  for (int i = 0; i < nkc; ++i) {
    const long slot = base + i * 2 + hh;
    m[i] = pS[(slot * 64 + r) * 2];
    l[i] = pS[(slot * 64 + r) * 2 + 1];
    M = fmaxf(M, m[i]);
  }
  float L = 0.f;
  for (int i = 0; i < nkc; ++i) { wgt[i] = __expf(m[i] - M); L += l[i] * wgt[i]; }
  const float inv = 1.0f / L;

  u16* orow = ovb + (long)(qt * 64 + r) * 2048 + h * 128 + cq;
  for (int c8 = 0; c8 < 32; c8 += 8) {
    float acc[8] = {};
    for (int i = 0; i < nkc; ++i) {
      const long slot = base + i * 2 + hh;
      const u16x8 v = *(const u16x8*)(pO + (slot * 64 + r) * 128 + cq + c8);
#pragma unroll
      for (int e = 0; e < 8; ++e) acc[e] += b2f(v[e]) * wgt[i];
    }
    u16x8 o;
#pragma unroll
    for (int e = 0; e < 8; ++e) o[e] = f2b(acc[e] * inv);
    *(u16x8*)(orow + c8) = o;
  }
}

// ---------------- conversion / transpose kernels ----------------
__global__ __launch_bounds__(256) void cast_bf16(const float* __restrict__ in,
                                                 u16* __restrict__ out, long n) {
  long i = ((long)blockIdx.x * 256 + threadIdx.x) * 4;
  if (i >= n) return;
  float4 v = *(const float4*)(in + i);
  ushort4 o = { f2b(v.x), f2b(v.y), f2b(v.z), f2b(v.w) };
  *(ushort4*)(out + i) = o;
}

__global__ __launch_bounds__(256) void transpose_cast(const float* __restrict__ in,
    u16* __restrict__ out, int ldi, int ldo, long sIn, long sOut) {
  in += (long)blockIdx.z * sIn;
  out += (long)blockIdx.z * sOut;
  __shared__ u16 t[32][33];
  const int i0 = blockIdx.y * 32, j0 = blockIdx.x * 32;
  const int tx = threadIdx.x & 31, ty = threadIdx.x >> 5;
  for (int r = ty; r < 32; r += 8)
    t[r][tx] = f2b(in[(long)(i0 + r) * ldi + j0 + tx]);
  __syncthreads();
  for (int r = ty; r < 32; r += 8)
    out[(long)(j0 + r) * ldo + i0 + tx] = t[tx][r];
}

// ---------------- RMSNorm fp32 (row stride ldin) -> bf16 ----------------
__global__ __launch_bounds__(256) void rmsnorm_cast(const float* __restrict__ in,
    const float* __restrict__ w, u16* __restrict__ out, int n, int ldin) {
  __shared__ float red[4];
  const float* row = in + (long)blockIdx.x * ldin;
  u16* orow = out + (long)blockIdx.x * n;
  float ss = 0.f;
  for (int i = threadIdx.x; i < n; i += 256) { float v = row[i]; ss += v * v; }
  float tot = block_sum(ss, red);
  float inv = rsqrtf(tot / (float)n + 1e-6f);
  for (int i = threadIdx.x; i < n; i += 256) orow[i] = f2b(row[i] * inv * w[i]);
}

// ---------------- RoPE table (double precision) ----------------
__global__ __launch_bounds__(256) void rope_table(float* tab) {
  int s = blockIdx.x * 8 + (threadIdx.x >> 5), j = threadIdx.x & 31;
  double freq = pow(10000.0, -(double)j / 32.0);
  double ang = (double)s * freq;
  tab[s * 64 + j] = (float)cos(ang);
  tab[s * 64 + 32 + j] = (float)sin(ang);
}

// ---------------- k_full: rmsnorm(ckv) ++ rope(k_pe) -> bf16 ----------------
// ckv points at col 1536 of the fused [2048][2176] f32 buffer.
__global__ __launch_bounds__(256) void build_kfull(const float* __restrict__ ckv,
    const float* __restrict__ lnw, const float* __restrict__ tab, u16* __restrict__ kfb) {
  __shared__ float red[4];
  const int s = blockIdx.x;
  const float* row = ckv + (long)s * 2176;
  float ss = 0.f;
  for (int i = threadIdx.x; i < 512; i += 256) { float v = row[i]; ss += v * v; }
  float tot = block_sum(ss, red);
  float inv = rsqrtf(tot / 512.0f + 1e-6f);
  u16* orow = kfb + (long)s * 576;
  for (int i = threadIdx.x; i < 512; i += 256) orow[i] = f2b(row[i] * inv * lnw[i]);
  if (threadIdx.x < 64) {
    int i = threadIdx.x, j = i & 31;
    float c = tab[s * 64 + j], sn = tab[s * 64 + 32 + j];
    float xv = row[512 + i];
    float rot = (i < 32) ? -row[512 + i + 32] : row[512 + i - 32];
    orow[512 + i] = f2b(xv * c + rot * sn);
  }
}

// ---------------- roped q_pe (bf16 in) into qfb[..., 512:576] ----------------
// grid 2048 x 256 threads: thread (h = t>>4, 4 i's).
__global__ __launch_bounds__(256) void rope_qpe(const u16* __restrict__ qb,
    const float* __restrict__ tab, u16* __restrict__ qfb) {
  const int s = blockIdx.x;
  const int h = threadIdx.x >> 4;
  const int i0 = (threadIdx.x & 15) * 4;
  const u16* src = qb + (long)s * 3072 + h * 192 + 128;
  u16* dst = qfb + (long)s * 9216 + h * 576 + 512;
#pragma unroll
  for (int k = 0; k < 4; ++k) {
    const int i = i0 + k, j = i & 31;
    float c = tab[s * 64 + j], sn = tab[s * 64 + 32 + j];
    float xv = b2f(src[i]);
    float rot = (i < 32) ? -b2f(src[i + 32]) : b2f(src[i - 32]);
    dst[i] = f2b(xv * c + rot * sn);
  }
}

extern "C" void kernel_launch(void* const* d_in, const int* in_sizes, int n_in,
                              void* d_out, int out_size, void* d_ws, size_t ws_size,
                              hipStream_t stream) {
  const float* x      = (const float*)d_in[0];
  const float* w_q_a  = (const float*)d_in[1];
  const float* q_ln   = (const float*)d_in[2];
  const float* w_q_b  = (const float*)d_in[3];
  const float* w_kv_a = (const float*)d_in[4];
  const float* kv_ln  = (const float*)d_in[5];
  const float* w_kv_b = (const float*)d_in[6];
  const float* w_o    = (const float*)d_in[7];
  float* out = (float*)d_out;

  // ---- fixed workspace (bytes) ----
  char* p = (char*)d_ws;
  float* tab   = (float*)p;  p += 524288;      // 2048*64 f32
  u16* wkvbb   = (u16*)p;    p += 4194304;     // 512*4096
  u16* wuvT    = (u16*)p;    p += 2097152;     // 16*128*512
  u16* woT     = (u16*)p;    p += 8388608;     // 2048*2048
  u16* qfb     = (u16*)p;    p += 37748736;    // 2048*9216
  u16* vallT   = (u16*)p;    p += 8388608;     // 16*128*2048
  u16* kfb     = (u16*)p;    p += 2359296;     // 2048*576
  u16* ovb     = (u16*)p;    p += 8388608;     // 2048*2048
  char* tb = p;
  // phase 1 transient:
  u16* xb      = (u16*)tb;                     // 2048*2048            (8.4 MB)
  u16* wabT    = (u16*)(tb + 8388608);         // 2176*2048 (qa++kva transposed)
  float* qac   = (float*)(tb + 17301504);      // 2048*2176 f32 (qa | ckv_kpe)
  u16* qab     = (u16*)(tb + 35127296);        // 2048*1536
  u16* wqbT    = (u16*)(tb + 41418752);        // 3072*1536
  u16* qb      = (u16*)(tb + 50855936);        // 2048*3072  (ends 63.4 MB)
  // phase 2 transient (aliases phase 1, used only after it is dead):
  u16* pO      = (u16*)tb;                     // 1280*64*128 bf16 (21 MB)
  float* pS    = (float*)(tb + 20971520);      // 1280*64*2 f32
  u32* ctr     = (u32*)(tb + 21626880);        // 8 group counters

  rope_table<<<dim3(256), 256, 0, stream>>>(tab);

  // weight prep
  cast_bf16<<<4096, 256, 0, stream>>>(x, xb, 4194304);
  transpose_cast<<<dim3(48, 64), 256, 0, stream>>>(w_q_a, wabT, 1536, 2048, 0, 0);
  transpose_cast<<<dim3(18, 64), 256, 0, stream>>>(w_kv_a, wabT + 1536 * 2048, 576, 2048, 0, 0);
  transpose_cast<<<dim3(96, 48), 256, 0, stream>>>(w_q_b, wqbT, 3072, 1536, 0, 0);
  cast_bf16<<<2048, 256, 0, stream>>>(w_kv_b, wkvbb, 2097152);
  transpose_cast<<<dim3(4, 16, 16), 256, 0, stream>>>(w_kv_b + 128, wuvT, 4096, 512, 256, 65536);
  transpose_cast<<<dim3(64, 64), 256, 0, stream>>>(w_o, woT, 2048, 2048, 0, 0);

  // fused: [q_a | ckv_kpe] = x @ [w_q_a | w_kv_a]  (f32, ldc 2176)
  gemm_mfma<0><<<dim3(17, 16), 256, 0, stream>>>(
      xb, wabT, qac, 2048, 2048, 2048, 2176, 0, 0, 0);
  rmsnorm_cast<<<2048, 256, 0, stream>>>(qac, q_ln, qab, 1536, 2176);
  build_kfull<<<2048, 256, 0, stream>>>(qac + 1536, kv_ln, tab, kfb);

  // q = q_a @ w_q_b (bf16 out)
  gemm_mfma<1><<<dim3(24, 16), 256, 0, stream>>>(
      qab, wqbT, qb, 1536, 1536, 1536, 3072, 0, 0, 0);

  // q_full[:, h, :512] = q_nope[h] @ w_uk[h]^T (bf16 out, batched over h)
  gemm_mfma<1><<<dim3(4, 16, 16), 256, 0, stream>>>(
      qb, wkvbb, qfb, 128, 3072, 4096, 9216, 192, 256, 576);
  rope_qpe<<<dim3(2048), 256, 0, stream>>>(qb, tab, qfb);

  // vallT[h] = (ckv_n @ w_uv[h])^T  (bf16 transposed out)
  gemm_mfma<2><<<dim3(1, 16, 16), 256, 0, stream>>>(
      kfb, wuvT, vallT, 512, 576, 512, 2048, 0, 65536, 262144);

  // split-K flash attention, XCD-partitioned dynamic queues (3 blocks/CU)
  init_ctr<<<1, 64, 0, stream>>>(ctr);
  attn_partial<<<dim3(768), 256, 0, stream>>>(qfb, kfb, vallT, ctr, pO, pS);
  attn_reduce<<<dim3(16, 32), 256, 0, stream>>>(pO, pS, ovb);

  // y = o_v @ w_o (f32 out)
  gemm_mfma<0><<<dim3(16, 16), 256, 0, stream>>>(
      ovb, woT, out, 2048, 2048, 2048, 2048, 0, 0, 0);
}

// Round 7
// 577.385 us; speedup vs baseline: 1.0503x; 1.0252x over previous
//
#include <hip/hip_runtime.h>
#include <math.h>

// DeepSeek V2 MLA attention — bf16 MFMA GEMMs + split-K flash attention with
// a dynamic work queue (v7). v7 = v6 + register diet: v5/v6's
// __launch_bounds__(256,3) capped the unified VGPR+AGPR file at 168/wave but
// the kernel needed ~172 (aq 72 + sc 32 + Oacc 32 + V ping-pong 16 + addr)
// -> allocator split 84+84 and SPILLED aq to scratch = ~250MB deterministic
// HBM write traffic (WRITE_SIZE 277MB, identical v5/v6) and MfmaUtil 7%.
// Fix: single vA[4] V buffer (8 regs, was 16) -> total ~156 <= 168, no spill.
// Keeps v6's XCD-partitioned queues (heads {g,g+8} per XCD, V+K L2-resident).
// B=1 S=2048 E=2048 H=16 DN=128 DR=64 DV=128 R=512 QLR=1536

typedef unsigned short u16;
typedef unsigned int u32;
typedef __bf16 bf16x8 __attribute__((ext_vector_type(8)));
typedef float f32x4 __attribute__((ext_vector_type(4)));
typedef unsigned short u16x8 __attribute__((ext_vector_type(8)));

__device__ __forceinline__ u16 f2b(float f) {  // fp32 -> bf16 RNE
  u32 u = __float_as_uint(f);
  u += 0x7FFFu + ((u >> 16) & 1u);
  return (u16)(u >> 16);
}
__device__ __forceinline__ float b2f(u16 v) {
  return __uint_as_float(((u32)v) << 16);
}

#define GLDS(g, l) __builtin_amdgcn_global_load_lds( \
    (const __attribute__((address_space(1))) u32*)(g), \
    (__attribute__((address_space(3))) u32*)(l), 16, 0, 0)

#define MFMA(a, b, c) __builtin_amdgcn_mfma_f32_16x16x32_bf16(a, b, c, 0, 0, 0)

// s_waitcnt vmcnt(N) (lgkmcnt/expcnt untouched) + s_barrier.
template<int N>
__device__ __forceinline__ void vm_barrier() {
  __builtin_amdgcn_s_waitcnt(0xF70 | N);  // expcnt=7, lgkmcnt=15, vmcnt=N
  __builtin_amdgcn_s_barrier();
}

// Per-group (2 heads) items enumerated qt-descending (heavy first):
// for qt=31..0, kc=0..nkc-1, hh=0..1.  nkc(qt) = ceil((qt/2+1)/4).
// Per-group total = 160; global slot = g*160 + local.
#define N_ITEMS_G 160
__device__ __forceinline__ int nkc_of(int qt) { return (((qt >> 1) + 1) + 3) >> 2; }

// ---------------- block reduction helper ----------------
__device__ __forceinline__ float block_sum(float v, float* red) {
#pragma unroll
  for (int off = 32; off > 0; off >>= 1) v += __shfl_down(v, off);
  const int lane = threadIdx.x & 63, w = threadIdx.x >> 6;
  if (lane == 0) red[w] = v;
  __syncthreads();
  float r = red[0] + red[1] + red[2] + red[3];
  __syncthreads();
  return r;
}

// ---------------- bf16 MFMA GEMM, 128x128 tile, BK=32, pipelined ------------
// C = A[M,K] @ B[N,K]^T (both row-major bf16). Batched over blockIdx.z.
// OUTK: 0 = fp32 out, 1 = bf16 out, 2 = bf16 transposed out (C[n*ldc+m]).
template<int OUTK>
__global__ __launch_bounds__(256) void gemm_mfma(
    const u16* __restrict__ A, const u16* __restrict__ B, void* __restrict__ Cv,
    int K, int lda, int ldb, int ldc, long sA, long sB, long sC)
{
  __shared__ u16 At[3][4096];  // triple-buffered 128x32 tiles
  __shared__ u16 Bt[3][4096];
  const u16* Ab = A + (long)blockIdx.z * sA;
  const u16* Bb = B + (long)blockIdx.z * sB;
  const int tid = threadIdx.x;
  const int w = tid >> 6, lane = tid & 63;
  const int m0 = blockIdx.y * 128, n0 = blockIdx.x * 128;
  const int wm = (w >> 1) * 64, wn = (w & 1) * 64;
  const int fr = lane & 15, fq = lane >> 4;

  const int c0 = w * 2, c1 = w * 2 + 1;
  const int e0 = (c0 * 64 + lane) * 8, e1 = (c1 * 64 + lane) * 8;
  const int r0 = e0 >> 5, col0 = e0 & 31;
  const int r1 = e1 >> 5, col1 = e1 & 31;

  const int nk = K >> 5;
  auto issue = [&](int kc) {
    const int k0 = kc * 32;
    u16* at = At[kc % 3];
    u16* bt = Bt[kc % 3];
    GLDS(Ab + (long)(m0 + r0) * lda + k0 + col0, at + c0 * 512);
    GLDS(Bb + (long)(n0 + r0) * ldb + k0 + col0, bt + c0 * 512);
    GLDS(Ab + (long)(m0 + r1) * lda + k0 + col1, at + c1 * 512);
    GLDS(Bb + (long)(n0 + r1) * ldb + k0 + col1, bt + c1 * 512);
  };

  f32x4 acc[4][4] = {};
  issue(0);
  issue(1);
  vm_barrier<4>();
  for (int kc = 0; kc < nk; ++kc) {
    if (kc + 2 < nk) issue(kc + 2);
    const u16* at = At[kc % 3];
    const u16* bt = Bt[kc % 3];
    bf16x8 af[4], bfr[4];
#pragma unroll
    for (int i = 0; i < 4; ++i)
      af[i] = *(const bf16x8*)(at + (wm + i * 16 + fr) * 32 + fq * 8);
#pragma unroll
    for (int j = 0; j < 4; ++j)
      bfr[j] = *(const bf16x8*)(bt + (wn + j * 16 + fr) * 32 + fq * 8);
#pragma unroll
    for (int i = 0; i < 4; ++i)
#pragma unroll
      for (int j = 0; j < 4; ++j)
        acc[i][j] = MFMA(af[i], bfr[j], acc[i][j]);
    if (kc + 1 < nk) {
      if (kc + 2 < nk) vm_barrier<4>();
      else vm_barrier<0>();
    }
  }

  if (OUTK == 0) {
    float* C = (float*)Cv + (long)blockIdx.z * sC;
#pragma unroll
    for (int i = 0; i < 4; ++i)
#pragma unroll
      for (int j = 0; j < 4; ++j) {
        long base = (long)(m0 + wm + i * 16 + fq * 4) * ldc + (n0 + wn + j * 16 + fr);
#pragma unroll
        for (int r = 0; r < 4; ++r) C[base + (long)r * ldc] = acc[i][j][r];
      }
  } else if (OUTK == 1) {
    u16* C = (u16*)Cv + (long)blockIdx.z * sC;
#pragma unroll
    for (int i = 0; i < 4; ++i)
#pragma unroll
      for (int j = 0; j < 4; ++j) {
        long base = (long)(m0 + wm + i * 16 + fq * 4) * ldc + (n0 + wn + j * 16 + fr);
#pragma unroll
        for (int r = 0; r < 4; ++r) C[base + (long)r * ldc] = f2b(acc[i][j][r]);
      }
  } else {
    u16* C = (u16*)Cv + (long)blockIdx.z * sC;
#pragma unroll
    for (int i = 0; i < 4; ++i)
#pragma unroll
      for (int j = 0; j < 4; ++j) {
        ushort4 v = { f2b(acc[i][j][0]), f2b(acc[i][j][1]),
                      f2b(acc[i][j][2]), f2b(acc[i][j][3]) };
        *(ushort4*)(C + (long)(n0 + wn + j * 16 + fr) * ldc + (m0 + wm + i * 16 + fq * 4)) = v;
      }
  }
}

// ---------------- counter init (8 group counters) ----------------
__global__ void init_ctr(u32* ctr) {
  if (threadIdx.x < 8) ctr[threadIdx.x] = 0;
}

// ---------------- split-K flash attention, XCD-partitioned queue ------------
// 768 persistent blocks (3/CU). Block b belongs to group g = b&7 (XCD-aligned
// under the default round-robin dispatch) and only processes heads {g, g+8},
// so its V slices (2 x 524KB) + K (2.3MB) stay resident in that XCD's 4MB L2.
// Item = (hh, qt, kc): q-rows [qt*64,+64) of head g+8*hh vs K-tiles
// [4kc, min(4kc+4, ktt)). Writes raw-O partial (bf16) + per-row (m,l) stats.
// LDS = Ks 24 KiB + Ps 17 KiB = 41 KiB -> 3 blocks/CU. Register budget at
// 3 waves/SIMD = 168 (unified VGPR+AGPR): aq 72 + sc 32 + Oacc 32 + vA 8
// + addr ~12 = ~156 -> no spill (v5/v6 spilled with the 16-reg V ping-pong).
__global__ __launch_bounds__(256, 3) void attn_partial(
    const u16* __restrict__ qfb,   // [2048][16*576]
    const u16* __restrict__ kfb,   // [2048][576]
    const u16* __restrict__ vallT, // [16][128][2048]
    u32* __restrict__ ctr,         // [8]
    u16* __restrict__ pO,          // [1280][64][128]
    float* __restrict__ pS)        // [1280][64][2]
{
  __shared__ u16 Ks[3][4096];    // K chunks, [row 128][g'=g^(row&3)][8]
  __shared__ u16 Ps[4 * 2176];   // per-wave P, 16 rows x 136 stride
  __shared__ u32 cur;

  const int tid = threadIdx.x;
  const int w = tid >> 6, lane = tid & 63;
  const int fr = lane & 15, fq = lane >> 4;
  const float scale = 0.07216878364870323f;  // (DN+DR)^-0.5
  const int grp = (int)(blockIdx.x & 7);     // XCD-aligned head group
  u16* Psw = Ps + w * 2176;

  const int krow0 = (w * 2) * 16 + (lane >> 2);
  const int krow1 = (w * 2 + 1) * 16 + (lane >> 2);
  const int kg0 = (lane & 3) ^ (krow0 & 3);
  const int kg1 = (lane & 3) ^ (krow1 & 3);

  while (true) {
    if (tid == 0) cur = atomicAdd(&ctr[grp], 1u);
    __syncthreads();
    const u32 it = cur;
    if (it >= N_ITEMS_G) break;

    // decode group-local item (qt descending; within qt: kc asc, hh 0..1)
    int rem = (int)it, qt = 31, kc = 0, hh = 0;
    for (int q = 31; q >= 0; --q) {
      int cnt = nkc_of(q) * 2;
      if (rem < cnt) { qt = q; kc = rem >> 1; hh = rem & 1; break; }
      rem -= cnt;
    }
    const int h = grp + hh * 8;
    const u32 gslot = (u32)grp * N_ITEMS_G + it;   // global partial slot
    const int q0 = qt * 64;
    const int ktt = (qt >> 1) + 1;
    const int kt0 = kc * 4, kt1 = min(kt0 + 4, ktt);

    // Q fragments resident (A[m=fr][k=fq*8+j])
    bf16x8 aq[18];
    {
      const u16* qp = qfb + (long)(q0 + w * 16 + fr) * 9216 + h * 576 + fq * 8;
#pragma unroll
      for (int d = 0; d < 18; ++d) aq[d] = *(const bf16x8*)(qp + d * 32);
    }

    float m_run[4], l_run[4];
#pragma unroll
    for (int r = 0; r < 4; ++r) { m_run[r] = -1e30f; l_run[r] = 0.f; }
    f32x4 Oacc[8] = {};
    // per-lane V fragment base: frag(jv,ks) = vlane + k0 + jv*32768 + ks*32
    const u16* vlane = vallT + (long)h * 262144 + (long)fr * 2048 + fq * 8;

    auto issueK = [&](int kt, int c) {
      const int k0i = kt * 128, d0 = c * 32;
      u16* dst = Ks[c % 3];
      GLDS(kfb + (long)(k0i + krow0) * 576 + d0 + kg0 * 8, dst + (w * 2) * 512);
      GLDS(kfb + (long)(k0i + krow1) * 576 + d0 + kg1 * 8, dst + (w * 2 + 1) * 512);
    };

    issueK(kt0, 0);
    issueK(kt0, 1);

    for (int kt = kt0; kt < kt1; ++kt) {
      const int k0 = kt * 128;
      vm_barrier<2>();  // chunk0 landed block-wide (chunk1 in flight)

      f32x4 sc[8] = {};
#pragma unroll
      for (int d = 0; d < 18; ++d) {
        if (d + 2 < 18) issueK(kt, d + 2);
        const u16* kb = Ks[d % 3];
        __builtin_amdgcn_s_setprio(1);
#pragma unroll
        for (int j = 0; j < 8; ++j) {
          const int row = j * 16 + fr;
          bf16x8 b = *(const bf16x8*)(kb + row * 32 + ((fq ^ (row & 3)) * 8));
          sc[j] = MFMA(aq[d], b, sc[j]);
        }
        __builtin_amdgcn_s_setprio(0);
        if (d < 17) {
          if (d + 2 < 18) vm_barrier<2>();
          else vm_barrier<0>();
        }
      }
      // all waves done reading Ks for this tile; Ks bufs may be rewritten
      __builtin_amdgcn_s_barrier();

      // V (ks=0, jv=0..3) into the single 4-frag register buffer (latency
      // hidden under softmax), then prefetch next tile's first two K chunks.
      const u16* vk = vlane + k0;
      bf16x8 vA[4];
#pragma unroll
      for (int q = 0; q < 4; ++q)
        vA[q] = *(const bf16x8*)(vk + (long)q * 32768);
      if (kt + 1 < kt1) { issueK(kt + 1, 0); issueK(kt + 1, 1); }

      // wave-local online softmax
      const bool diag = (kt == ktt - 1);
#pragma unroll
      for (int r = 0; r < 4; ++r) {
        float mx = m_run[r];
#pragma unroll
        for (int j = 0; j < 8; ++j) {
          float s = sc[j][r] * scale;
          if (diag) {
            const int row = q0 + w * 16 + fq * 4 + r;
            const int col = k0 + j * 16 + fr;
            if (col > row) s = -1e30f;
          }
          sc[j][r] = s;
          mx = fmaxf(mx, s);
        }
        mx = fmaxf(mx, __shfl_xor(mx, 1));
        mx = fmaxf(mx, __shfl_xor(mx, 2));
        mx = fmaxf(mx, __shfl_xor(mx, 4));
        mx = fmaxf(mx, __shfl_xor(mx, 8));
        const float alpha = __expf(m_run[r] - mx);
        m_run[r] = mx;
        float sum = 0.f;
#pragma unroll
        for (int j = 0; j < 8; ++j) {
          float p = __expf(sc[j][r] - mx);
          sc[j][r] = p;
          sum += p;
        }
        sum += __shfl_xor(sum, 1);
        sum += __shfl_xor(sum, 2);
        sum += __shfl_xor(sum, 4);
        sum += __shfl_xor(sum, 8);
        l_run[r] = l_run[r] * alpha + sum;
#pragma unroll
        for (int jv = 0; jv < 8; ++jv) Oacc[jv][r] *= alpha;
#pragma unroll
        for (int j = 0; j < 8; ++j)
          Psw[(fq * 4 + r) * 136 + j * 16 + fr] = f2b(sc[j][r]);
      }

      // PV: O += P @ V^T.  Single vA buffer, refilled between half-groups:
      // {MFMA jv0-3} -> load jv4-7 -> {MFMA jv4-7} -> load next-ks jv0-3.
#pragma unroll
      for (int ks = 0; ks < 4; ++ks) {
        bf16x8 ap = *(const bf16x8*)(Psw + fr * 136 + ks * 32 + fq * 8);
        __builtin_amdgcn_s_setprio(1);
#pragma unroll
        for (int q = 0; q < 4; ++q) Oacc[q] = MFMA(ap, vA[q], Oacc[q]);
        __builtin_amdgcn_s_setprio(0);
#pragma unroll
        for (int q = 0; q < 4; ++q)
          vA[q] = *(const bf16x8*)(vk + (long)(q + 4) * 32768 + ks * 32);
        __builtin_amdgcn_s_setprio(1);
#pragma unroll
        for (int q = 0; q < 4; ++q) Oacc[q + 4] = MFMA(ap, vA[q], Oacc[q + 4]);
        __builtin_amdgcn_s_setprio(0);
        if (ks < 3) {
#pragma unroll
          for (int q = 0; q < 4; ++q)
            vA[q] = *(const bf16x8*)(vk + (long)q * 32768 + (ks + 1) * 32);
        }
      }
    }

    // write partial: raw O (bf16) + per-row stats
    const long po = (long)gslot * 8192;
#pragma unroll
    for (int r = 0; r < 4; ++r) {
      const int lr = w * 16 + fq * 4 + r;
      if (fr == 0) {
        pS[((long)gslot * 64 + lr) * 2] = m_run[r];
        pS[((long)gslot * 64 + lr) * 2 + 1] = l_run[r];
      }
#pragma unroll
      for (int jv = 0; jv < 8; ++jv)
        pO[po + (long)lr * 128 + jv * 16 + fr] = f2b(Oacc[jv][r]);
    }
  }
}

// ---------------- combine partials (log-sum-exp weights) ----------------
__global__ __launch_bounds__(256) void attn_reduce(
    const u16* __restrict__ pO, const float* __restrict__ pS,
    u16* __restrict__ ovb)
{
  const int h = blockIdx.x, qt = blockIdx.y;
  const int g = h & 7, hh = h >> 3;
  const int ktt = (qt >> 1) + 1;
  const int nkc = (ktt + 3) >> 2;
  int base = g * N_ITEMS_G;
  for (int q = qt + 1; q < 32; ++q) base += nkc_of(q) * 2;
  const int tid = threadIdx.x;
  const int r = tid >> 2, cq = (tid & 3) * 32;

  float m[4], l[4], wgt[4];
  float M = -1e30f;
  for (int i = 0; i < nkc; ++i) {
    const long slot = base + i * 2 + hh;
    m[i] = pS[(slot * 64 + r) * 2];
    l[i] = pS[(slot * 64 + r) * 2 + 1];
    M = fmaxf(M, m[i]);
  }
  float L = 0.f;
  for (int i = 0; i < nkc; ++i) { wgt[i] = __expf(m[i] - M); L += l[i] * wgt[i]; }
  const float inv = 1.0f / L;

  u16* orow = ovb + (long)(qt * 64 + r) * 2048 + h * 128 + cq;
  for (int c8 = 0; c8 < 32; c8 += 8) {
    float acc[8] = {};
    for (int i = 0; i < nkc; ++i) {
      const long slot = base + i * 2 + hh;
      const u16x8 v = *(const u16x8*)(pO + (slot * 64 + r) * 128 + cq + c8);
#pragma unroll
      for (int e = 0; e < 8; ++e) acc[e] += b2f(v[e]) * wgt[i];
    }
    u16x8 o;
#pragma unroll
    for (int e = 0; e < 8; ++e) o[e] = f2b(acc[e] * inv);
    *(u16x8*)(orow + c8) = o;
  }
}

// ---------------- conversion / transpose kernels ----------------
__global__ __launch_bounds__(256) void cast_bf16(const float* __restrict__ in,
                                                 u16* __restrict__ out, long n) {
  long i = ((long)blockIdx.x * 256 + threadIdx.x) * 4;
  if (i >= n) return;
  float4 v = *(const float4*)(in + i);
  ushort4 o = { f2b(v.x), f2b(v.y), f2b(v.z), f2b(v.w) };
  *(ushort4*)(out + i) = o;
}

__global__ __launch_bounds__(256) void transpose_cast(const float* __restrict__ in,
    u16* __restrict__ out, int ldi, int ldo, long sIn, long sOut) {
  in += (long)blockIdx.z * sIn;
  out += (long)blockIdx.z * sOut;
  __shared__ u16 t[32][33];
  const int i0 = blockIdx.y * 32, j0 = blockIdx.x * 32;
  const int tx = threadIdx.x & 31, ty = threadIdx.x >> 5;
  for (int r = ty; r < 32; r += 8)
    t[r][tx] = f2b(in[(long)(i0 + r) * ldi + j0 + tx]);
  __syncthreads();
  for (int r = ty; r < 32; r += 8)
    out[(long)(j0 + r) * ldo + i0 + tx] = t[tx][r];
}

// ---------------- RMSNorm fp32 (row stride ldin) -> bf16 ----------------
__global__ __launch_bounds__(256) void rmsnorm_cast(const float* __restrict__ in,
    const float* __restrict__ w, u16* __restrict__ out, int n, int ldin) {
  __shared__ float red[4];
  const float* row = in + (long)blockIdx.x * ldin;
  u16* orow = out + (long)blockIdx.x * n;
  float ss = 0.f;
  for (int i = threadIdx.x; i < n; i += 256) { float v = row[i]; ss += v * v; }
  float tot = block_sum(ss, red);
  float inv = rsqrtf(tot / (float)n + 1e-6f);
  for (int i = threadIdx.x; i < n; i += 256) orow[i] = f2b(row[i] * inv * w[i]);
}

// ---------------- RoPE table (double precision) ----------------
__global__ __launch_bounds__(256) void rope_table(float* tab) {
  int s = blockIdx.x * 8 + (threadIdx.x >> 5), j = threadIdx.x & 31;
  double freq = pow(10000.0, -(double)j / 32.0);
  double ang = (double)s * freq;
  tab[s * 64 + j] = (float)cos(ang);
  tab[s * 64 + 32 + j] = (float)sin(ang);
}

// ---------------- k_full: rmsnorm(ckv) ++ rope(k_pe) -> bf16 ----------------
// ckv points at col 1536 of the fused [2048][2176] f32 buffer.
__global__ __launch_bounds__(256) void build_kfull(const float* __restrict__ ckv,
    const float* __restrict__ lnw, const float* __restrict__ tab, u16* __restrict__ kfb) {
  __shared__ float red[4];
  const int s = blockIdx.x;
  const float* row = ckv + (long)s * 2176;
  float ss = 0.f;
  for (int i = threadIdx.x; i < 512; i += 256) { float v = row[i]; ss += v * v; }
  float tot = block_sum(ss, red);
  float inv = rsqrtf(tot / 512.0f + 1e-6f);
  u16* orow = kfb + (long)s * 576;
  for (int i = threadIdx.x; i < 512; i += 256) orow[i] = f2b(row[i] * inv * lnw[i]);
  if (threadIdx.x < 64) {
    int i = threadIdx.x, j = i & 31;
    float c = tab[s * 64 + j], sn = tab[s * 64 + 32 + j];
    float xv = row[512 + i];
    float rot = (i < 32) ? -row[512 + i + 32] : row[512 + i - 32];
    orow[512 + i] = f2b(xv * c + rot * sn);
  }
}

// ---------------- roped q_pe (bf16 in) into qfb[..., 512:576] ----------------
// grid 2048 x 256 threads: thread (h = t>>4, 4 i's).
__global__ __launch_bounds__(256) void rope_qpe(const u16* __restrict__ qb,
    const float* __restrict__ tab, u16* __restrict__ qfb) {
  const int s = blockIdx.x;
  const int h = threadIdx.x >> 4;
  const int i0 = (threadIdx.x & 15) * 4;
  const u16* src = qb + (long)s * 3072 + h * 192 + 128;
  u16* dst = qfb + (long)s * 9216 + h * 576 + 512;
#pragma unroll
  for (int k = 0; k < 4; ++k) {
    const int i = i0 + k, j = i & 31;
    float c = tab[s * 64 + j], sn = tab[s * 64 + 32 + j];
    float xv = b2f(src[i]);
    float rot = (i < 32) ? -b2f(src[i + 32]) : b2f(src[i - 32]);
    dst[i] = f2b(xv * c + rot * sn);
  }
}

extern "C" void kernel_launch(void* const* d_in, const int* in_sizes, int n_in,
                              void* d_out, int out_size, void* d_ws, size_t ws_size,
                              hipStream_t stream) {
  const float* x      = (const float*)d_in[0];
  const float* w_q_a  = (const float*)d_in[1];
  const float* q_ln   = (const float*)d_in[2];
  const float* w_q_b  = (const float*)d_in[3];
  const float* w_kv_a = (const float*)d_in[4];
  const float* kv_ln  = (const float*)d_in[5];
  const float* w_kv_b = (const float*)d_in[6];
  const float* w_o    = (const float*)d_in[7];
  float* out = (float*)d_out;

  // ---- fixed workspace (bytes) ----
  char* p = (char*)d_ws;
  float* tab   = (float*)p;  p += 524288;      // 2048*64 f32
  u16* wkvbb   = (u16*)p;    p += 4194304;     // 512*4096
  u16* wuvT    = (u16*)p;    p += 2097152;     // 16*128*512
  u16* woT     = (u16*)p;    p += 8388608;     // 2048*2048
  u16* qfb     = (u16*)p;    p += 37748736;    // 2048*9216
  u16* vallT   = (u16*)p;    p += 8388608;     // 16*128*2048
  u16* kfb     = (u16*)p;    p += 2359296;     // 2048*576
  u16* ovb     = (u16*)p;    p += 8388608;     // 2048*2048
  char* tb = p;
  // phase 1 transient:
  u16* xb      = (u16*)tb;                     // 2048*2048            (8.4 MB)
  u16* wabT    = (u16*)(tb + 8388608);         // 2176*2048 (qa++kva transposed)
  float* qac   = (float*)(tb + 17301504);      // 2048*2176 f32 (qa | ckv_kpe)
  u16* qab     = (u16*)(tb + 35127296);        // 2048*1536
  u16* wqbT    = (u16*)(tb + 41418752);        // 3072*1536
  u16* qb      = (u16*)(tb + 50855936);        // 2048*3072  (ends 63.4 MB)
  // phase 2 transient (aliases phase 1, used only after it is dead):
  u16* pO      = (u16*)tb;                     // 1280*64*128 bf16 (21 MB)
  float* pS    = (float*)(tb + 20971520);      // 1280*64*2 f32
  u32* ctr     = (u32*)(tb + 21626880);        // 8 group counters

  rope_table<<<dim3(256), 256, 0, stream>>>(tab);

  // weight prep
  cast_bf16<<<4096, 256, 0, stream>>>(x, xb, 4194304);
  transpose_cast<<<dim3(48, 64), 256, 0, stream>>>(w_q_a, wabT, 1536, 2048, 0, 0);
  transpose_cast<<<dim3(18, 64), 256, 0, stream>>>(w_kv_a, wabT + 1536 * 2048, 576, 2048, 0, 0);
  transpose_cast<<<dim3(96, 48), 256, 0, stream>>>(w_q_b, wqbT, 3072, 1536, 0, 0);
  cast_bf16<<<2048, 256, 0, stream>>>(w_kv_b, wkvbb, 2097152);
  transpose_cast<<<dim3(4, 16, 16), 256, 0, stream>>>(w_kv_b + 128, wuvT, 4096, 512, 256, 65536);
  transpose_cast<<<dim3(64, 64), 256, 0, stream>>>(w_o, woT, 2048, 2048, 0, 0);

  // fused: [q_a | ckv_kpe] = x @ [w_q_a | w_kv_a]  (f32, ldc 2176)
  gemm_mfma<0><<<dim3(17, 16), 256, 0, stream>>>(
      xb, wabT, qac, 2048, 2048, 2048, 2176, 0, 0, 0);
  rmsnorm_cast<<<2048, 256, 0, stream>>>(qac, q_ln, qab, 1536, 2176);
  build_kfull<<<2048, 256, 0, stream>>>(qac + 1536, kv_ln, tab, kfb);

  // q = q_a @ w_q_b (bf16 out)
  gemm_mfma<1><<<dim3(24, 16), 256, 0, stream>>>(
      qab, wqbT, qb, 1536, 1536, 1536, 3072, 0, 0, 0);

  // q_full[:, h, :512] = q_nope[h] @ w_uk[h]^T (bf16 out, batched over h)
  gemm_mfma<1><<<dim3(4, 16, 16), 256, 0, stream>>>(
      qb, wkvbb, qfb, 128, 3072, 4096, 9216, 192, 256, 576);
  rope_qpe<<<dim3(2048), 256, 0, stream>>>(qb, tab, qfb);

  // vallT[h] = (ckv_n @ w_uv[h])^T  (bf16 transposed out)
  gemm_mfma<2><<<dim3(1, 16, 16), 256, 0, stream>>>(
      kfb, wuvT, vallT, 512, 576, 512, 2048, 0, 65536, 262144);

  // split-K flash attention, XCD-partitioned dynamic queues (3 blocks/CU)
  init_ctr<<<1, 64, 0, stream>>>(ctr);
  attn_partial<<<dim3(768), 256, 0, stream>>>(qfb, kfb, vallT, ctr, pO, pS);
  attn_reduce<<<dim3(16, 32), 256, 0, stream>>>(pO, pS, ovb);

  // y = o_v @ w_o (f32 out)
  gemm_mfma<0><<<dim3(16, 16), 256, 0, stream>>>(
      ovb, woT, out, 2048, 2048, 2048, 2048, 0, 0, 0);
}

// Round 8
// 508.330 us; speedup vs baseline: 1.1930x; 1.1358x over previous
//
#include <hip/hip_runtime.h>
#include <math.h>

// DeepSeek V2 MLA attention — bf16 MFMA GEMMs + split-K flash attention with
// a dynamic work queue (v8). v8 = v7 with __launch_bounds__(256,2):
// the (256,3) cap (168 unified regs/wave) forced spills (VGPR_Count=84,
// WRITE_SIZE 277/209MB in v5-v7) AND never delivered 3 blocks/CU anyway
// (measured occupancy ~25% = 2 blocks/CU). At (256,2) the ~190-reg demand
// (aq 72 + sc 32 + Oacc 32 + vA/vB 16 + addr/state) fits spill-free.
// Keeps v6's XCD-partitioned queues (heads {g,g+8} per XCD -> V+K L2-resident,
// FETCH 292->160MB verified) + V-register-direct PV + cross-tile K prefetch.
// B=1 S=2048 E=2048 H=16 DN=128 DR=64 DV=128 R=512 QLR=1536

typedef unsigned short u16;
typedef unsigned int u32;
typedef __bf16 bf16x8 __attribute__((ext_vector_type(8)));
typedef float f32x4 __attribute__((ext_vector_type(4)));
typedef unsigned short u16x8 __attribute__((ext_vector_type(8)));

__device__ __forceinline__ u16 f2b(float f) {  // fp32 -> bf16 RNE
  u32 u = __float_as_uint(f);
  u += 0x7FFFu + ((u >> 16) & 1u);
  return (u16)(u >> 16);
}
__device__ __forceinline__ float b2f(u16 v) {
  return __uint_as_float(((u32)v) << 16);
}

#define GLDS(g, l) __builtin_amdgcn_global_load_lds( \
    (const __attribute__((address_space(1))) u32*)(g), \
    (__attribute__((address_space(3))) u32*)(l), 16, 0, 0)

#define MFMA(a, b, c) __builtin_amdgcn_mfma_f32_16x16x32_bf16(a, b, c, 0, 0, 0)

// s_waitcnt vmcnt(N) (lgkmcnt/expcnt untouched) + s_barrier.
template<int N>
__device__ __forceinline__ void vm_barrier() {
  __builtin_amdgcn_s_waitcnt(0xF70 | N);  // expcnt=7, lgkmcnt=15, vmcnt=N
  __builtin_amdgcn_s_barrier();
}

// Per-group (2 heads) items enumerated qt-descending (heavy first):
// for qt=31..0, kc=0..nkc-1, hh=0..1.  nkc(qt) = ceil((qt/2+1)/4).
// Per-group total = 160; global slot = g*160 + local.
#define N_ITEMS_G 160
__device__ __forceinline__ int nkc_of(int qt) { return (((qt >> 1) + 1) + 3) >> 2; }

// ---------------- block reduction helper ----------------
__device__ __forceinline__ float block_sum(float v, float* red) {
#pragma unroll
  for (int off = 32; off > 0; off >>= 1) v += __shfl_down(v, off);
  const int lane = threadIdx.x & 63, w = threadIdx.x >> 6;
  if (lane == 0) red[w] = v;
  __syncthreads();
  float r = red[0] + red[1] + red[2] + red[3];
  __syncthreads();
  return r;
}

// ---------------- bf16 MFMA GEMM, 128x128 tile, BK=32, pipelined ------------
// C = A[M,K] @ B[N,K]^T (both row-major bf16). Batched over blockIdx.z.
// OUTK: 0 = fp32 out, 1 = bf16 out, 2 = bf16 transposed out (C[n*ldc+m]).
template<int OUTK>
__global__ __launch_bounds__(256) void gemm_mfma(
    const u16* __restrict__ A, const u16* __restrict__ B, void* __restrict__ Cv,
    int K, int lda, int ldb, int ldc, long sA, long sB, long sC)
{
  __shared__ u16 At[3][4096];  // triple-buffered 128x32 tiles
  __shared__ u16 Bt[3][4096];
  const u16* Ab = A + (long)blockIdx.z * sA;
  const u16* Bb = B + (long)blockIdx.z * sB;
  const int tid = threadIdx.x;
  const int w = tid >> 6, lane = tid & 63;
  const int m0 = blockIdx.y * 128, n0 = blockIdx.x * 128;
  const int wm = (w >> 1) * 64, wn = (w & 1) * 64;
  const int fr = lane & 15, fq = lane >> 4;

  const int c0 = w * 2, c1 = w * 2 + 1;
  const int e0 = (c0 * 64 + lane) * 8, e1 = (c1 * 64 + lane) * 8;
  const int r0 = e0 >> 5, col0 = e0 & 31;
  const int r1 = e1 >> 5, col1 = e1 & 31;

  const int nk = K >> 5;
  auto issue = [&](int kc) {
    const int k0 = kc * 32;
    u16* at = At[kc % 3];
    u16* bt = Bt[kc % 3];
    GLDS(Ab + (long)(m0 + r0) * lda + k0 + col0, at + c0 * 512);
    GLDS(Bb + (long)(n0 + r0) * ldb + k0 + col0, bt + c0 * 512);
    GLDS(Ab + (long)(m0 + r1) * lda + k0 + col1, at + c1 * 512);
    GLDS(Bb + (long)(n0 + r1) * ldb + k0 + col1, bt + c1 * 512);
  };

  f32x4 acc[4][4] = {};
  issue(0);
  issue(1);
  vm_barrier<4>();
  for (int kc = 0; kc < nk; ++kc) {
    if (kc + 2 < nk) issue(kc + 2);
    const u16* at = At[kc % 3];
    const u16* bt = Bt[kc % 3];
    bf16x8 af[4], bfr[4];
#pragma unroll
    for (int i = 0; i < 4; ++i)
      af[i] = *(const bf16x8*)(at + (wm + i * 16 + fr) * 32 + fq * 8);
#pragma unroll
    for (int j = 0; j < 4; ++j)
      bfr[j] = *(const bf16x8*)(bt + (wn + j * 16 + fr) * 32 + fq * 8);
#pragma unroll
    for (int i = 0; i < 4; ++i)
#pragma unroll
      for (int j = 0; j < 4; ++j)
        acc[i][j] = MFMA(af[i], bfr[j], acc[i][j]);
    if (kc + 1 < nk) {
      if (kc + 2 < nk) vm_barrier<4>();
      else vm_barrier<0>();
    }
  }

  if (OUTK == 0) {
    float* C = (float*)Cv + (long)blockIdx.z * sC;
#pragma unroll
    for (int i = 0; i < 4; ++i)
#pragma unroll
      for (int j = 0; j < 4; ++j) {
        long base = (long)(m0 + wm + i * 16 + fq * 4) * ldc + (n0 + wn + j * 16 + fr);
#pragma unroll
        for (int r = 0; r < 4; ++r) C[base + (long)r * ldc] = acc[i][j][r];
      }
  } else if (OUTK == 1) {
    u16* C = (u16*)Cv + (long)blockIdx.z * sC;
#pragma unroll
    for (int i = 0; i < 4; ++i)
#pragma unroll
      for (int j = 0; j < 4; ++j) {
        long base = (long)(m0 + wm + i * 16 + fq * 4) * ldc + (n0 + wn + j * 16 + fr);
#pragma unroll
        for (int r = 0; r < 4; ++r) C[base + (long)r * ldc] = f2b(acc[i][j][r]);
      }
  } else {
    u16* C = (u16*)Cv + (long)blockIdx.z * sC;
#pragma unroll
    for (int i = 0; i < 4; ++i)
#pragma unroll
      for (int j = 0; j < 4; ++j) {
        ushort4 v = { f2b(acc[i][j][0]), f2b(acc[i][j][1]),
                      f2b(acc[i][j][2]), f2b(acc[i][j][3]) };
        *(ushort4*)(C + (long)(n0 + wn + j * 16 + fr) * ldc + (m0 + wm + i * 16 + fq * 4)) = v;
      }
  }
}

// ---------------- counter init (8 group counters) ----------------
__global__ void init_ctr(u32* ctr) {
  if (threadIdx.x < 8) ctr[threadIdx.x] = 0;
}

// ---------------- split-K flash attention, XCD-partitioned queue ------------
// 768 persistent blocks (2/CU resident). Block b belongs to group g = b&7
// (XCD-aligned under round-robin dispatch) and only processes heads {g, g+8},
// so its V slices (2 x 524KB) + K (2.3MB) stay resident in that XCD's 4MB L2.
// Item = (hh, qt, kc): q-rows [qt*64,+64) of head g+8*hh vs K-tiles
// [4kc, min(4kc+4, ktt)). Writes raw-O partial (bf16) + per-row (m,l) stats.
// LDS = Ks 24 KiB + Ps 17 KiB = 41 KiB. __launch_bounds__(256,2): 256 unified
// regs/wave — the ~190-reg demand fits with ZERO spill (the (256,3)/168-cap
// variants spilled aq -> 200+MB of deterministic scratch HBM traffic).
__global__ __launch_bounds__(256, 2) void attn_partial(
    const u16* __restrict__ qfb,   // [2048][16*576]
    const u16* __restrict__ kfb,   // [2048][576]
    const u16* __restrict__ vallT, // [16][128][2048]
    u32* __restrict__ ctr,         // [8]
    u16* __restrict__ pO,          // [1280][64][128]
    float* __restrict__ pS)        // [1280][64][2]
{
  __shared__ u16 Ks[3][4096];    // K chunks, [row 128][g'=g^(row&3)][8]
  __shared__ u16 Ps[4 * 2176];   // per-wave P, 16 rows x 136 stride
  __shared__ u32 cur;

  const int tid = threadIdx.x;
  const int w = tid >> 6, lane = tid & 63;
  const int fr = lane & 15, fq = lane >> 4;
  const float scale = 0.07216878364870323f;  // (DN+DR)^-0.5
  const int grp = (int)(blockIdx.x & 7);     // XCD-aligned head group
  u16* Psw = Ps + w * 2176;

  const int krow0 = (w * 2) * 16 + (lane >> 2);
  const int krow1 = (w * 2 + 1) * 16 + (lane >> 2);
  const int kg0 = (lane & 3) ^ (krow0 & 3);
  const int kg1 = (lane & 3) ^ (krow1 & 3);

  while (true) {
    if (tid == 0) cur = atomicAdd(&ctr[grp], 1u);
    __syncthreads();
    const u32 it = cur;
    if (it >= N_ITEMS_G) break;

    // decode group-local item (qt descending; within qt: kc asc, hh 0..1)
    int rem = (int)it, qt = 31, kc = 0, hh = 0;
    for (int q = 31; q >= 0; --q) {
      int cnt = nkc_of(q) * 2;
      if (rem < cnt) { qt = q; kc = rem >> 1; hh = rem & 1; break; }
      rem -= cnt;
    }
    const int h = grp + hh * 8;
    const u32 gslot = (u32)grp * N_ITEMS_G + it;   // global partial slot
    const int q0 = qt * 64;
    const int ktt = (qt >> 1) + 1;
    const int kt0 = kc * 4, kt1 = min(kt0 + 4, ktt);

    // Q fragments resident (A[m=fr][k=fq*8+j])
    bf16x8 aq[18];
    {
      const u16* qp = qfb + (long)(q0 + w * 16 + fr) * 9216 + h * 576 + fq * 8;
#pragma unroll
      for (int d = 0; d < 18; ++d) aq[d] = *(const bf16x8*)(qp + d * 32);
    }

    float m_run[4], l_run[4];
#pragma unroll
    for (int r = 0; r < 4; ++r) { m_run[r] = -1e30f; l_run[r] = 0.f; }
    f32x4 Oacc[8] = {};
    // per-lane V fragment base: frag(jv,ks) = vlane + k0 + jv*32768 + ks*32
    const u16* vlane = vallT + (long)h * 262144 + (long)fr * 2048 + fq * 8;

    auto issueK = [&](int kt, int c) {
      const int k0i = kt * 128, d0 = c * 32;
      u16* dst = Ks[c % 3];
      GLDS(kfb + (long)(k0i + krow0) * 576 + d0 + kg0 * 8, dst + (w * 2) * 512);
      GLDS(kfb + (long)(k0i + krow1) * 576 + d0 + kg1 * 8, dst + (w * 2 + 1) * 512);
    };

    issueK(kt0, 0);
    issueK(kt0, 1);

    for (int kt = kt0; kt < kt1; ++kt) {
      const int k0 = kt * 128;
      vm_barrier<2>();  // chunk0 landed block-wide (chunk1 in flight)

      f32x4 sc[8] = {};
#pragma unroll
      for (int d = 0; d < 18; ++d) {
        if (d + 2 < 18) issueK(kt, d + 2);
        const u16* kb = Ks[d % 3];
        __builtin_amdgcn_s_setprio(1);
#pragma unroll
        for (int j = 0; j < 8; ++j) {
          const int row = j * 16 + fr;
          bf16x8 b = *(const bf16x8*)(kb + row * 32 + ((fq ^ (row & 3)) * 8));
          sc[j] = MFMA(aq[d], b, sc[j]);
        }
        __builtin_amdgcn_s_setprio(0);
        if (d < 17) {
          if (d + 2 < 18) vm_barrier<2>();
          else vm_barrier<0>();
        }
      }
      // all waves done reading Ks for this tile; Ks bufs may be rewritten
      __builtin_amdgcn_s_barrier();

      // V ks-group 0 into the dual register buffers (latency hidden under
      // softmax), then prefetch next tile's first two K chunks.
      const u16* vk = vlane + k0;
      bf16x8 vA[4], vB[4];
#pragma unroll
      for (int q = 0; q < 4; ++q) {
        vA[q] = *(const bf16x8*)(vk + (long)q * 32768);
        vB[q] = *(const bf16x8*)(vk + (long)(q + 4) * 32768);
      }
      if (kt + 1 < kt1) { issueK(kt + 1, 0); issueK(kt + 1, 1); }

      // wave-local online softmax
      const bool diag = (kt == ktt - 1);
#pragma unroll
      for (int r = 0; r < 4; ++r) {
        float mx = m_run[r];
#pragma unroll
        for (int j = 0; j < 8; ++j) {
          float s = sc[j][r] * scale;
          if (diag) {
            const int row = q0 + w * 16 + fq * 4 + r;
            const int col = k0 + j * 16 + fr;
            if (col > row) s = -1e30f;
          }
          sc[j][r] = s;
          mx = fmaxf(mx, s);
        }
        mx = fmaxf(mx, __shfl_xor(mx, 1));
        mx = fmaxf(mx, __shfl_xor(mx, 2));
        mx = fmaxf(mx, __shfl_xor(mx, 4));
        mx = fmaxf(mx, __shfl_xor(mx, 8));
        const float alpha = __expf(m_run[r] - mx);
        m_run[r] = mx;
        float sum = 0.f;
#pragma unroll
        for (int j = 0; j < 8; ++j) {
          float p = __expf(sc[j][r] - mx);
          sc[j][r] = p;
          sum += p;
        }
        sum += __shfl_xor(sum, 1);
        sum += __shfl_xor(sum, 2);
        sum += __shfl_xor(sum, 4);
        sum += __shfl_xor(sum, 8);
        l_run[r] = l_run[r] * alpha + sum;
#pragma unroll
        for (int jv = 0; jv < 8; ++jv) Oacc[jv][r] *= alpha;
#pragma unroll
        for (int j = 0; j < 8; ++j)
          Psw[(fq * 4 + r) * 136 + j * 16 + fr] = f2b(sc[j][r]);
      }

      // PV: O += P @ V^T, V fragments ping-ponged from global (no barrier)
#pragma unroll
      for (int ks = 0; ks < 4; ++ks) {
        bf16x8 ap = *(const bf16x8*)(Psw + fr * 136 + ks * 32 + fq * 8);
        __builtin_amdgcn_s_setprio(1);
#pragma unroll
        for (int q = 0; q < 4; ++q) Oacc[q] = MFMA(ap, vA[q], Oacc[q]);
        __builtin_amdgcn_s_setprio(0);
        if (ks < 3) {
#pragma unroll
          for (int q = 0; q < 4; ++q)
            vA[q] = *(const bf16x8*)(vk + (long)q * 32768 + (ks + 1) * 32);
        }
        __builtin_amdgcn_s_setprio(1);
#pragma unroll
        for (int q = 0; q < 4; ++q) Oacc[q + 4] = MFMA(ap, vB[q], Oacc[q + 4]);
        __builtin_amdgcn_s_setprio(0);
        if (ks < 3) {
#pragma unroll
          for (int q = 0; q < 4; ++q)
            vB[q] = *(const bf16x8*)(vk + (long)(q + 4) * 32768 + (ks + 1) * 32);
        }
      }
    }

    // write partial: raw O (bf16) + per-row stats
    const long po = (long)gslot * 8192;
#pragma unroll
    for (int r = 0; r < 4; ++r) {
      const int lr = w * 16 + fq * 4 + r;
      if (fr == 0) {
        pS[((long)gslot * 64 + lr) * 2] = m_run[r];
        pS[((long)gslot * 64 + lr) * 2 + 1] = l_run[r];
      }
#pragma unroll
      for (int jv = 0; jv < 8; ++jv)
        pO[po + (long)lr * 128 + jv * 16 + fr] = f2b(Oacc[jv][r]);
    }
  }
}

// ---------------- combine partials (log-sum-exp weights) ----------------
__global__ __launch_bounds__(256) void attn_reduce(
    const u16* __restrict__ pO, const float* __restrict__ pS,
    u16* __restrict__ ovb)
{
  const int h = blockIdx.x, qt = blockIdx.y;
  const int g = h & 7, hh = h >> 3;
  const int ktt = (qt >> 1) + 1;
  const int nkc = (ktt + 3) >> 2;
  int base = g * N_ITEMS_G;
  for (int q = qt + 1; q < 32; ++q) base += nkc_of(q) * 2;
  const int tid = threadIdx.x;
  const int r = tid >> 2, cq = (tid & 3) * 32;

  float m[4], l[4], wgt[4];
  float M = -1e30f;
  for (int i = 0; i < nkc; ++i) {
    const long slot = base + i * 2 + hh;
    m[i] = pS[(slot * 64 + r) * 2];
    l[i] = pS[(slot * 64 + r) * 2 + 1];
    M = fmaxf(M, m[i]);
  }
  float L = 0.f;
  for (int i = 0; i < nkc; ++i) { wgt[i] = __expf(m[i] - M); L += l[i] * wgt[i]; }
  const float inv = 1.0f / L;

  u16* orow = ovb + (long)(qt * 64 + r) * 2048 + h * 128 + cq;
  for (int c8 = 0; c8 < 32; c8 += 8) {
    float acc[8] = {};
    for (int i = 0; i < nkc; ++i) {
      const long slot = base + i * 2 + hh;
      const u16x8 v = *(const u16x8*)(pO + (slot * 64 + r) * 128 + cq + c8);
#pragma unroll
      for (int e = 0; e < 8; ++e) acc[e] += b2f(v[e]) * wgt[i];
    }
    u16x8 o;
#pragma unroll
    for (int e = 0; e < 8; ++e) o[e] = f2b(acc[e] * inv);
    *(u16x8*)(orow + c8) = o;
  }
}

// ---------------- conversion / transpose kernels ----------------
__global__ __launch_bounds__(256) void cast_bf16(const float* __restrict__ in,
                                                 u16* __restrict__ out, long n) {
  long i = ((long)blockIdx.x * 256 + threadIdx.x) * 4;
  if (i >= n) return;
  float4 v = *(const float4*)(in + i);
  ushort4 o = { f2b(v.x), f2b(v.y), f2b(v.z), f2b(v.w) };
  *(ushort4*)(out + i) = o;
}

__global__ __launch_bounds__(256) void transpose_cast(const float* __restrict__ in,
    u16* __restrict__ out, int ldi, int ldo, long sIn, long sOut) {
  in += (long)blockIdx.z * sIn;
  out += (long)blockIdx.z * sOut;
  __shared__ u16 t[32][33];
  const int i0 = blockIdx.y * 32, j0 = blockIdx.x * 32;
  const int tx = threadIdx.x & 31, ty = threadIdx.x >> 5;
  for (int r = ty; r < 32; r += 8)
    t[r][tx] = f2b(in[(long)(i0 + r) * ldi + j0 + tx]);
  __syncthreads();
  for (int r = ty; r < 32; r += 8)
    out[(long)(j0 + r) * ldo + i0 + tx] = t[tx][r];
}

// ---------------- RMSNorm fp32 (row stride ldin) -> bf16 ----------------
__global__ __launch_bounds__(256) void rmsnorm_cast(const float* __restrict__ in,
    const float* __restrict__ w, u16* __restrict__ out, int n, int ldin) {
  __shared__ float red[4];
  const float* row = in + (long)blockIdx.x * ldin;
  u16* orow = out + (long)blockIdx.x * n;
  float ss = 0.f;
  for (int i = threadIdx.x; i < n; i += 256) { float v = row[i]; ss += v * v; }
  float tot = block_sum(ss, red);
  float inv = rsqrtf(tot / (float)n + 1e-6f);
  for (int i = threadIdx.x; i < n; i += 256) orow[i] = f2b(row[i] * inv * w[i]);
}

// ---------------- RoPE table (double precision) ----------------
__global__ __launch_bounds__(256) void rope_table(float* tab) {
  int s = blockIdx.x * 8 + (threadIdx.x >> 5), j = threadIdx.x & 31;
  double freq = pow(10000.0, -(double)j / 32.0);
  double ang = (double)s * freq;
  tab[s * 64 + j] = (float)cos(ang);
  tab[s * 64 + 32 + j] = (float)sin(ang);
}

// ---------------- k_full: rmsnorm(ckv) ++ rope(k_pe) -> bf16 ----------------
// ckv points at col 1536 of the fused [2048][2176] f32 buffer.
__global__ __launch_bounds__(256) void build_kfull(const float* __restrict__ ckv,
    const float* __restrict__ lnw, const float* __restrict__ tab, u16* __restrict__ kfb) {
  __shared__ float red[4];
  const int s = blockIdx.x;
  const float* row = ckv + (long)s * 2176;
  float ss = 0.f;
  for (int i = threadIdx.x; i < 512; i += 256) { float v = row[i]; ss += v * v; }
  float tot = block_sum(ss, red);
  float inv = rsqrtf(tot / 512.0f + 1e-6f);
  u16* orow = kfb + (long)s * 576;
  for (int i = threadIdx.x; i < 512; i += 256) orow[i] = f2b(row[i] * inv * lnw[i]);
  if (threadIdx.x < 64) {
    int i = threadIdx.x, j = i & 31;
    float c = tab[s * 64 + j], sn = tab[s * 64 + 32 + j];
    float xv = row[512 + i];
    float rot = (i < 32) ? -row[512 + i + 32] : row[512 + i - 32];
    orow[512 + i] = f2b(xv * c + rot * sn);
  }
}

// ---------------- roped q_pe (bf16 in) into qfb[..., 512:576] ----------------
// grid 2048 x 256 threads: thread (h = t>>4, 4 i's).
__global__ __launch_bounds__(256) void rope_qpe(const u16* __restrict__ qb,
    const float* __restrict__ tab, u16* __restrict__ qfb) {
  const int s = blockIdx.x;
  const int h = threadIdx.x >> 4;
  const int i0 = (threadIdx.x & 15) * 4;
  const u16* src = qb + (long)s * 3072 + h * 192 + 128;
  u16* dst = qfb + (long)s * 9216 + h * 576 + 512;
#pragma unroll
  for (int k = 0; k < 4; ++k) {
    const int i = i0 + k, j = i & 31;
    float c = tab[s * 64 + j], sn = tab[s * 64 + 32 + j];
    float xv = b2f(src[i]);
    float rot = (i < 32) ? -b2f(src[i + 32]) : b2f(src[i - 32]);
    dst[i] = f2b(xv * c + rot * sn);
  }
}

extern "C" void kernel_launch(void* const* d_in, const int* in_sizes, int n_in,
                              void* d_out, int out_size, void* d_ws, size_t ws_size,
                              hipStream_t stream) {
  const float* x      = (const float*)d_in[0];
  const float* w_q_a  = (const float*)d_in[1];
  const float* q_ln   = (const float*)d_in[2];
  const float* w_q_b  = (const float*)d_in[3];
  const float* w_kv_a = (const float*)d_in[4];
  const float* kv_ln  = (const float*)d_in[5];
  const float* w_kv_b = (const float*)d_in[6];
  const float* w_o    = (const float*)d_in[7];
  float* out = (float*)d_out;

  // ---- fixed workspace (bytes) ----
  char* p = (char*)d_ws;
  float* tab   = (float*)p;  p += 524288;      // 2048*64 f32
  u16* wkvbb   = (u16*)p;    p += 4194304;     // 512*4096
  u16* wuvT    = (u16*)p;    p += 2097152;     // 16*128*512
  u16* woT     = (u16*)p;    p += 8388608;     // 2048*2048
  u16* qfb     = (u16*)p;    p += 37748736;    // 2048*9216
  u16* vallT   = (u16*)p;    p += 8388608;     // 16*128*2048
  u16* kfb     = (u16*)p;    p += 2359296;     // 2048*576
  u16* ovb     = (u16*)p;    p += 8388608;     // 2048*2048
  char* tb = p;
  // phase 1 transient:
  u16* xb      = (u16*)tb;                     // 2048*2048            (8.4 MB)
  u16* wabT    = (u16*)(tb + 8388608);         // 2176*2048 (qa++kva transposed)
  float* qac   = (float*)(tb + 17301504);      // 2048*2176 f32 (qa | ckv_kpe)
  u16* qab     = (u16*)(tb + 35127296);        // 2048*1536
  u16* wqbT    = (u16*)(tb + 41418752);        // 3072*1536
  u16* qb      = (u16*)(tb + 50855936);        // 2048*3072  (ends 63.4 MB)
  // phase 2 transient (aliases phase 1, used only after it is dead):
  u16* pO      = (u16*)tb;                     // 1280*64*128 bf16 (21 MB)
  float* pS    = (float*)(tb + 20971520);      // 1280*64*2 f32
  u32* ctr     = (u32*)(tb + 21626880);        // 8 group counters

  rope_table<<<dim3(256), 256, 0, stream>>>(tab);

  // weight prep
  cast_bf16<<<4096, 256, 0, stream>>>(x, xb, 4194304);
  transpose_cast<<<dim3(48, 64), 256, 0, stream>>>(w_q_a, wabT, 1536, 2048, 0, 0);
  transpose_cast<<<dim3(18, 64), 256, 0, stream>>>(w_kv_a, wabT + 1536 * 2048, 576, 2048, 0, 0);
  transpose_cast<<<dim3(96, 48), 256, 0, stream>>>(w_q_b, wqbT, 3072, 1536, 0, 0);
  cast_bf16<<<2048, 256, 0, stream>>>(w_kv_b, wkvbb, 2097152);
  transpose_cast<<<dim3(4, 16, 16), 256, 0, stream>>>(w_kv_b + 128, wuvT, 4096, 512, 256, 65536);
  transpose_cast<<<dim3(64, 64), 256, 0, stream>>>(w_o, woT, 2048, 2048, 0, 0);

  // fused: [q_a | ckv_kpe] = x @ [w_q_a | w_kv_a]  (f32, ldc 2176)
  gemm_mfma<0><<<dim3(17, 16), 256, 0, stream>>>(
      xb, wabT, qac, 2048, 2048, 2048, 2176, 0, 0, 0);
  rmsnorm_cast<<<2048, 256, 0, stream>>>(qac, q_ln, qab, 1536, 2176);
  build_kfull<<<2048, 256, 0, stream>>>(qac + 1536, kv_ln, tab, kfb);

  // q = q_a @ w_q_b (bf16 out)
  gemm_mfma<1><<<dim3(24, 16), 256, 0, stream>>>(
      qab, wqbT, qb, 1536, 1536, 1536, 3072, 0, 0, 0);

  // q_full[:, h, :512] = q_nope[h] @ w_uk[h]^T (bf16 out, batched over h)
  gemm_mfma<1><<<dim3(4, 16, 16), 256, 0, stream>>>(
      qb, wkvbb, qfb, 128, 3072, 4096, 9216, 192, 256, 576);
  rope_qpe<<<dim3(2048), 256, 0, stream>>>(qb, tab, qfb);

  // vallT[h] = (ckv_n @ w_uv[h])^T  (bf16 transposed out)
  gemm_mfma<2><<<dim3(1, 16, 16), 256, 0, stream>>>(
      kfb, wuvT, vallT, 512, 576, 512, 2048, 0, 65536, 262144);

  // split-K flash attention, XCD-partitioned dynamic queues (2 blocks/CU)
  init_ctr<<<1, 64, 0, stream>>>(ctr);
  attn_partial<<<dim3(768), 256, 0, stream>>>(qfb, kfb, vallT, ctr, pO, pS);
  attn_reduce<<<dim3(16, 32), 256, 0, stream>>>(pO, pS, ovb);

  // y = o_v @ w_o (f32 out)
  gemm_mfma<0><<<dim3(16, 16), 256, 0, stream>>>(
      ovb, woT, out, 2048, 2048, 2048, 2048, 0, 0, 0);
}

// Round 9
// 498.951 us; speedup vs baseline: 1.2154x; 1.0188x over previous
//
#include <hip/hip_runtime.h>
#include <math.h>

// DeepSeek V2 MLA attention — bf16 MFMA GEMMs + split-K flash attention with
// a dynamic work queue (v9). v9 = v8 + K-staging restructure: v8 fixed spill
// (VGPR 128, WRITE 21MB) and L2 locality (FETCH 38MB) but stalled on ~19
// block-wide barriers per K-tile at 2 waves/SIMD (MfmaUtil 11%, all pipes
// idle). Now K is staged in 9 x 64-k groups (triple-buffered, 48KB) with ONE
// vm_barrier<4> per group -> 9 barriers/tile, 16 MFMAs + 2x prefetch distance
// per barrier interval. Running buffer index mod 3 (9%3==0) makes cross-tile
// prefetch seamless (no end-of-tile s_barrier).
// B=1 S=2048 E=2048 H=16 DN=128 DR=64 DV=128 R=512 QLR=1536

typedef unsigned short u16;
typedef unsigned int u32;
typedef __bf16 bf16x8 __attribute__((ext_vector_type(8)));
typedef float f32x4 __attribute__((ext_vector_type(4)));
typedef unsigned short u16x8 __attribute__((ext_vector_type(8)));

__device__ __forceinline__ u16 f2b(float f) {  // fp32 -> bf16 RNE
  u32 u = __float_as_uint(f);
  u += 0x7FFFu + ((u >> 16) & 1u);
  return (u16)(u >> 16);
}
__device__ __forceinline__ float b2f(u16 v) {
  return __uint_as_float(((u32)v) << 16);
}

#define GLDS(g, l) __builtin_amdgcn_global_load_lds( \
    (const __attribute__((address_space(1))) u32*)(g), \
    (__attribute__((address_space(3))) u32*)(l), 16, 0, 0)

#define MFMA(a, b, c) __builtin_amdgcn_mfma_f32_16x16x32_bf16(a, b, c, 0, 0, 0)

// s_waitcnt vmcnt(N) (lgkmcnt/expcnt untouched) + s_barrier.
template<int N>
__device__ __forceinline__ void vm_barrier() {
  __builtin_amdgcn_s_waitcnt(0xF70 | N);  // expcnt=7, lgkmcnt=15, vmcnt=N
  __builtin_amdgcn_s_barrier();
}

// Per-group (2 heads) items enumerated qt-descending (heavy first):
// for qt=31..0, kc=0..nkc-1, hh=0..1.  nkc(qt) = ceil((qt/2+1)/4).
// Per-group total = 160; global slot = g*160 + local.
#define N_ITEMS_G 160
__device__ __forceinline__ int nkc_of(int qt) { return (((qt >> 1) + 1) + 3) >> 2; }

// ---------------- block reduction helper ----------------
__device__ __forceinline__ float block_sum(float v, float* red) {
#pragma unroll
  for (int off = 32; off > 0; off >>= 1) v += __shfl_down(v, off);
  const int lane = threadIdx.x & 63, w = threadIdx.x >> 6;
  if (lane == 0) red[w] = v;
  __syncthreads();
  float r = red[0] + red[1] + red[2] + red[3];
  __syncthreads();
  return r;
}

// ---------------- bf16 MFMA GEMM, 128x128 tile, BK=32, pipelined ------------
// C = A[M,K] @ B[N,K]^T (both row-major bf16). Batched over blockIdx.z.
// OUTK: 0 = fp32 out, 1 = bf16 out, 2 = bf16 transposed out (C[n*ldc+m]).
template<int OUTK>
__global__ __launch_bounds__(256) void gemm_mfma(
    const u16* __restrict__ A, const u16* __restrict__ B, void* __restrict__ Cv,
    int K, int lda, int ldb, int ldc, long sA, long sB, long sC)
{
  __shared__ u16 At[3][4096];  // triple-buffered 128x32 tiles
  __shared__ u16 Bt[3][4096];
  const u16* Ab = A + (long)blockIdx.z * sA;
  const u16* Bb = B + (long)blockIdx.z * sB;
  const int tid = threadIdx.x;
  const int w = tid >> 6, lane = tid & 63;
  const int m0 = blockIdx.y * 128, n0 = blockIdx.x * 128;
  const int wm = (w >> 1) * 64, wn = (w & 1) * 64;
  const int fr = lane & 15, fq = lane >> 4;

  const int c0 = w * 2, c1 = w * 2 + 1;
  const int e0 = (c0 * 64 + lane) * 8, e1 = (c1 * 64 + lane) * 8;
  const int r0 = e0 >> 5, col0 = e0 & 31;
  const int r1 = e1 >> 5, col1 = e1 & 31;

  const int nk = K >> 5;
  auto issue = [&](int kc) {
    const int k0 = kc * 32;
    u16* at = At[kc % 3];
    u16* bt = Bt[kc % 3];
    GLDS(Ab + (long)(m0 + r0) * lda + k0 + col0, at + c0 * 512);
    GLDS(Bb + (long)(n0 + r0) * ldb + k0 + col0, bt + c0 * 512);
    GLDS(Ab + (long)(m0 + r1) * lda + k0 + col1, at + c1 * 512);
    GLDS(Bb + (long)(n0 + r1) * ldb + k0 + col1, bt + c1 * 512);
  };

  f32x4 acc[4][4] = {};
  issue(0);
  issue(1);
  vm_barrier<4>();
  for (int kc = 0; kc < nk; ++kc) {
    if (kc + 2 < nk) issue(kc + 2);
    const u16* at = At[kc % 3];
    const u16* bt = Bt[kc % 3];
    bf16x8 af[4], bfr[4];
#pragma unroll
    for (int i = 0; i < 4; ++i)
      af[i] = *(const bf16x8*)(at + (wm + i * 16 + fr) * 32 + fq * 8);
#pragma unroll
    for (int j = 0; j < 4; ++j)
      bfr[j] = *(const bf16x8*)(bt + (wn + j * 16 + fr) * 32 + fq * 8);
#pragma unroll
    for (int i = 0; i < 4; ++i)
#pragma unroll
      for (int j = 0; j < 4; ++j)
        acc[i][j] = MFMA(af[i], bfr[j], acc[i][j]);
    if (kc + 1 < nk) {
      if (kc + 2 < nk) vm_barrier<4>();
      else vm_barrier<0>();
    }
  }

  if (OUTK == 0) {
    float* C = (float*)Cv + (long)blockIdx.z * sC;
#pragma unroll
    for (int i = 0; i < 4; ++i)
#pragma unroll
      for (int j = 0; j < 4; ++j) {
        long base = (long)(m0 + wm + i * 16 + fq * 4) * ldc + (n0 + wn + j * 16 + fr);
#pragma unroll
        for (int r = 0; r < 4; ++r) C[base + (long)r * ldc] = acc[i][j][r];
      }
  } else if (OUTK == 1) {
    u16* C = (u16*)Cv + (long)blockIdx.z * sC;
#pragma unroll
    for (int i = 0; i < 4; ++i)
#pragma unroll
      for (int j = 0; j < 4; ++j) {
        long base = (long)(m0 + wm + i * 16 + fq * 4) * ldc + (n0 + wn + j * 16 + fr);
#pragma unroll
        for (int r = 0; r < 4; ++r) C[base + (long)r * ldc] = f2b(acc[i][j][r]);
      }
  } else {
    u16* C = (u16*)Cv + (long)blockIdx.z * sC;
#pragma unroll
    for (int i = 0; i < 4; ++i)
#pragma unroll
      for (int j = 0; j < 4; ++j) {
        ushort4 v = { f2b(acc[i][j][0]), f2b(acc[i][j][1]),
                      f2b(acc[i][j][2]), f2b(acc[i][j][3]) };
        *(ushort4*)(C + (long)(n0 + wn + j * 16 + fr) * ldc + (m0 + wm + i * 16 + fq * 4)) = v;
      }
  }
}

// ---------------- counter init (8 group counters) ----------------
__global__ void init_ctr(u32* ctr) {
  if (threadIdx.x < 8) ctr[threadIdx.x] = 0;
}

// ---------------- split-K flash attention, XCD-partitioned queue ------------
// 768 persistent blocks (2/CU resident). Block b -> group g = b&7 (XCD-aligned
// under round-robin dispatch), processes heads {g, g+8} only; V (2x524KB) +
// K (2.3MB) stay L2-resident per XCD. Item = (hh, qt, kc): q-rows [qt*64,+64)
// of head g+8*hh vs K-tiles [4kc, min(4kc+4, ktt)).
// K staging: 9 groups of 64-k per tile, triple-buffered (3 x 16KB), running
// buffer index mod 3 across tiles (9%3==0 -> seamless cross-tile prefetch).
// ONE vm_barrier<4> per group (16 MFMAs between barriers, prefetch distance
// = 2 groups ~ 320cy >= L2 latency). LDS = Ks 48K + Ps 17K = 65.5 KiB.
// __launch_bounds__(256,2): 256 regs/wave, ~190-reg demand fits spill-free.
__global__ __launch_bounds__(256, 2) void attn_partial(
    const u16* __restrict__ qfb,   // [2048][16*576]
    const u16* __restrict__ kfb,   // [2048][576]
    const u16* __restrict__ vallT, // [16][128][2048]
    u32* __restrict__ ctr,         // [8]
    u16* __restrict__ pO,          // [1280][64][128]
    float* __restrict__ pS)        // [1280][64][2]
{
  __shared__ u16 Ks[3 * 8192];   // 3 bufs x (2 chunks x [128 rows][32 k])
  __shared__ u16 Ps[4 * 2176];   // per-wave P, 16 rows x 136 stride
  __shared__ u32 cur;

  const int tid = threadIdx.x;
  const int w = tid >> 6, lane = tid & 63;
  const int fr = lane & 15, fq = lane >> 4;
  const float scale = 0.07216878364870323f;  // (DN+DR)^-0.5
  const int grp = (int)(blockIdx.x & 7);     // XCD-aligned head group
  u16* Psw = Ps + w * 2176;

  const int krow0 = (w * 2) * 16 + (lane >> 2);
  const int krow1 = (w * 2 + 1) * 16 + (lane >> 2);
  const int kg0 = (lane & 3) ^ (krow0 & 3);
  const int kg1 = (lane & 3) ^ (krow1 & 3);

  while (true) {
    if (tid == 0) cur = atomicAdd(&ctr[grp], 1u);
    __syncthreads();
    const u32 it = cur;
    if (it >= N_ITEMS_G) break;

    // decode group-local item (qt descending; within qt: kc asc, hh 0..1)
    int rem = (int)it, qt = 31, kc = 0, hh = 0;
    for (int q = 31; q >= 0; --q) {
      int cnt = nkc_of(q) * 2;
      if (rem < cnt) { qt = q; kc = rem >> 1; hh = rem & 1; break; }
      rem -= cnt;
    }
    const int h = grp + hh * 8;
    const u32 gslot = (u32)grp * N_ITEMS_G + it;   // global partial slot
    const int q0 = qt * 64;
    const int ktt = (qt >> 1) + 1;
    const int kt0 = kc * 4, kt1 = min(kt0 + 4, ktt);

    // Q fragments resident (A[m=fr][k=fq*8+j])
    bf16x8 aq[18];
    {
      const u16* qp = qfb + (long)(q0 + w * 16 + fr) * 9216 + h * 576 + fq * 8;
#pragma unroll
      for (int d = 0; d < 18; ++d) aq[d] = *(const bf16x8*)(qp + d * 32);
    }

    float m_run[4], l_run[4];
#pragma unroll
    for (int r = 0; r < 4; ++r) { m_run[r] = -1e30f; l_run[r] = 0.f; }
    f32x4 Oacc[8] = {};
    // per-lane V fragment base: frag(jv,ks) = vlane + k0 + jv*32768 + ks*32
    const u16* vlane = vallT + (long)h * 262144 + (long)fr * 2048 + fq * 8;

    // Stage one 64-k group (2 chunks, 4 GLDS/thread) into buffer gb (0..2).
    auto issueG = [&](int kt, int gk, int gb) {
      const int k0i = kt * 128;
      u16* buf = Ks + gb * 8192;
#pragma unroll
      for (int c = 0; c < 2; ++c) {
        const int d0 = (gk * 2 + c) * 32;
        u16* dst = buf + c * 4096;
        GLDS(kfb + (long)(k0i + krow0) * 576 + d0 + kg0 * 8, dst + (w * 2) * 512);
        GLDS(kfb + (long)(k0i + krow1) * 576 + d0 + kg1 * 8, dst + (w * 2 + 1) * 512);
      }
    };

    issueG(kt0, 0, 0);
    issueG(kt0, 1, 1);

    for (int kt = kt0; kt < kt1; ++kt) {
      const int k0 = kt * 128;
      // group0 of this tile landed block-wide (vmcnt in-order: >=8 younger
      // ops issued since); also WAR-protects buf2 before g=0 issues into it.
      vm_barrier<4>();

      f32x4 sc[8] = {};
#pragma unroll
      for (int g = 0; g < 9; ++g) {
        const int gg = g + 2;
        if (gg <= 8) issueG(kt, gg, gg % 3);
        else if (kt + 1 < kt1) issueG(kt + 1, gg - 9, gg % 3);  // 9,10 -> 0,1
        const u16* kb0 = Ks + (g % 3) * 8192;
        __builtin_amdgcn_s_setprio(1);
#pragma unroll
        for (int c = 0; c < 2; ++c) {
          const int d = 2 * g + c;
          const u16* kb = kb0 + c * 4096;
#pragma unroll
          for (int j = 0; j < 8; ++j) {
            const int row = j * 16 + fr;
            bf16x8 b = *(const bf16x8*)(kb + row * 32 + ((fq ^ (row & 3)) * 8));
            sc[j] = MFMA(aq[d], b, sc[j]);
          }
        }
        __builtin_amdgcn_s_setprio(0);
        if (g < 8) vm_barrier<4>();  // next group landed; frees buf[g%3]
      }

      // V ks-group 0 into dual register buffers (L2-resident; latency hidden
      // under softmax). No barrier needed: V loads don't touch LDS.
      const u16* vk = vlane + k0;
      bf16x8 vA[4], vB[4];
#pragma unroll
      for (int q = 0; q < 4; ++q) {
        vA[q] = *(const bf16x8*)(vk + (long)q * 32768);
        vB[q] = *(const bf16x8*)(vk + (long)(q + 4) * 32768);
      }

      // wave-local online softmax
      const bool diag = (kt == ktt - 1);
#pragma unroll
      for (int r = 0; r < 4; ++r) {
        float mx = m_run[r];
#pragma unroll
        for (int j = 0; j < 8; ++j) {
          float s = sc[j][r] * scale;
          if (diag) {
            const int row = q0 + w * 16 + fq * 4 + r;
            const int col = k0 + j * 16 + fr;
            if (col > row) s = -1e30f;
          }
          sc[j][r] = s;
          mx = fmaxf(mx, s);
        }
        mx = fmaxf(mx, __shfl_xor(mx, 1));
        mx = fmaxf(mx, __shfl_xor(mx, 2));
        mx = fmaxf(mx, __shfl_xor(mx, 4));
        mx = fmaxf(mx, __shfl_xor(mx, 8));
        const float alpha = __expf(m_run[r] - mx);
        m_run[r] = mx;
        float sum = 0.f;
#pragma unroll
        for (int j = 0; j < 8; ++j) {
          float p = __expf(sc[j][r] - mx);
          sc[j][r] = p;
          sum += p;
        }
        sum += __shfl_xor(sum, 1);
        sum += __shfl_xor(sum, 2);
        sum += __shfl_xor(sum, 4);
        sum += __shfl_xor(sum, 8);
        l_run[r] = l_run[r] * alpha + sum;
#pragma unroll
        for (int jv = 0; jv < 8; ++jv) Oacc[jv][r] *= alpha;
#pragma unroll
        for (int j = 0; j < 8; ++j)
          Psw[(fq * 4 + r) * 136 + j * 16 + fr] = f2b(sc[j][r]);
      }

      // PV: O += P @ V^T, V fragments ping-ponged from global (no barrier)
#pragma unroll
      for (int ks = 0; ks < 4; ++ks) {
        bf16x8 ap = *(const bf16x8*)(Psw + fr * 136 + ks * 32 + fq * 8);
        __builtin_amdgcn_s_setprio(1);
#pragma unroll
        for (int q = 0; q < 4; ++q) Oacc[q] = MFMA(ap, vA[q], Oacc[q]);
        __builtin_amdgcn_s_setprio(0);
        if (ks < 3) {
#pragma unroll
          for (int q = 0; q < 4; ++q)
            vA[q] = *(const bf16x8*)(vk + (long)q * 32768 + (ks + 1) * 32);
        }
        __builtin_amdgcn_s_setprio(1);
#pragma unroll
        for (int q = 0; q < 4; ++q) Oacc[q + 4] = MFMA(ap, vB[q], Oacc[q + 4]);
        __builtin_amdgcn_s_setprio(0);
        if (ks < 3) {
#pragma unroll
          for (int q = 0; q < 4; ++q)
            vB[q] = *(const bf16x8*)(vk + (long)(q + 4) * 32768 + (ks + 1) * 32);
        }
      }
    }

    // write partial: raw O (bf16) + per-row stats
    const long po = (long)gslot * 8192;
#pragma unroll
    for (int r = 0; r < 4; ++r) {
      const int lr = w * 16 + fq * 4 + r;
      if (fr == 0) {
        pS[((long)gslot * 64 + lr) * 2] = m_run[r];
        pS[((long)gslot * 64 + lr) * 2 + 1] = l_run[r];
      }
#pragma unroll
      for (int jv = 0; jv < 8; ++jv)
        pO[po + (long)lr * 128 + jv * 16 + fr] = f2b(Oacc[jv][r]);
    }
  }
}

// ---------------- combine partials (log-sum-exp weights) ----------------
__global__ __launch_bounds__(256) void attn_reduce(
    const u16* __restrict__ pO, const float* __restrict__ pS,
    u16* __restrict__ ovb)
{
  const int h = blockIdx.x, qt = blockIdx.y;
  const int g = h & 7, hh = h >> 3;
  const int ktt = (qt >> 1) + 1;
  const int nkc = (ktt + 3) >> 2;
  int base = g * N_ITEMS_G;
  for (int q = qt + 1; q < 32; ++q) base += nkc_of(q) * 2;
  const int tid = threadIdx.x;
  const int r = tid >> 2, cq = (tid & 3) * 32;

  float m[4], l[4], wgt[4];
  float M = -1e30f;
  for (int i = 0; i < nkc; ++i) {
    const long slot = base + i * 2 + hh;
    m[i] = pS[(slot * 64 + r) * 2];
    l[i] = pS[(slot * 64 + r) * 2 + 1];
    M = fmaxf(M, m[i]);
  }
  float L = 0.f;
  for (int i = 0; i < nkc; ++i) { wgt[i] = __expf(m[i] - M); L += l[i] * wgt[i]; }
  const float inv = 1.0f / L;

  u16* orow = ovb + (long)(qt * 64 + r) * 2048 + h * 128 + cq;
  for (int c8 = 0; c8 < 32; c8 += 8) {
    float acc[8] = {};
    for (int i = 0; i < nkc; ++i) {
      const long slot = base + i * 2 + hh;
      const u16x8 v = *(const u16x8*)(pO + (slot * 64 + r) * 128 + cq + c8);
#pragma unroll
      for (int e = 0; e < 8; ++e) acc[e] += b2f(v[e]) * wgt[i];
    }
    u16x8 o;
#pragma unroll
    for (int e = 0; e < 8; ++e) o[e] = f2b(acc[e] * inv);
    *(u16x8*)(orow + c8) = o;
  }
}

// ---------------- conversion / transpose kernels ----------------
__global__ __launch_bounds__(256) void cast_bf16(const float* __restrict__ in,
                                                 u16* __restrict__ out, long n) {
  long i = ((long)blockIdx.x * 256 + threadIdx.x) * 4;
  if (i >= n) return;
  float4 v = *(const float4*)(in + i);
  ushort4 o = { f2b(v.x), f2b(v.y), f2b(v.z), f2b(v.w) };
  *(ushort4*)(out + i) = o;
}

__global__ __launch_bounds__(256) void transpose_cast(const float* __restrict__ in,
    u16* __restrict__ out, int ldi, int ldo, long sIn, long sOut) {
  in += (long)blockIdx.z * sIn;
  out += (long)blockIdx.z * sOut;
  __shared__ u16 t[32][33];
  const int i0 = blockIdx.y * 32, j0 = blockIdx.x * 32;
  const int tx = threadIdx.x & 31, ty = threadIdx.x >> 5;
  for (int r = ty; r < 32; r += 8)
    t[r][tx] = f2b(in[(long)(i0 + r) * ldi + j0 + tx]);
  __syncthreads();
  for (int r = ty; r < 32; r += 8)
    out[(long)(j0 + r) * ldo + i0 + tx] = t[tx][r];
}

// ---------------- RMSNorm fp32 (row stride ldin) -> bf16 ----------------
__global__ __launch_bounds__(256) void rmsnorm_cast(const float* __restrict__ in,
    const float* __restrict__ w, u16* __restrict__ out, int n, int ldin) {
  __shared__ float red[4];
  const float* row = in + (long)blockIdx.x * ldin;
  u16* orow = out + (long)blockIdx.x * n;
  float ss = 0.f;
  for (int i = threadIdx.x; i < n; i += 256) { float v = row[i]; ss += v * v; }
  float tot = block_sum(ss, red);
  float inv = rsqrtf(tot / (float)n + 1e-6f);
  for (int i = threadIdx.x; i < n; i += 256) orow[i] = f2b(row[i] * inv * w[i]);
}

// ---------------- RoPE table (double precision) ----------------
__global__ __launch_bounds__(256) void rope_table(float* tab) {
  int s = blockIdx.x * 8 + (threadIdx.x >> 5), j = threadIdx.x & 31;
  double freq = pow(10000.0, -(double)j / 32.0);
  double ang = (double)s * freq;
  tab[s * 64 + j] = (float)cos(ang);
  tab[s * 64 + 32 + j] = (float)sin(ang);
}

// ---------------- k_full: rmsnorm(ckv) ++ rope(k_pe) -> bf16 ----------------
// ckv points at col 1536 of the fused [2048][2176] f32 buffer.
__global__ __launch_bounds__(256) void build_kfull(const float* __restrict__ ckv,
    const float* __restrict__ lnw, const float* __restrict__ tab, u16* __restrict__ kfb) {
  __shared__ float red[4];
  const int s = blockIdx.x;
  const float* row = ckv + (long)s * 2176;
  float ss = 0.f;
  for (int i = threadIdx.x; i < 512; i += 256) { float v = row[i]; ss += v * v; }
  float tot = block_sum(ss, red);
  float inv = rsqrtf(tot / 512.0f + 1e-6f);
  u16* orow = kfb + (long)s * 576;
  for (int i = threadIdx.x; i < 512; i += 256) orow[i] = f2b(row[i] * inv * lnw[i]);
  if (threadIdx.x < 64) {
    int i = threadIdx.x, j = i & 31;
    float c = tab[s * 64 + j], sn = tab[s * 64 + 32 + j];
    float xv = row[512 + i];
    float rot = (i < 32) ? -row[512 + i + 32] : row[512 + i - 32];
    orow[512 + i] = f2b(xv * c + rot * sn);
  }
}

// ---------------- roped q_pe (bf16 in) into qfb[..., 512:576] ----------------
// grid 2048 x 256 threads: thread (h = t>>4, 4 i's).
__global__ __launch_bounds__(256) void rope_qpe(const u16* __restrict__ qb,
    const float* __restrict__ tab, u16* __restrict__ qfb) {
  const int s = blockIdx.x;
  const int h = threadIdx.x >> 4;
  const int i0 = (threadIdx.x & 15) * 4;
  const u16* src = qb + (long)s * 3072 + h * 192 + 128;
  u16* dst = qfb + (long)s * 9216 + h * 576 + 512;
#pragma unroll
  for (int k = 0; k < 4; ++k) {
    const int i = i0 + k, j = i & 31;
    float c = tab[s * 64 + j], sn = tab[s * 64 + 32 + j];
    float xv = b2f(src[i]);
    float rot = (i < 32) ? -b2f(src[i + 32]) : b2f(src[i - 32]);
    dst[i] = f2b(xv * c + rot * sn);
  }
}

extern "C" void kernel_launch(void* const* d_in, const int* in_sizes, int n_in,
                              void* d_out, int out_size, void* d_ws, size_t ws_size,
                              hipStream_t stream) {
  const float* x      = (const float*)d_in[0];
  const float* w_q_a  = (const float*)d_in[1];
  const float* q_ln   = (const float*)d_in[2];
  const float* w_q_b  = (const float*)d_in[3];
  const float* w_kv_a = (const float*)d_in[4];
  const float* kv_ln  = (const float*)d_in[5];
  const float* w_kv_b = (const float*)d_in[6];
  const float* w_o    = (const float*)d_in[7];
  float* out = (float*)d_out;

  // ---- fixed workspace (bytes) ----
  char* p = (char*)d_ws;
  float* tab   = (float*)p;  p += 524288;      // 2048*64 f32
  u16* wkvbb   = (u16*)p;    p += 4194304;     // 512*4096
  u16* wuvT    = (u16*)p;    p += 2097152;     // 16*128*512
  u16* woT     = (u16*)p;    p += 8388608;     // 2048*2048
  u16* qfb     = (u16*)p;    p += 37748736;    // 2048*9216
  u16* vallT   = (u16*)p;    p += 8388608;     // 16*128*2048
  u16* kfb     = (u16*)p;    p += 2359296;     // 2048*576
  u16* ovb     = (u16*)p;    p += 8388608;     // 2048*2048
  char* tb = p;
  // phase 1 transient:
  u16* xb      = (u16*)tb;                     // 2048*2048            (8.4 MB)
  u16* wabT    = (u16*)(tb + 8388608);         // 2176*2048 (qa++kva transposed)
  float* qac   = (float*)(tb + 17301504);      // 2048*2176 f32 (qa | ckv_kpe)
  u16* qab     = (u16*)(tb + 35127296);        // 2048*1536
  u16* wqbT    = (u16*)(tb + 41418752);        // 3072*1536
  u16* qb      = (u16*)(tb + 50855936);        // 2048*3072  (ends 63.4 MB)
  // phase 2 transient (aliases phase 1, used only after it is dead):
  u16* pO      = (u16*)tb;                     // 1280*64*128 bf16 (21 MB)
  float* pS    = (float*)(tb + 20971520);      // 1280*64*2 f32
  u32* ctr     = (u32*)(tb + 21626880);        // 8 group counters

  rope_table<<<dim3(256), 256, 0, stream>>>(tab);

  // weight prep
  cast_bf16<<<4096, 256, 0, stream>>>(x, xb, 4194304);
  transpose_cast<<<dim3(48, 64), 256, 0, stream>>>(w_q_a, wabT, 1536, 2048, 0, 0);
  transpose_cast<<<dim3(18, 64), 256, 0, stream>>>(w_kv_a, wabT + 1536 * 2048, 576, 2048, 0, 0);
  transpose_cast<<<dim3(96, 48), 256, 0, stream>>>(w_q_b, wqbT, 3072, 1536, 0, 0);
  cast_bf16<<<2048, 256, 0, stream>>>(w_kv_b, wkvbb, 2097152);
  transpose_cast<<<dim3(4, 16, 16), 256, 0, stream>>>(w_kv_b + 128, wuvT, 4096, 512, 256, 65536);
  transpose_cast<<<dim3(64, 64), 256, 0, stream>>>(w_o, woT, 2048, 2048, 0, 0);

  // fused: [q_a | ckv_kpe] = x @ [w_q_a | w_kv_a]  (f32, ldc 2176)
  gemm_mfma<0><<<dim3(17, 16), 256, 0, stream>>>(
      xb, wabT, qac, 2048, 2048, 2048, 2176, 0, 0, 0);
  rmsnorm_cast<<<2048, 256, 0, stream>>>(qac, q_ln, qab, 1536, 2176);
  build_kfull<<<2048, 256, 0, stream>>>(qac + 1536, kv_ln, tab, kfb);

  // q = q_a @ w_q_b (bf16 out)
  gemm_mfma<1><<<dim3(24, 16), 256, 0, stream>>>(
      qab, wqbT, qb, 1536, 1536, 1536, 3072, 0, 0, 0);

  // q_full[:, h, :512] = q_nope[h] @ w_uk[h]^T (bf16 out, batched over h)
  gemm_mfma<1><<<dim3(4, 16, 16), 256, 0, stream>>>(
      qb, wkvbb, qfb, 128, 3072, 4096, 9216, 192, 256, 576);
  rope_qpe<<<dim3(2048), 256, 0, stream>>>(qb, tab, qfb);

  // vallT[h] = (ckv_n @ w_uv[h])^T  (bf16 transposed out)
  gemm_mfma<2><<<dim3(1, 16, 16), 256, 0, stream>>>(
      kfb, wuvT, vallT, 512, 576, 512, 2048, 0, 65536, 262144);

  // split-K flash attention, XCD-partitioned dynamic queues (2 blocks/CU)
  init_ctr<<<1, 64, 0, stream>>>(ctr);
  attn_partial<<<dim3(768), 256, 0, stream>>>(qfb, kfb, vallT, ctr, pO, pS);
  attn_reduce<<<dim3(16, 32), 256, 0, stream>>>(pO, pS, ovb);

  // y = o_v @ w_o (f32 out)
  gemm_mfma<0><<<dim3(16, 16), 256, 0, stream>>>(
      ovb, woT, out, 2048, 2048, 2048, 2048, 0, 0, 0);
}

// Round 10
// 482.143 us; speedup vs baseline: 1.2577x; 1.0349x over previous
//
#include <hip/hip_runtime.h>
#include <math.h>

// DeepSeek V2 MLA attention — bf16 MFMA GEMMs + split-K flash attention with
// a dynamic work queue (v10). v10 = v9 attn (unchanged, plateaued ~169us) +
// split-K=2 on the occupancy-starved big GEMMs: GEMM1 (272 blocks ~1/CU) and
// the output GEMM (256 blocks = 1/CU) run at 1 wave/SIMD where the m97 GEMM
// structure measures only ~320TF. Split-K doubles blocks/CU via blockIdx.z
// (gemm_mfma's batch strides reused as K-offsets); partials combined in the
// consumers (rmsnorm/build_kfull sum two streams) or a float4 add kernel.
// GEMM1 split gated on ws_size (+17.8MB partial buffer). attn grid 768->512
// (extra blocks provably idle: persistent blocks drain queues before exit).
// B=1 S=2048 E=2048 H=16 DN=128 DR=64 DV=128 R=512 QLR=1536

typedef unsigned short u16;
typedef unsigned int u32;
typedef __bf16 bf16x8 __attribute__((ext_vector_type(8)));
typedef float f32x4 __attribute__((ext_vector_type(4)));
typedef unsigned short u16x8 __attribute__((ext_vector_type(8)));

__device__ __forceinline__ u16 f2b(float f) {  // fp32 -> bf16 RNE
  u32 u = __float_as_uint(f);
  u += 0x7FFFu + ((u >> 16) & 1u);
  return (u16)(u >> 16);
}
__device__ __forceinline__ float b2f(u16 v) {
  return __uint_as_float(((u32)v) << 16);
}

#define GLDS(g, l) __builtin_amdgcn_global_load_lds( \
    (const __attribute__((address_space(1))) u32*)(g), \
    (__attribute__((address_space(3))) u32*)(l), 16, 0, 0)

#define MFMA(a, b, c) __builtin_amdgcn_mfma_f32_16x16x32_bf16(a, b, c, 0, 0, 0)

// s_waitcnt vmcnt(N) (lgkmcnt/expcnt untouched) + s_barrier.
template<int N>
__device__ __forceinline__ void vm_barrier() {
  __builtin_amdgcn_s_waitcnt(0xF70 | N);  // expcnt=7, lgkmcnt=15, vmcnt=N
  __builtin_amdgcn_s_barrier();
}

// Per-group (2 heads) items enumerated qt-descending (heavy first):
// for qt=31..0, kc=0..nkc-1, hh=0..1.  nkc(qt) = ceil((qt/2+1)/4).
// Per-group total = 160; global slot = g*160 + local.
#define N_ITEMS_G 160
__device__ __forceinline__ int nkc_of(int qt) { return (((qt >> 1) + 1) + 3) >> 2; }

// ---------------- block reduction helper ----------------
__device__ __forceinline__ float block_sum(float v, float* red) {
#pragma unroll
  for (int off = 32; off > 0; off >>= 1) v += __shfl_down(v, off);
  const int lane = threadIdx.x & 63, w = threadIdx.x >> 6;
  if (lane == 0) red[w] = v;
  __syncthreads();
  float r = red[0] + red[1] + red[2] + red[3];
  __syncthreads();
  return r;
}

// ---------------- bf16 MFMA GEMM, 128x128 tile, BK=32, pipelined ------------
// C = A[M,K] @ B[N,K]^T (both row-major bf16). Batched over blockIdx.z.
// Split-K reuses z with sA=sB=K-offset, sC=partial-buffer stride.
// OUTK: 0 = fp32 out, 1 = bf16 out, 2 = bf16 transposed out (C[n*ldc+m]).
template<int OUTK>
__global__ __launch_bounds__(256) void gemm_mfma(
    const u16* __restrict__ A, const u16* __restrict__ B, void* __restrict__ Cv,
    int K, int lda, int ldb, int ldc, long sA, long sB, long sC)
{
  __shared__ u16 At[3][4096];  // triple-buffered 128x32 tiles
  __shared__ u16 Bt[3][4096];
  const u16* Ab = A + (long)blockIdx.z * sA;
  const u16* Bb = B + (long)blockIdx.z * sB;
  const int tid = threadIdx.x;
  const int w = tid >> 6, lane = tid & 63;
  const int m0 = blockIdx.y * 128, n0 = blockIdx.x * 128;
  const int wm = (w >> 1) * 64, wn = (w & 1) * 64;
  const int fr = lane & 15, fq = lane >> 4;

  const int c0 = w * 2, c1 = w * 2 + 1;
  const int e0 = (c0 * 64 + lane) * 8, e1 = (c1 * 64 + lane) * 8;
  const int r0 = e0 >> 5, col0 = e0 & 31;
  const int r1 = e1 >> 5, col1 = e1 & 31;

  const int nk = K >> 5;
  auto issue = [&](int kc) {
    const int k0 = kc * 32;
    u16* at = At[kc % 3];
    u16* bt = Bt[kc % 3];
    GLDS(Ab + (long)(m0 + r0) * lda + k0 + col0, at + c0 * 512);
    GLDS(Bb + (long)(n0 + r0) * ldb + k0 + col0, bt + c0 * 512);
    GLDS(Ab + (long)(m0 + r1) * lda + k0 + col1, at + c1 * 512);
    GLDS(Bb + (long)(n0 + r1) * ldb + k0 + col1, bt + c1 * 512);
  };

  f32x4 acc[4][4] = {};
  issue(0);
  issue(1);
  vm_barrier<4>();
  for (int kc = 0; kc < nk; ++kc) {
    if (kc + 2 < nk) issue(kc + 2);
    const u16* at = At[kc % 3];
    const u16* bt = Bt[kc % 3];
    bf16x8 af[4], bfr[4];
#pragma unroll
    for (int i = 0; i < 4; ++i)
      af[i] = *(const bf16x8*)(at + (wm + i * 16 + fr) * 32 + fq * 8);
#pragma unroll
    for (int j = 0; j < 4; ++j)
      bfr[j] = *(const bf16x8*)(bt + (wn + j * 16 + fr) * 32 + fq * 8);
#pragma unroll
    for (int i = 0; i < 4; ++i)
#pragma unroll
      for (int j = 0; j < 4; ++j)
        acc[i][j] = MFMA(af[i], bfr[j], acc[i][j]);
    if (kc + 1 < nk) {
      if (kc + 2 < nk) vm_barrier<4>();
      else vm_barrier<0>();
    }
  }

  if (OUTK == 0) {
    float* C = (float*)Cv + (long)blockIdx.z * sC;
#pragma unroll
    for (int i = 0; i < 4; ++i)
#pragma unroll
      for (int j = 0; j < 4; ++j) {
        long base = (long)(m0 + wm + i * 16 + fq * 4) * ldc + (n0 + wn + j * 16 + fr);
#pragma unroll
        for (int r = 0; r < 4; ++r) C[base + (long)r * ldc] = acc[i][j][r];
      }
  } else if (OUTK == 1) {
    u16* C = (u16*)Cv + (long)blockIdx.z * sC;
#pragma unroll
    for (int i = 0; i < 4; ++i)
#pragma unroll
      for (int j = 0; j < 4; ++j) {
        long base = (long)(m0 + wm + i * 16 + fq * 4) * ldc + (n0 + wn + j * 16 + fr);
#pragma unroll
        for (int r = 0; r < 4; ++r) C[base + (long)r * ldc] = f2b(acc[i][j][r]);
      }
  } else {
    u16* C = (u16*)Cv + (long)blockIdx.z * sC;
#pragma unroll
    for (int i = 0; i < 4; ++i)
#pragma unroll
      for (int j = 0; j < 4; ++j) {
        ushort4 v = { f2b(acc[i][j][0]), f2b(acc[i][j][1]),
                      f2b(acc[i][j][2]), f2b(acc[i][j][3]) };
        *(ushort4*)(C + (long)(n0 + wn + j * 16 + fr) * ldc + (m0 + wm + i * 16 + fq * 4)) = v;
      }
  }
}

// ---------------- split-K combine: o = a + b (fp32, float4) ----------------
__global__ __launch_bounds__(256) void add_f32(const float* __restrict__ a,
    const float* __restrict__ b, float* __restrict__ o, long n) {
  long i = ((long)blockIdx.x * 256 + threadIdx.x) * 4;
  if (i >= n) return;
  float4 va = *(const float4*)(a + i);
  float4 vb = *(const float4*)(b + i);
  float4 vo = { va.x + vb.x, va.y + vb.y, va.z + vb.z, va.w + vb.w };
  *(float4*)(o + i) = vo;
}

// ---------------- counter init (8 group counters) ----------------
__global__ void init_ctr(u32* ctr) {
  if (threadIdx.x < 8) ctr[threadIdx.x] = 0;
}

// ---------------- split-K flash attention, XCD-partitioned queue ------------
// 512 persistent blocks (2/CU, all resident). Block b -> group g = b&7
// (XCD-aligned), processes heads {g, g+8} only; V (2x524KB) + K (2.3MB) stay
// L2-resident per XCD. Item = (hh, qt, kc): q-rows [qt*64,+64) of head g+8*hh
// vs K-tiles [4kc, min(4kc+4, ktt)).
// K staging: 9 groups of 64-k per tile, triple-buffered (3 x 16KB), running
// buffer index mod 3 across tiles; ONE vm_barrier<4> per group. LDS 65.5 KiB.
// __launch_bounds__(256,2): 256 regs/wave, ~190-reg demand fits spill-free.
__global__ __launch_bounds__(256, 2) void attn_partial(
    const u16* __restrict__ qfb,   // [2048][16*576]
    const u16* __restrict__ kfb,   // [2048][576]
    const u16* __restrict__ vallT, // [16][128][2048]
    u32* __restrict__ ctr,         // [8]
    u16* __restrict__ pO,          // [1280][64][128]
    float* __restrict__ pS)        // [1280][64][2]
{
  __shared__ u16 Ks[3 * 8192];   // 3 bufs x (2 chunks x [128 rows][32 k])
  __shared__ u16 Ps[4 * 2176];   // per-wave P, 16 rows x 136 stride
  __shared__ u32 cur;

  const int tid = threadIdx.x;
  const int w = tid >> 6, lane = tid & 63;
  const int fr = lane & 15, fq = lane >> 4;
  const float scale = 0.07216878364870323f;  // (DN+DR)^-0.5
  const int grp = (int)(blockIdx.x & 7);     // XCD-aligned head group
  u16* Psw = Ps + w * 2176;

  const int krow0 = (w * 2) * 16 + (lane >> 2);
  const int krow1 = (w * 2 + 1) * 16 + (lane >> 2);
  const int kg0 = (lane & 3) ^ (krow0 & 3);
  const int kg1 = (lane & 3) ^ (krow1 & 3);

  while (true) {
    if (tid == 0) cur = atomicAdd(&ctr[grp], 1u);
    __syncthreads();
    const u32 it = cur;
    if (it >= N_ITEMS_G) break;

    // decode group-local item (qt descending; within qt: kc asc, hh 0..1)
    int rem = (int)it, qt = 31, kc = 0, hh = 0;
    for (int q = 31; q >= 0; --q) {
      int cnt = nkc_of(q) * 2;
      if (rem < cnt) { qt = q; kc = rem >> 1; hh = rem & 1; break; }
      rem -= cnt;
    }
    const int h = grp + hh * 8;
    const u32 gslot = (u32)grp * N_ITEMS_G + it;   // global partial slot
    const int q0 = qt * 64;
    const int ktt = (qt >> 1) + 1;
    const int kt0 = kc * 4, kt1 = min(kt0 + 4, ktt);

    // Q fragments resident (A[m=fr][k=fq*8+j])
    bf16x8 aq[18];
    {
      const u16* qp = qfb + (long)(q0 + w * 16 + fr) * 9216 + h * 576 + fq * 8;
#pragma unroll
      for (int d = 0; d < 18; ++d) aq[d] = *(const bf16x8*)(qp + d * 32);
    }

    float m_run[4], l_run[4];
#pragma unroll
    for (int r = 0; r < 4; ++r) { m_run[r] = -1e30f; l_run[r] = 0.f; }
    f32x4 Oacc[8] = {};
    // per-lane V fragment base: frag(jv,ks) = vlane + k0 + jv*32768 + ks*32
    const u16* vlane = vallT + (long)h * 262144 + (long)fr * 2048 + fq * 8;

    // Stage one 64-k group (2 chunks, 4 GLDS/thread) into buffer gb (0..2).
    auto issueG = [&](int kt, int gk, int gb) {
      const int k0i = kt * 128;
      u16* buf = Ks + gb * 8192;
#pragma unroll
      for (int c = 0; c < 2; ++c) {
        const int d0 = (gk * 2 + c) * 32;
        u16* dst = buf + c * 4096;
        GLDS(kfb + (long)(k0i + krow0) * 576 + d0 + kg0 * 8, dst + (w * 2) * 512);
        GLDS(kfb + (long)(k0i + krow1) * 576 + d0 + kg1 * 8, dst + (w * 2 + 1) * 512);
      }
    };

    issueG(kt0, 0, 0);
    issueG(kt0, 1, 1);

    for (int kt = kt0; kt < kt1; ++kt) {
      const int k0 = kt * 128;
      // group0 of this tile landed block-wide; also WAR-protects buf2.
      vm_barrier<4>();

      f32x4 sc[8] = {};
#pragma unroll
      for (int g = 0; g < 9; ++g) {
        const int gg = g + 2;
        if (gg <= 8) issueG(kt, gg, gg % 3);
        else if (kt + 1 < kt1) issueG(kt + 1, gg - 9, gg % 3);  // 9,10 -> 0,1
        const u16* kb0 = Ks + (g % 3) * 8192;
        __builtin_amdgcn_s_setprio(1);
#pragma unroll
        for (int c = 0; c < 2; ++c) {
          const int d = 2 * g + c;
          const u16* kb = kb0 + c * 4096;
#pragma unroll
          for (int j = 0; j < 8; ++j) {
            const int row = j * 16 + fr;
            bf16x8 b = *(const bf16x8*)(kb + row * 32 + ((fq ^ (row & 3)) * 8));
            sc[j] = MFMA(aq[d], b, sc[j]);
          }
        }
        __builtin_amdgcn_s_setprio(0);
        if (g < 8) vm_barrier<4>();  // next group landed; frees buf[g%3]
      }

      // V ks-group 0 into dual register buffers (L2-resident; latency hidden
      // under softmax). No barrier needed: V loads don't touch LDS.
      const u16* vk = vlane + k0;
      bf16x8 vA[4], vB[4];
#pragma unroll
      for (int q = 0; q < 4; ++q) {
        vA[q] = *(const bf16x8*)(vk + (long)q * 32768);
        vB[q] = *(const bf16x8*)(vk + (long)(q + 4) * 32768);
      }

      // wave-local online softmax
      const bool diag = (kt == ktt - 1);
#pragma unroll
      for (int r = 0; r < 4; ++r) {
        float mx = m_run[r];
#pragma unroll
        for (int j = 0; j < 8; ++j) {
          float s = sc[j][r] * scale;
          if (diag) {
            const int row = q0 + w * 16 + fq * 4 + r;
            const int col = k0 + j * 16 + fr;
            if (col > row) s = -1e30f;
          }
          sc[j][r] = s;
          mx = fmaxf(mx, s);
        }
        mx = fmaxf(mx, __shfl_xor(mx, 1));
        mx = fmaxf(mx, __shfl_xor(mx, 2));
        mx = fmaxf(mx, __shfl_xor(mx, 4));
        mx = fmaxf(mx, __shfl_xor(mx, 8));
        const float alpha = __expf(m_run[r] - mx);
        m_run[r] = mx;
        float sum = 0.f;
#pragma unroll
        for (int j = 0; j < 8; ++j) {
          float p = __expf(sc[j][r] - mx);
          sc[j][r] = p;
          sum += p;
        }
        sum += __shfl_xor(sum, 1);
        sum += __shfl_xor(sum, 2);
        sum += __shfl_xor(sum, 4);
        sum += __shfl_xor(sum, 8);
        l_run[r] = l_run[r] * alpha + sum;
#pragma unroll
        for (int jv = 0; jv < 8; ++jv) Oacc[jv][r] *= alpha;
#pragma unroll
        for (int j = 0; j < 8; ++j)
          Psw[(fq * 4 + r) * 136 + j * 16 + fr] = f2b(sc[j][r]);
      }

      // PV: O += P @ V^T, V fragments ping-ponged from global (no barrier)
#pragma unroll
      for (int ks = 0; ks < 4; ++ks) {
        bf16x8 ap = *(const bf16x8*)(Psw + fr * 136 + ks * 32 + fq * 8);
        __builtin_amdgcn_s_setprio(1);
#pragma unroll
        for (int q = 0; q < 4; ++q) Oacc[q] = MFMA(ap, vA[q], Oacc[q]);
        __builtin_amdgcn_s_setprio(0);
        if (ks < 3) {
#pragma unroll
          for (int q = 0; q < 4; ++q)
            vA[q] = *(const bf16x8*)(vk + (long)q * 32768 + (ks + 1) * 32);
        }
        __builtin_amdgcn_s_setprio(1);
#pragma unroll
        for (int q = 0; q < 4; ++q) Oacc[q + 4] = MFMA(ap, vB[q], Oacc[q + 4]);
        __builtin_amdgcn_s_setprio(0);
        if (ks < 3) {
#pragma unroll
          for (int q = 0; q < 4; ++q)
            vB[q] = *(const bf16x8*)(vk + (long)(q + 4) * 32768 + (ks + 1) * 32);
        }
      }
    }

    // write partial: raw O (bf16) + per-row stats
    const long po = (long)gslot * 8192;
#pragma unroll
    for (int r = 0; r < 4; ++r) {
      const int lr = w * 16 + fq * 4 + r;
      if (fr == 0) {
        pS[((long)gslot * 64 + lr) * 2] = m_run[r];
        pS[((long)gslot * 64 + lr) * 2 + 1] = l_run[r];
      }
#pragma unroll
      for (int jv = 0; jv < 8; ++jv)
        pO[po + (long)lr * 128 + jv * 16 + fr] = f2b(Oacc[jv][r]);
    }
  }
}

// ---------------- combine partials (log-sum-exp weights) ----------------
__global__ __launch_bounds__(256) void attn_reduce(
    const u16* __restrict__ pO, const float* __restrict__ pS,
    u16* __restrict__ ovb)
{
  const int h = blockIdx.x, qt = blockIdx.y;
  const int g = h & 7, hh = h >> 3;
  const int ktt = (qt >> 1) + 1;
  const int nkc = (ktt + 3) >> 2;
  int base = g * N_ITEMS_G;
  for (int q = qt + 1; q < 32; ++q) base += nkc_of(q) * 2;
  const int tid = threadIdx.x;
  const int r = tid >> 2, cq = (tid & 3) * 32;

  float m[4], l[4], wgt[4];
  float M = -1e30f;
  for (int i = 0; i < nkc; ++i) {
    const long slot = base + i * 2 + hh;
    m[i] = pS[(slot * 64 + r) * 2];
    l[i] = pS[(slot * 64 + r) * 2 + 1];
    M = fmaxf(M, m[i]);
  }
  float L = 0.f;
  for (int i = 0; i < nkc; ++i) { wgt[i] = __expf(m[i] - M); L += l[i] * wgt[i]; }
  const float inv = 1.0f / L;

  u16* orow = ovb + (long)(qt * 64 + r) * 2048 + h * 128 + cq;
  for (int c8 = 0; c8 < 32; c8 += 8) {
    float acc[8] = {};
    for (int i = 0; i < nkc; ++i) {
      const long slot = base + i * 2 + hh;
      const u16x8 v = *(const u16x8*)(pO + (slot * 64 + r) * 128 + cq + c8);
#pragma unroll
      for (int e = 0; e < 8; ++e) acc[e] += b2f(v[e]) * wgt[i];
    }
    u16x8 o;
#pragma unroll
    for (int e = 0; e < 8; ++e) o[e] = f2b(acc[e] * inv);
    *(u16x8*)(orow + c8) = o;
  }
}

// ---------------- conversion / transpose kernels ----------------
__global__ __launch_bounds__(256) void cast_bf16(const float* __restrict__ in,
                                                 u16* __restrict__ out, long n) {
  long i = ((long)blockIdx.x * 256 + threadIdx.x) * 4;
  if (i >= n) return;
  float4 v = *(const float4*)(in + i);
  ushort4 o = { f2b(v.x), f2b(v.y), f2b(v.z), f2b(v.w) };
  *(ushort4*)(out + i) = o;
}

__global__ __launch_bounds__(256) void transpose_cast(const float* __restrict__ in,
    u16* __restrict__ out, int ldi, int ldo, long sIn, long sOut) {
  in += (long)blockIdx.z * sIn;
  out += (long)blockIdx.z * sOut;
  __shared__ u16 t[32][33];
  const int i0 = blockIdx.y * 32, j0 = blockIdx.x * 32;
  const int tx = threadIdx.x & 31, ty = threadIdx.x >> 5;
  for (int r = ty; r < 32; r += 8)
    t[r][tx] = f2b(in[(long)(i0 + r) * ldi + j0 + tx]);
  __syncthreads();
  for (int r = ty; r < 32; r += 8)
    out[(long)(j0 + r) * ldo + i0 + tx] = t[tx][r];
}

// ---------- RMSNorm fp32 (row stride ldin) -> bf16; optional 2nd stream ----
// in2 != nullptr: value = in[i] + in2[i] (split-K partial sum fused here).
__global__ __launch_bounds__(256) void rmsnorm_cast(const float* __restrict__ in,
    const float* __restrict__ w, u16* __restrict__ out, int n, int ldin,
    const float* __restrict__ in2) {
  __shared__ float red[4];
  const float* row = in + (long)blockIdx.x * ldin;
  const float* row2 = in2 ? in2 + (long)blockIdx.x * ldin : nullptr;
  u16* orow = out + (long)blockIdx.x * n;
  float ss = 0.f;
  if (row2) {
    for (int i = threadIdx.x; i < n; i += 256) {
      float v = row[i] + row2[i]; ss += v * v;
    }
  } else {
    for (int i = threadIdx.x; i < n; i += 256) { float v = row[i]; ss += v * v; }
  }
  float tot = block_sum(ss, red);
  float inv = rsqrtf(tot / (float)n + 1e-6f);
  if (row2) {
    for (int i = threadIdx.x; i < n; i += 256)
      orow[i] = f2b((row[i] + row2[i]) * inv * w[i]);
  } else {
    for (int i = threadIdx.x; i < n; i += 256) orow[i] = f2b(row[i] * inv * w[i]);
  }
}

// ---------------- RoPE table (double precision) ----------------
__global__ __launch_bounds__(256) void rope_table(float* tab) {
  int s = blockIdx.x * 8 + (threadIdx.x >> 5), j = threadIdx.x & 31;
  double freq = pow(10000.0, -(double)j / 32.0);
  double ang = (double)s * freq;
  tab[s * 64 + j] = (float)cos(ang);
  tab[s * 64 + 32 + j] = (float)sin(ang);
}

// ---------------- k_full: rmsnorm(ckv) ++ rope(k_pe) -> bf16 ----------------
// ckv points at col 1536 of the fused [2048][2176] f32 buffer.
// ckv2 != nullptr: value = ckv[i] + ckv2[i] (split-K partial sum fused).
__global__ __launch_bounds__(256) void build_kfull(const float* __restrict__ ckv,
    const float* __restrict__ lnw, const float* __restrict__ tab,
    u16* __restrict__ kfb, const float* __restrict__ ckv2) {
  __shared__ float red[4];
  const int s = blockIdx.x;
  const float* row = ckv + (long)s * 2176;
  const float* row2 = ckv2 ? ckv2 + (long)s * 2176 : nullptr;
  float ss = 0.f;
  if (row2) {
    for (int i = threadIdx.x; i < 512; i += 256) {
      float v = row[i] + row2[i]; ss += v * v;
    }
  } else {
    for (int i = threadIdx.x; i < 512; i += 256) { float v = row[i]; ss += v * v; }
  }
  float tot = block_sum(ss, red);
  float inv = rsqrtf(tot / 512.0f + 1e-6f);
  u16* orow = kfb + (long)s * 576;
  if (row2) {
    for (int i = threadIdx.x; i < 512; i += 256)
      orow[i] = f2b((row[i] + row2[i]) * inv * lnw[i]);
  } else {
    for (int i = threadIdx.x; i < 512; i += 256)
      orow[i] = f2b(row[i] * inv * lnw[i]);
  }
  if (threadIdx.x < 64) {
    int i = threadIdx.x, j = i & 31;
    float c = tab[s * 64 + j], sn = tab[s * 64 + 32 + j];
    float xv = row[512 + i] + (row2 ? row2[512 + i] : 0.f);
    float rv = (i < 32) ? row[512 + i + 32] + (row2 ? row2[512 + i + 32] : 0.f)
                        : row[512 + i - 32] + (row2 ? row2[512 + i - 32] : 0.f);
    float rot = (i < 32) ? -rv : rv;
    orow[512 + i] = f2b(xv * c + rot * sn);
  }
}

// ---------------- roped q_pe (bf16 in) into qfb[..., 512:576] ----------------
// grid 2048 x 256 threads: thread (h = t>>4, 4 i's).
__global__ __launch_bounds__(256) void rope_qpe(const u16* __restrict__ qb,
    const float* __restrict__ tab, u16* __restrict__ qfb) {
  const int s = blockIdx.x;
  const int h = threadIdx.x >> 4;
  const int i0 = (threadIdx.x & 15) * 4;
  const u16* src = qb + (long)s * 3072 + h * 192 + 128;
  u16* dst = qfb + (long)s * 9216 + h * 576 + 512;
#pragma unroll
  for (int k = 0; k < 4; ++k) {
    const int i = i0 + k, j = i & 31;
    float c = tab[s * 64 + j], sn = tab[s * 64 + 32 + j];
    float xv = b2f(src[i]);
    float rot = (i < 32) ? -b2f(src[i + 32]) : b2f(src[i - 32]);
    dst[i] = f2b(xv * c + rot * sn);
  }
}

extern "C" void kernel_launch(void* const* d_in, const int* in_sizes, int n_in,
                              void* d_out, int out_size, void* d_ws, size_t ws_size,
                              hipStream_t stream) {
  const float* x      = (const float*)d_in[0];
  const float* w_q_a  = (const float*)d_in[1];
  const float* q_ln   = (const float*)d_in[2];
  const float* w_q_b  = (const float*)d_in[3];
  const float* w_kv_a = (const float*)d_in[4];
  const float* kv_ln  = (const float*)d_in[5];
  const float* w_kv_b = (const float*)d_in[6];
  const float* w_o    = (const float*)d_in[7];
  float* out = (float*)d_out;

  // ---- fixed workspace (bytes) ----
  char* p = (char*)d_ws;
  float* tab   = (float*)p;  p += 524288;      // 2048*64 f32
  u16* wkvbb   = (u16*)p;    p += 4194304;     // 512*4096
  u16* wuvT    = (u16*)p;    p += 2097152;     // 16*128*512
  u16* woT     = (u16*)p;    p += 8388608;     // 2048*2048
  u16* qfb     = (u16*)p;    p += 37748736;    // 2048*9216
  u16* vallT   = (u16*)p;    p += 8388608;     // 16*128*2048
  u16* kfb     = (u16*)p;    p += 2359296;     // 2048*576
  u16* ovb     = (u16*)p;    p += 8388608;     // 2048*2048
  char* tb = p;
  // phase 1 transient (63.44 MB):
  u16* xb      = (u16*)tb;                     // 2048*2048            (8.39 MB)
  u16* wabT    = (u16*)(tb + 8388608);         // 2176*2048 (qa++kva transposed)
  float* qac   = (float*)(tb + 17301504);      // 2048*2176 f32 (qa | ckv_kpe)
  u16* qab     = (u16*)(tb + 35127296);        // 2048*1536
  u16* wqbT    = (u16*)(tb + 41418752);        // 3072*1536
  u16* qb      = (u16*)(tb + 50855936);        // 2048*3072  (ends 63,438,848)
  // gated split-K partial for GEMM1 (needs ws >= 155 MB):
  float* qacB  = (float*)(tb + 63438848);      // 2048*2176 f32 (17.8 MB)
  const size_t need_split1 = (size_t)(tb - (char*)d_ws) + 63438848 + 17825792;
  const bool split1 = ws_size >= need_split1;
  // phase 2 transient (aliases phase 1, used only after it is dead):
  u16* pO      = (u16*)tb;                     // 1280*64*128 bf16 (21 MB)
  float* pS    = (float*)(tb + 20971520);      // 1280*64*2 f32
  u32* ctr     = (u32*)(tb + 21626880);        // 8 group counters
  // phase 3 transient (after attn_reduce; pO/pS/ctr dead):
  float* outP  = (float*)tb;                   // 2 x 2048*2048 f32 (33.5 MB)

  rope_table<<<dim3(256), 256, 0, stream>>>(tab);

  // weight prep
  cast_bf16<<<4096, 256, 0, stream>>>(x, xb, 4194304);
  transpose_cast<<<dim3(48, 64), 256, 0, stream>>>(w_q_a, wabT, 1536, 2048, 0, 0);
  transpose_cast<<<dim3(18, 64), 256, 0, stream>>>(w_kv_a, wabT + 1536 * 2048, 576, 2048, 0, 0);
  transpose_cast<<<dim3(96, 48), 256, 0, stream>>>(w_q_b, wqbT, 3072, 1536, 0, 0);
  cast_bf16<<<2048, 256, 0, stream>>>(w_kv_b, wkvbb, 2097152);
  transpose_cast<<<dim3(4, 16, 16), 256, 0, stream>>>(w_kv_b + 128, wuvT, 4096, 512, 256, 65536);
  transpose_cast<<<dim3(64, 64), 256, 0, stream>>>(w_o, woT, 2048, 2048, 0, 0);

  // fused: [q_a | ckv_kpe] = x @ [w_q_a | w_kv_a]  (f32, ldc 2176)
  // split-K=2 (2 blocks/CU) when workspace allows; consumers sum the halves.
  if (split1) {
    gemm_mfma<0><<<dim3(17, 16, 2), 256, 0, stream>>>(
        xb, wabT, qac, 1024, 2048, 2048, 2176, 1024, 1024, (long)(qacB - qac));
  } else {
    gemm_mfma<0><<<dim3(17, 16), 256, 0, stream>>>(
        xb, wabT, qac, 2048, 2048, 2048, 2176, 0, 0, 0);
  }
  rmsnorm_cast<<<2048, 256, 0, stream>>>(qac, q_ln, qab, 1536, 2176,
                                         split1 ? qacB : nullptr);
  build_kfull<<<2048, 256, 0, stream>>>(qac + 1536, kv_ln, tab, kfb,
                                        split1 ? qacB + 1536 : nullptr);

  // q = q_a @ w_q_b (bf16 out; 384 blocks = 1.5/CU, not split)
  gemm_mfma<1><<<dim3(24, 16), 256, 0, stream>>>(
      qab, wqbT, qb, 1536, 1536, 1536, 3072, 0, 0, 0);

  // q_full[:, h, :512] = q_nope[h] @ w_uk[h]^T (bf16 out, batched over h)
  gemm_mfma<1><<<dim3(4, 16, 16), 256, 0, stream>>>(
      qb, wkvbb, qfb, 128, 3072, 4096, 9216, 192, 256, 576);
  rope_qpe<<<dim3(2048), 256, 0, stream>>>(qb, tab, qfb);

  // vallT[h] = (ckv_n @ w_uv[h])^T  (bf16 transposed out)
  gemm_mfma<2><<<dim3(1, 16, 16), 256, 0, stream>>>(
      kfb, wuvT, vallT, 512, 576, 512, 2048, 0, 65536, 262144);

  // split-K flash attention, XCD-partitioned dynamic queues (512 = 2/CU)
  init_ctr<<<1, 64, 0, stream>>>(ctr);
  attn_partial<<<dim3(512), 256, 0, stream>>>(qfb, kfb, vallT, ctr, pO, pS);
  attn_reduce<<<dim3(16, 32), 256, 0, stream>>>(pO, pS, ovb);

  // y = o_v @ w_o: split-K=2 (512 blocks = 2/CU) into fp32 partials + add
  gemm_mfma<0><<<dim3(16, 16, 2), 256, 0, stream>>>(
      ovb, woT, outP, 1024, 2048, 2048, 2048, 1024, 1024, 4194304);
  add_f32<<<4096, 256, 0, stream>>>(outP, outP + 4194304, out, 4194304);
}

// Round 11
// 461.605 us; speedup vs baseline: 1.3137x; 1.0445x over previous
//
#include <hip/hip_runtime.h>
#include <math.h>

// DeepSeek V2 MLA attention — bf16 MFMA GEMMs + split-K flash attention with
// a dynamic work queue (v11). v11 = v10 with launch-count 21 -> 11:
// ~200us of the 482 total is unaccounted by per-kernel cost models; prime
// suspect is inter-dispatch gaps (20 graph edges x ~5-10us). prep_all fuses
// rope_table + 2 casts + 5 transposes into one 20352-block launch;
// norm_fused fuses rmsnorm_cast + build_kfull; init_ctr folds into rope_qpe.
// attn (v9 structure, 169us plateau) and split-K GEMMs unchanged.
// B=1 S=2048 E=2048 H=16 DN=128 DR=64 DV=128 R=512 QLR=1536

typedef unsigned short u16;
typedef unsigned int u32;
typedef __bf16 bf16x8 __attribute__((ext_vector_type(8)));
typedef float f32x4 __attribute__((ext_vector_type(4)));
typedef unsigned short u16x8 __attribute__((ext_vector_type(8)));

__device__ __forceinline__ u16 f2b(float f) {  // fp32 -> bf16 RNE
  u32 u = __float_as_uint(f);
  u += 0x7FFFu + ((u >> 16) & 1u);
  return (u16)(u >> 16);
}
__device__ __forceinline__ float b2f(u16 v) {
  return __uint_as_float(((u32)v) << 16);
}

#define GLDS(g, l) __builtin_amdgcn_global_load_lds( \
    (const __attribute__((address_space(1))) u32*)(g), \
    (__attribute__((address_space(3))) u32*)(l), 16, 0, 0)

#define MFMA(a, b, c) __builtin_amdgcn_mfma_f32_16x16x32_bf16(a, b, c, 0, 0, 0)

// s_waitcnt vmcnt(N) (lgkmcnt/expcnt untouched) + s_barrier.
template<int N>
__device__ __forceinline__ void vm_barrier() {
  __builtin_amdgcn_s_waitcnt(0xF70 | N);  // expcnt=7, lgkmcnt=15, vmcnt=N
  __builtin_amdgcn_s_barrier();
}

// Per-group (2 heads) items enumerated qt-descending (heavy first):
// for qt=31..0, kc=0..nkc-1, hh=0..1.  nkc(qt) = ceil((qt/2+1)/4).
// Per-group total = 160; global slot = g*160 + local.
#define N_ITEMS_G 160
__device__ __forceinline__ int nkc_of(int qt) { return (((qt >> 1) + 1) + 3) >> 2; }

// ---------------- block reduction helper ----------------
__device__ __forceinline__ float block_sum(float v, float* red) {
#pragma unroll
  for (int off = 32; off > 0; off >>= 1) v += __shfl_down(v, off);
  const int lane = threadIdx.x & 63, w = threadIdx.x >> 6;
  if (lane == 0) red[w] = v;
  __syncthreads();
  float r = red[0] + red[1] + red[2] + red[3];
  __syncthreads();
  return r;
}

// ---------------- bf16 MFMA GEMM, 128x128 tile, BK=32, pipelined ------------
// C = A[M,K] @ B[N,K]^T (both row-major bf16). Batched over blockIdx.z.
// Split-K reuses z with sA=sB=K-offset, sC=partial-buffer stride.
// OUTK: 0 = fp32 out, 1 = bf16 out, 2 = bf16 transposed out (C[n*ldc+m]).
template<int OUTK>
__global__ __launch_bounds__(256) void gemm_mfma(
    const u16* __restrict__ A, const u16* __restrict__ B, void* __restrict__ Cv,
    int K, int lda, int ldb, int ldc, long sA, long sB, long sC)
{
  __shared__ u16 At[3][4096];  // triple-buffered 128x32 tiles
  __shared__ u16 Bt[3][4096];
  const u16* Ab = A + (long)blockIdx.z * sA;
  const u16* Bb = B + (long)blockIdx.z * sB;
  const int tid = threadIdx.x;
  const int w = tid >> 6, lane = tid & 63;
  const int m0 = blockIdx.y * 128, n0 = blockIdx.x * 128;
  const int wm = (w >> 1) * 64, wn = (w & 1) * 64;
  const int fr = lane & 15, fq = lane >> 4;

  const int c0 = w * 2, c1 = w * 2 + 1;
  const int e0 = (c0 * 64 + lane) * 8, e1 = (c1 * 64 + lane) * 8;
  const int r0 = e0 >> 5, col0 = e0 & 31;
  const int r1 = e1 >> 5, col1 = e1 & 31;

  const int nk = K >> 5;
  auto issue = [&](int kc) {
    const int k0 = kc * 32;
    u16* at = At[kc % 3];
    u16* bt = Bt[kc % 3];
    GLDS(Ab + (long)(m0 + r0) * lda + k0 + col0, at + c0 * 512);
    GLDS(Bb + (long)(n0 + r0) * ldb + k0 + col0, bt + c0 * 512);
    GLDS(Ab + (long)(m0 + r1) * lda + k0 + col1, at + c1 * 512);
    GLDS(Bb + (long)(n0 + r1) * ldb + k0 + col1, bt + c1 * 512);
  };

  f32x4 acc[4][4] = {};
  issue(0);
  issue(1);
  vm_barrier<4>();
  for (int kc = 0; kc < nk; ++kc) {
    if (kc + 2 < nk) issue(kc + 2);
    const u16* at = At[kc % 3];
    const u16* bt = Bt[kc % 3];
    bf16x8 af[4], bfr[4];
#pragma unroll
    for (int i = 0; i < 4; ++i)
      af[i] = *(const bf16x8*)(at + (wm + i * 16 + fr) * 32 + fq * 8);
#pragma unroll
    for (int j = 0; j < 4; ++j)
      bfr[j] = *(const bf16x8*)(bt + (wn + j * 16 + fr) * 32 + fq * 8);
#pragma unroll
    for (int i = 0; i < 4; ++i)
#pragma unroll
      for (int j = 0; j < 4; ++j)
        acc[i][j] = MFMA(af[i], bfr[j], acc[i][j]);
    if (kc + 1 < nk) {
      if (kc + 2 < nk) vm_barrier<4>();
      else vm_barrier<0>();
    }
  }

  if (OUTK == 0) {
    float* C = (float*)Cv + (long)blockIdx.z * sC;
#pragma unroll
    for (int i = 0; i < 4; ++i)
#pragma unroll
      for (int j = 0; j < 4; ++j) {
        long base = (long)(m0 + wm + i * 16 + fq * 4) * ldc + (n0 + wn + j * 16 + fr);
#pragma unroll
        for (int r = 0; r < 4; ++r) C[base + (long)r * ldc] = acc[i][j][r];
      }
  } else if (OUTK == 1) {
    u16* C = (u16*)Cv + (long)blockIdx.z * sC;
#pragma unroll
    for (int i = 0; i < 4; ++i)
#pragma unroll
      for (int j = 0; j < 4; ++j) {
        long base = (long)(m0 + wm + i * 16 + fq * 4) * ldc + (n0 + wn + j * 16 + fr);
#pragma unroll
        for (int r = 0; r < 4; ++r) C[base + (long)r * ldc] = f2b(acc[i][j][r]);
      }
  } else {
    u16* C = (u16*)Cv + (long)blockIdx.z * sC;
#pragma unroll
    for (int i = 0; i < 4; ++i)
#pragma unroll
      for (int j = 0; j < 4; ++j) {
        ushort4 v = { f2b(acc[i][j][0]), f2b(acc[i][j][1]),
                      f2b(acc[i][j][2]), f2b(acc[i][j][3]) };
        *(ushort4*)(C + (long)(n0 + wn + j * 16 + fr) * ldc + (m0 + wm + i * 16 + fq * 4)) = v;
      }
  }
}

// ---------------- split-K combine: o = a + b (fp32, float4) ----------------
__global__ __launch_bounds__(256) void add_f32(const float* __restrict__ a,
    const float* __restrict__ b, float* __restrict__ o, long n) {
  long i = ((long)blockIdx.x * 256 + threadIdx.x) * 4;
  if (i >= n) return;
  float4 va = *(const float4*)(a + i);
  float4 vb = *(const float4*)(b + i);
  float4 vo = { va.x + vb.x, va.y + vb.y, va.z + vb.z, va.w + vb.w };
  *(float4*)(o + i) = vo;
}

// ---------------- fused prep: rope_table + casts + transposes ----------------
// One launch replacing 8. Flattened grid, block-uniform section decode:
//   s0 rope_table            256
//   s1 cast x -> xb         4096
//   s2 cast w_kv_b -> wkvbb 2048
//   s3 T w_q_a  -> wabT      48x64  = 3072
//   s4 T w_kv_a -> wabT+     18x64  = 1152
//   s5 T w_q_b  -> wqbT      96x48  = 4608
//   s6 T w_kv_b+128 -> wuvT  4x16x16= 1024
//   s7 T w_o    -> woT       64x64  = 4096   (total 20352)
__device__ __forceinline__ void cast4(const float* __restrict__ in,
                                      u16* __restrict__ out, int id) {
  long i = ((long)id * 256 + threadIdx.x) * 4;
  float4 v = *(const float4*)(in + i);
  ushort4 o = { f2b(v.x), f2b(v.y), f2b(v.z), f2b(v.w) };
  *(ushort4*)(out + i) = o;
}
__device__ __forceinline__ void t32(const float* __restrict__ in,
    u16* __restrict__ out, int ldi, int ldo, int bx, int by, u16 (*t)[33]) {
  const int i0 = by * 32, j0 = bx * 32;
  const int tx = threadIdx.x & 31, ty = threadIdx.x >> 5;
  for (int r = ty; r < 32; r += 8)
    t[r][tx] = f2b(in[(long)(i0 + r) * ldi + j0 + tx]);
  __syncthreads();
  for (int r = ty; r < 32; r += 8)
    out[(long)(j0 + r) * ldo + i0 + tx] = t[tx][r];
}
__global__ __launch_bounds__(256) void prep_all(
    const float* __restrict__ x, const float* __restrict__ w_q_a,
    const float* __restrict__ w_kv_a, const float* __restrict__ w_q_b,
    const float* __restrict__ w_kv_b, const float* __restrict__ w_o,
    float* __restrict__ tab, u16* __restrict__ xb, u16* __restrict__ wkvbb,
    u16* __restrict__ wabT, u16* __restrict__ wqbT, u16* __restrict__ wuvT,
    u16* __restrict__ woT)
{
  __shared__ u16 t[32][33];
  int id = blockIdx.x;
  if (id < 256) {                                   // s0 rope table
    int s = id * 8 + (threadIdx.x >> 5), j = threadIdx.x & 31;
    double freq = pow(10000.0, -(double)j / 32.0);
    double ang = (double)s * freq;
    tab[s * 64 + j] = (float)cos(ang);
    tab[s * 64 + 32 + j] = (float)sin(ang);
    return;
  }
  id -= 256;
  if (id < 4096) { cast4(x, xb, id); return; }      // s1
  id -= 4096;
  if (id < 2048) { cast4(w_kv_b, wkvbb, id); return; }  // s2
  id -= 2048;
  if (id < 3072) { t32(w_q_a, wabT, 1536, 2048, id % 48, id / 48, t); return; }
  id -= 3072;
  if (id < 1152) { t32(w_kv_a, wabT + 1536 * 2048, 576, 2048, id % 18, id / 18, t); return; }
  id -= 1152;
  if (id < 4608) { t32(w_q_b, wqbT, 3072, 1536, id % 96, id / 96, t); return; }
  id -= 4608;
  if (id < 1024) {                                  // s6 wuvT (batched z=16)
    int z = id >> 6, r6 = id & 63;
    t32(w_kv_b + 128 + (long)z * 256, wuvT + (long)z * 65536, 4096, 512,
        r6 & 3, r6 >> 2, t);
    return;
  }
  id -= 1024;
  t32(w_o, woT, 2048, 2048, id & 63, id >> 6, t);   // s7
}

// ---------------- fused norm phase: rmsnorm(q_a) + build_kfull --------------
// blocks 0..2047: qab row; blocks 2048..4095: kfb row. qacB/in2 optional
// (split-K partial second stream, summed in-pass).
__global__ __launch_bounds__(256) void norm_fused(
    const float* __restrict__ qac, const float* __restrict__ q_ln,
    u16* __restrict__ qab, const float* __restrict__ kv_ln,
    const float* __restrict__ tab, u16* __restrict__ kfb,
    const float* __restrict__ qacB)
{
  __shared__ float red[4];
  const int b = blockIdx.x;
  if (b < 2048) {                                   // rmsnorm q_a -> qab
    const float* row = qac + (long)b * 2176;
    const float* row2 = qacB ? qacB + (long)b * 2176 : nullptr;
    u16* orow = qab + (long)b * 1536;
    float ss = 0.f;
    if (row2) {
      for (int i = threadIdx.x; i < 1536; i += 256) {
        float v = row[i] + row2[i]; ss += v * v;
      }
    } else {
      for (int i = threadIdx.x; i < 1536; i += 256) { float v = row[i]; ss += v * v; }
    }
    float tot = block_sum(ss, red);
    float inv = rsqrtf(tot / 1536.0f + 1e-6f);
    if (row2) {
      for (int i = threadIdx.x; i < 1536; i += 256)
        orow[i] = f2b((row[i] + row2[i]) * inv * q_ln[i]);
    } else {
      for (int i = threadIdx.x; i < 1536; i += 256)
        orow[i] = f2b(row[i] * inv * q_ln[i]);
    }
  } else {                                          // build_kfull -> kfb
    const int s = b - 2048;
    const float* row = qac + 1536 + (long)s * 2176;
    const float* row2 = qacB ? qacB + 1536 + (long)s * 2176 : nullptr;
    float ss = 0.f;
    if (row2) {
      for (int i = threadIdx.x; i < 512; i += 256) {
        float v = row[i] + row2[i]; ss += v * v;
      }
    } else {
      for (int i = threadIdx.x; i < 512; i += 256) { float v = row[i]; ss += v * v; }
    }
    float tot = block_sum(ss, red);
    float inv = rsqrtf(tot / 512.0f + 1e-6f);
    u16* orow = kfb + (long)s * 576;
    if (row2) {
      for (int i = threadIdx.x; i < 512; i += 256)
        orow[i] = f2b((row[i] + row2[i]) * inv * kv_ln[i]);
    } else {
      for (int i = threadIdx.x; i < 512; i += 256)
        orow[i] = f2b(row[i] * inv * kv_ln[i]);
    }
    if (threadIdx.x < 64) {
      int i = threadIdx.x, j = i & 31;
      float c = tab[s * 64 + j], sn = tab[s * 64 + 32 + j];
      float xv = row[512 + i] + (row2 ? row2[512 + i] : 0.f);
      float rv = (i < 32) ? row[512 + i + 32] + (row2 ? row2[512 + i + 32] : 0.f)
                          : row[512 + i - 32] + (row2 ? row2[512 + i - 32] : 0.f);
      float rot = (i < 32) ? -rv : rv;
      orow[512 + i] = f2b(xv * c + rot * sn);
    }
  }
}

// ---------------- split-K flash attention, XCD-partitioned queue ------------
// 512 persistent blocks (2/CU, all resident). Block b -> group g = b&7
// (XCD-aligned), processes heads {g, g+8} only; V (2x524KB) + K (2.3MB) stay
// L2-resident per XCD. Item = (hh, qt, kc): q-rows [qt*64,+64) of head g+8*hh
// vs K-tiles [4kc, min(4kc+4, ktt)).
// K staging: 9 groups of 64-k per tile, triple-buffered (3 x 16KB), running
// buffer index mod 3 across tiles; ONE vm_barrier<4> per group. LDS 65.5 KiB.
// __launch_bounds__(256,2): 256 regs/wave, ~190-reg demand fits spill-free.
__global__ __launch_bounds__(256, 2) void attn_partial(
    const u16* __restrict__ qfb,   // [2048][16*576]
    const u16* __restrict__ kfb,   // [2048][576]
    const u16* __restrict__ vallT, // [16][128][2048]
    u32* __restrict__ ctr,         // [8]
    u16* __restrict__ pO,          // [1280][64][128]
    float* __restrict__ pS)        // [1280][64][2]
{
  __shared__ u16 Ks[3 * 8192];   // 3 bufs x (2 chunks x [128 rows][32 k])
  __shared__ u16 Ps[4 * 2176];   // per-wave P, 16 rows x 136 stride
  __shared__ u32 cur;

  const int tid = threadIdx.x;
  const int w = tid >> 6, lane = tid & 63;
  const int fr = lane & 15, fq = lane >> 4;
  const float scale = 0.07216878364870323f;  // (DN+DR)^-0.5
  const int grp = (int)(blockIdx.x & 7);     // XCD-aligned head group
  u16* Psw = Ps + w * 2176;

  const int krow0 = (w * 2) * 16 + (lane >> 2);
  const int krow1 = (w * 2 + 1) * 16 + (lane >> 2);
  const int kg0 = (lane & 3) ^ (krow0 & 3);
  const int kg1 = (lane & 3) ^ (krow1 & 3);

  while (true) {
    if (tid == 0) cur = atomicAdd(&ctr[grp], 1u);
    __syncthreads();
    const u32 it = cur;
    if (it >= N_ITEMS_G) break;

    // decode group-local item (qt descending; within qt: kc asc, hh 0..1)
    int rem = (int)it, qt = 31, kc = 0, hh = 0;
    for (int q = 31; q >= 0; --q) {
      int cnt = nkc_of(q) * 2;
      if (rem < cnt) { qt = q; kc = rem >> 1; hh = rem & 1; break; }
      rem -= cnt;
    }
    const int h = grp + hh * 8;
    const u32 gslot = (u32)grp * N_ITEMS_G + it;   // global partial slot
    const int q0 = qt * 64;
    const int ktt = (qt >> 1) + 1;
    const int kt0 = kc * 4, kt1 = min(kt0 + 4, ktt);

    // Q fragments resident (A[m=fr][k=fq*8+j])
    bf16x8 aq[18];
    {
      const u16* qp = qfb + (long)(q0 + w * 16 + fr) * 9216 + h * 576 + fq * 8;
#pragma unroll
      for (int d = 0; d < 18; ++d) aq[d] = *(const bf16x8*)(qp + d * 32);
    }

    float m_run[4], l_run[4];
#pragma unroll
    for (int r = 0; r < 4; ++r) { m_run[r] = -1e30f; l_run[r] = 0.f; }
    f32x4 Oacc[8] = {};
    // per-lane V fragment base: frag(jv,ks) = vlane + k0 + jv*32768 + ks*32
    const u16* vlane = vallT + (long)h * 262144 + (long)fr * 2048 + fq * 8;

    // Stage one 64-k group (2 chunks, 4 GLDS/thread) into buffer gb (0..2).
    auto issueG = [&](int kt, int gk, int gb) {
      const int k0i = kt * 128;
      u16* buf = Ks + gb * 8192;
#pragma unroll
      for (int c = 0; c < 2; ++c) {
        const int d0 = (gk * 2 + c) * 32;
        u16* dst = buf + c * 4096;
        GLDS(kfb + (long)(k0i + krow0) * 576 + d0 + kg0 * 8, dst + (w * 2) * 512);
        GLDS(kfb + (long)(k0i + krow1) * 576 + d0 + kg1 * 8, dst + (w * 2 + 1) * 512);
      }
    };

    issueG(kt0, 0, 0);
    issueG(kt0, 1, 1);

    for (int kt = kt0; kt < kt1; ++kt) {
      const int k0 = kt * 128;
      // group0 of this tile landed block-wide; also WAR-protects buf2.
      vm_barrier<4>();

      f32x4 sc[8] = {};
#pragma unroll
      for (int g = 0; g < 9; ++g) {
        const int gg = g + 2;
        if (gg <= 8) issueG(kt, gg, gg % 3);
        else if (kt + 1 < kt1) issueG(kt + 1, gg - 9, gg % 3);  // 9,10 -> 0,1
        const u16* kb0 = Ks + (g % 3) * 8192;
        __builtin_amdgcn_s_setprio(1);
#pragma unroll
        for (int c = 0; c < 2; ++c) {
          const int d = 2 * g + c;
          const u16* kb = kb0 + c * 4096;
#pragma unroll
          for (int j = 0; j < 8; ++j) {
            const int row = j * 16 + fr;
            bf16x8 b = *(const bf16x8*)(kb + row * 32 + ((fq ^ (row & 3)) * 8));
            sc[j] = MFMA(aq[d], b, sc[j]);
          }
        }
        __builtin_amdgcn_s_setprio(0);
        if (g < 8) vm_barrier<4>();  // next group landed; frees buf[g%3]
      }

      // V ks-group 0 into dual register buffers (L2-resident; latency hidden
      // under softmax). No barrier needed: V loads don't touch LDS.
      const u16* vk = vlane + k0;
      bf16x8 vA[4], vB[4];
#pragma unroll
      for (int q = 0; q < 4; ++q) {
        vA[q] = *(const bf16x8*)(vk + (long)q * 32768);
        vB[q] = *(const bf16x8*)(vk + (long)(q + 4) * 32768);
      }

      // wave-local online softmax
      const bool diag = (kt == ktt - 1);
#pragma unroll
      for (int r = 0; r < 4; ++r) {
        float mx = m_run[r];
#pragma unroll
        for (int j = 0; j < 8; ++j) {
          float s = sc[j][r] * scale;
          if (diag) {
            const int row = q0 + w * 16 + fq * 4 + r;
            const int col = k0 + j * 16 + fr;
            if (col > row) s = -1e30f;
          }
          sc[j][r] = s;
          mx = fmaxf(mx, s);
        }
        mx = fmaxf(mx, __shfl_xor(mx, 1));
        mx = fmaxf(mx, __shfl_xor(mx, 2));
        mx = fmaxf(mx, __shfl_xor(mx, 4));
        mx = fmaxf(mx, __shfl_xor(mx, 8));
        const float alpha = __expf(m_run[r] - mx);
        m_run[r] = mx;
        float sum = 0.f;
#pragma unroll
        for (int j = 0; j < 8; ++j) {
          float p = __expf(sc[j][r] - mx);
          sc[j][r] = p;
          sum += p;
        }
        sum += __shfl_xor(sum, 1);
        sum += __shfl_xor(sum, 2);
        sum += __shfl_xor(sum, 4);
        sum += __shfl_xor(sum, 8);
        l_run[r] = l_run[r] * alpha + sum;
#pragma unroll
        for (int jv = 0; jv < 8; ++jv) Oacc[jv][r] *= alpha;
#pragma unroll
        for (int j = 0; j < 8; ++j)
          Psw[(fq * 4 + r) * 136 + j * 16 + fr] = f2b(sc[j][r]);
      }

      // PV: O += P @ V^T, V fragments ping-ponged from global (no barrier)
#pragma unroll
      for (int ks = 0; ks < 4; ++ks) {
        bf16x8 ap = *(const bf16x8*)(Psw + fr * 136 + ks * 32 + fq * 8);
        __builtin_amdgcn_s_setprio(1);
#pragma unroll
        for (int q = 0; q < 4; ++q) Oacc[q] = MFMA(ap, vA[q], Oacc[q]);
        __builtin_amdgcn_s_setprio(0);
        if (ks < 3) {
#pragma unroll
          for (int q = 0; q < 4; ++q)
            vA[q] = *(const bf16x8*)(vk + (long)q * 32768 + (ks + 1) * 32);
        }
        __builtin_amdgcn_s_setprio(1);
#pragma unroll
        for (int q = 0; q < 4; ++q) Oacc[q + 4] = MFMA(ap, vB[q], Oacc[q + 4]);
        __builtin_amdgcn_s_setprio(0);
        if (ks < 3) {
#pragma unroll
          for (int q = 0; q < 4; ++q)
            vB[q] = *(const bf16x8*)(vk + (long)(q + 4) * 32768 + (ks + 1) * 32);
        }
      }
    }

    // write partial: raw O (bf16) + per-row stats
    const long po = (long)gslot * 8192;
#pragma unroll
    for (int r = 0; r < 4; ++r) {
      const int lr = w * 16 + fq * 4 + r;
      if (fr == 0) {
        pS[((long)gslot * 64 + lr) * 2] = m_run[r];
        pS[((long)gslot * 64 + lr) * 2 + 1] = l_run[r];
      }
#pragma unroll
      for (int jv = 0; jv < 8; ++jv)
        pO[po + (long)lr * 128 + jv * 16 + fr] = f2b(Oacc[jv][r]);
    }
  }
}

// ---------------- combine partials (log-sum-exp weights) ----------------
__global__ __launch_bounds__(256) void attn_reduce(
    const u16* __restrict__ pO, const float* __restrict__ pS,
    u16* __restrict__ ovb)
{
  const int h = blockIdx.x, qt = blockIdx.y;
  const int g = h & 7, hh = h >> 3;
  const int ktt = (qt >> 1) + 1;
  const int nkc = (ktt + 3) >> 2;
  int base = g * N_ITEMS_G;
  for (int q = qt + 1; q < 32; ++q) base += nkc_of(q) * 2;
  const int tid = threadIdx.x;
  const int r = tid >> 2, cq = (tid & 3) * 32;

  float m[4], l[4], wgt[4];
  float M = -1e30f;
  for (int i = 0; i < nkc; ++i) {
    const long slot = base + i * 2 + hh;
    m[i] = pS[(slot * 64 + r) * 2];
    l[i] = pS[(slot * 64 + r) * 2 + 1];
    M = fmaxf(M, m[i]);
  }
  float L = 0.f;
  for (int i = 0; i < nkc; ++i) { wgt[i] = __expf(m[i] - M); L += l[i] * wgt[i]; }
  const float inv = 1.0f / L;

  u16* orow = ovb + (long)(qt * 64 + r) * 2048 + h * 128 + cq;
  for (int c8 = 0; c8 < 32; c8 += 8) {
    float acc[8] = {};
    for (int i = 0; i < nkc; ++i) {
      const long slot = base + i * 2 + hh;
      const u16x8 v = *(const u16x8*)(pO + (slot * 64 + r) * 128 + cq + c8);
#pragma unroll
      for (int e = 0; e < 8; ++e) acc[e] += b2f(v[e]) * wgt[i];
    }
    u16x8 o;
#pragma unroll
    for (int e = 0; e < 8; ++e) o[e] = f2b(acc[e] * inv);
    *(u16x8*)(orow + c8) = o;
  }
}

// ---------------- roped q_pe (bf16 in) into qfb[..., 512:576] ----------------
// grid 2048 x 256 threads: thread (h = t>>4, 4 i's). Block 0 also zeroes the
// 8 attn queue counters (runs before attn_partial in-stream).
__global__ __launch_bounds__(256) void rope_qpe(const u16* __restrict__ qb,
    const float* __restrict__ tab, u16* __restrict__ qfb, u32* __restrict__ ctr) {
  const int s = blockIdx.x;
  if (s == 0 && threadIdx.x < 8) ctr[threadIdx.x] = 0;
  const int h = threadIdx.x >> 4;
  const int i0 = (threadIdx.x & 15) * 4;
  const u16* src = qb + (long)s * 3072 + h * 192 + 128;
  u16* dst = qfb + (long)s * 9216 + h * 576 + 512;
#pragma unroll
  for (int k = 0; k < 4; ++k) {
    const int i = i0 + k, j = i & 31;
    float c = tab[s * 64 + j], sn = tab[s * 64 + 32 + j];
    float xv = b2f(src[i]);
    float rot = (i < 32) ? -b2f(src[i + 32]) : b2f(src[i - 32]);
    dst[i] = f2b(xv * c + rot * sn);
  }
}

extern "C" void kernel_launch(void* const* d_in, const int* in_sizes, int n_in,
                              void* d_out, int out_size, void* d_ws, size_t ws_size,
                              hipStream_t stream) {
  const float* x      = (const float*)d_in[0];
  const float* w_q_a  = (const float*)d_in[1];
  const float* q_ln   = (const float*)d_in[2];
  const float* w_q_b  = (const float*)d_in[3];
  const float* w_kv_a = (const float*)d_in[4];
  const float* kv_ln  = (const float*)d_in[5];
  const float* w_kv_b = (const float*)d_in[6];
  const float* w_o    = (const float*)d_in[7];
  float* out = (float*)d_out;

  // ---- fixed workspace (bytes) ----
  char* p = (char*)d_ws;
  float* tab   = (float*)p;  p += 524288;      // 2048*64 f32
  u16* wkvbb   = (u16*)p;    p += 4194304;     // 512*4096
  u16* wuvT    = (u16*)p;    p += 2097152;     // 16*128*512
  u16* woT     = (u16*)p;    p += 8388608;     // 2048*2048
  u16* qfb     = (u16*)p;    p += 37748736;    // 2048*9216
  u16* vallT   = (u16*)p;    p += 8388608;     // 16*128*2048
  u16* kfb     = (u16*)p;    p += 2359296;     // 2048*576
  u16* ovb     = (u16*)p;    p += 8388608;     // 2048*2048
  char* tb = p;
  // phase 1 transient (63.44 MB):
  u16* xb      = (u16*)tb;                     // 2048*2048            (8.39 MB)
  u16* wabT    = (u16*)(tb + 8388608);         // 2176*2048 (qa++kva transposed)
  float* qac   = (float*)(tb + 17301504);      // 2048*2176 f32 (qa | ckv_kpe)
  u16* qab     = (u16*)(tb + 35127296);        // 2048*1536
  u16* wqbT    = (u16*)(tb + 41418752);        // 3072*1536
  u16* qb      = (u16*)(tb + 50855936);        // 2048*3072  (ends 63,438,848)
  // gated split-K partial for GEMM1 (needs ws >= ~155 MB):
  float* qacB  = (float*)(tb + 63438848);      // 2048*2176 f32 (17.8 MB)
  const size_t need_split1 = (size_t)(tb - (char*)d_ws) + 63438848 + 17825792;
  const bool split1 = ws_size >= need_split1;
  // phase 2 transient (aliases phase 1, used only after it is dead):
  u16* pO      = (u16*)tb;                     // 1280*64*128 bf16 (21 MB)
  float* pS    = (float*)(tb + 20971520);      // 1280*64*2 f32
  u32* ctr     = (u32*)(tb + 21626880);        // 8 group counters
  // phase 3 transient (after attn_reduce; pO/pS/ctr dead):
  float* outP  = (float*)tb;                   // 2 x 2048*2048 f32 (33.5 MB)

  // fused prep: rope table + casts + transposes (one launch, 20352 blocks)
  prep_all<<<dim3(20352), 256, 0, stream>>>(
      x, w_q_a, w_kv_a, w_q_b, w_kv_b, w_o,
      tab, xb, wkvbb, wabT, wqbT, wuvT, woT);

  // fused: [q_a | ckv_kpe] = x @ [w_q_a | w_kv_a]  (f32, ldc 2176)
  // split-K=2 (2 blocks/CU) when workspace allows; consumers sum the halves.
  if (split1) {
    gemm_mfma<0><<<dim3(17, 16, 2), 256, 0, stream>>>(
        xb, wabT, qac, 1024, 2048, 2048, 2176, 1024, 1024, (long)(qacB - qac));
  } else {
    gemm_mfma<0><<<dim3(17, 16), 256, 0, stream>>>(
        xb, wabT, qac, 2048, 2048, 2048, 2176, 0, 0, 0);
  }
  // fused rmsnorm(q_a) -> qab  +  build_kfull -> kfb (one launch)
  norm_fused<<<dim3(4096), 256, 0, stream>>>(
      qac, q_ln, qab, kv_ln, tab, kfb, split1 ? qacB : nullptr);

  // q = q_a @ w_q_b (bf16 out; 384 blocks = 1.5/CU)
  gemm_mfma<1><<<dim3(24, 16), 256, 0, stream>>>(
      qab, wqbT, qb, 1536, 1536, 1536, 3072, 0, 0, 0);

  // q_full[:, h, :512] = q_nope[h] @ w_uk[h]^T (bf16 out, batched over h)
  gemm_mfma<1><<<dim3(4, 16, 16), 256, 0, stream>>>(
      qb, wkvbb, qfb, 128, 3072, 4096, 9216, 192, 256, 576);
  rope_qpe<<<dim3(2048), 256, 0, stream>>>(qb, tab, qfb, ctr);  // + ctr zero

  // vallT[h] = (ckv_n @ w_uv[h])^T  (bf16 transposed out)
  gemm_mfma<2><<<dim3(1, 16, 16), 256, 0, stream>>>(
      kfb, wuvT, vallT, 512, 576, 512, 2048, 0, 65536, 262144);

  // split-K flash attention, XCD-partitioned dynamic queues (512 = 2/CU)
  attn_partial<<<dim3(512), 256, 0, stream>>>(qfb, kfb, vallT, ctr, pO, pS);
  attn_reduce<<<dim3(16, 32), 256, 0, stream>>>(pO, pS, ovb);

  // y = o_v @ w_o: split-K=2 (512 blocks = 2/CU) into fp32 partials + add
  gemm_mfma<0><<<dim3(16, 16, 2), 256, 0, stream>>>(
      ovb, woT, outP, 1024, 2048, 2048, 2048, 1024, 1024, 4194304);
  add_f32<<<4096, 256, 0, stream>>>(outP, outP + 4194304, out, 4194304);
}

// Round 14
// 454.400 us; speedup vs baseline: 1.3345x; 1.0159x over previous
//
#include <hip/hip_runtime.h>
#include <math.h>

// DeepSeek V2 MLA attention — bf16 MFMA GEMMs + split-K flash attention with
// a dynamic work queue (v12). v12 = v11 with: (1) GEMM1 split-K partial
// buffer moved into the qfb region (dead until mid_fused) -> split always on
// (v10/v11's ws_size gate likely disabled it); (2) mid_fused unions GEMM3 +
// vallT-GEMM + rope_qpe (independent, disjoint outputs) into one 3328-block
// launch so the lonely 1-block/CU vallT GEMM co-schedules instead of
// serializing; launches 11 -> 9. attn (169us plateau) untouched.
// B=1 S=2048 E=2048 H=16 DN=128 DR=64 DV=128 R=512 QLR=1536

typedef unsigned short u16;
typedef unsigned int u32;
typedef __bf16 bf16x8 __attribute__((ext_vector_type(8)));
typedef float f32x4 __attribute__((ext_vector_type(4)));
typedef unsigned short u16x8 __attribute__((ext_vector_type(8)));

__device__ __forceinline__ u16 f2b(float f) {  // fp32 -> bf16 RNE
  u32 u = __float_as_uint(f);
  u += 0x7FFFu + ((u >> 16) & 1u);
  return (u16)(u >> 16);
}
__device__ __forceinline__ float b2f(u16 v) {
  return __uint_as_float(((u32)v) << 16);
}

#define GLDS(g, l) __builtin_amdgcn_global_load_lds( \
    (const __attribute__((address_space(1))) u32*)(g), \
    (__attribute__((address_space(3))) u32*)(l), 16, 0, 0)

#define MFMA(a, b, c) __builtin_amdgcn_mfma_f32_16x16x32_bf16(a, b, c, 0, 0, 0)

// s_waitcnt vmcnt(N) (lgkmcnt/expcnt untouched) + s_barrier.
template<int N>
__device__ __forceinline__ void vm_barrier() {
  __builtin_amdgcn_s_waitcnt(0xF70 | N);  // expcnt=7, lgkmcnt=15, vmcnt=N
  __builtin_amdgcn_s_barrier();
}

// Per-group (2 heads) items enumerated qt-descending (heavy first):
// for qt=31..0, kc=0..nkc-1, hh=0..1.  nkc(qt) = ceil((qt/2+1)/4).
// Per-group total = 160; global slot = g*160 + local.
#define N_ITEMS_G 160
__device__ __forceinline__ int nkc_of(int qt) { return (((qt >> 1) + 1) + 3) >> 2; }

// ---------------- block reduction helper ----------------
__device__ __forceinline__ float block_sum(float v, float* red) {
#pragma unroll
  for (int off = 32; off > 0; off >>= 1) v += __shfl_down(v, off);
  const int lane = threadIdx.x & 63, w = threadIdx.x >> 6;
  if (lane == 0) red[w] = v;
  __syncthreads();
  float r = red[0] + red[1] + red[2] + red[3];
  __syncthreads();
  return r;
}

// ---------------- bf16 MFMA GEMM body, 128x128 tile, BK=32, pipelined -------
// C = A[M,K] @ B[N,K]^T (both row-major bf16). (bx,by,bz) = tile coords.
// Split-K / batch via bz with sA=sB=offset, sC=output stride.
// OUTK: 0 = fp32 out, 1 = bf16 out, 2 = bf16 transposed out (C[n*ldc+m]).
template<int OUTK>
__device__ __forceinline__ void gemm_body(
    const u16* __restrict__ A, const u16* __restrict__ B, void* __restrict__ Cv,
    int K, int lda, int ldb, int ldc, long sA, long sB, long sC,
    int bx, int by, int bz, u16 (*At)[4096], u16 (*Bt)[4096])
{
  const u16* Ab = A + (long)bz * sA;
  const u16* Bb = B + (long)bz * sB;
  const int tid = threadIdx.x;
  const int w = tid >> 6, lane = tid & 63;
  const int m0 = by * 128, n0 = bx * 128;
  const int wm = (w >> 1) * 64, wn = (w & 1) * 64;
  const int fr = lane & 15, fq = lane >> 4;

  const int c0 = w * 2, c1 = w * 2 + 1;
  const int e0 = (c0 * 64 + lane) * 8, e1 = (c1 * 64 + lane) * 8;
  const int r0 = e0 >> 5, col0 = e0 & 31;
  const int r1 = e1 >> 5, col1 = e1 & 31;

  const int nk = K >> 5;
  auto issue = [&](int kc) {
    const int k0 = kc * 32;
    u16* at = At[kc % 3];
    u16* bt = Bt[kc % 3];
    GLDS(Ab + (long)(m0 + r0) * lda + k0 + col0, at + c0 * 512);
    GLDS(Bb + (long)(n0 + r0) * ldb + k0 + col0, bt + c0 * 512);
    GLDS(Ab + (long)(m0 + r1) * lda + k0 + col1, at + c1 * 512);
    GLDS(Bb + (long)(n0 + r1) * ldb + k0 + col1, bt + c1 * 512);
  };

  f32x4 acc[4][4] = {};
  issue(0);
  issue(1);
  vm_barrier<4>();
  for (int kc = 0; kc < nk; ++kc) {
    if (kc + 2 < nk) issue(kc + 2);
    const u16* at = At[kc % 3];
    const u16* bt = Bt[kc % 3];
    bf16x8 af[4], bfr[4];
#pragma unroll
    for (int i = 0; i < 4; ++i)
      af[i] = *(const bf16x8*)(at + (wm + i * 16 + fr) * 32 + fq * 8);
#pragma unroll
    for (int j = 0; j < 4; ++j)
      bfr[j] = *(const bf16x8*)(bt + (wn + j * 16 + fr) * 32 + fq * 8);
#pragma unroll
    for (int i = 0; i < 4; ++i)
#pragma unroll
      for (int j = 0; j < 4; ++j)
        acc[i][j] = MFMA(af[i], bfr[j], acc[i][j]);
    if (kc + 1 < nk) {
      if (kc + 2 < nk) vm_barrier<4>();
      else vm_barrier<0>();
    }
  }

  if (OUTK == 0) {
    float* C = (float*)Cv + (long)bz * sC;
#pragma unroll
    for (int i = 0; i < 4; ++i)
#pragma unroll
      for (int j = 0; j < 4; ++j) {
        long base = (long)(m0 + wm + i * 16 + fq * 4) * ldc + (n0 + wn + j * 16 + fr);
#pragma unroll
        for (int r = 0; r < 4; ++r) C[base + (long)r * ldc] = acc[i][j][r];
      }
  } else if (OUTK == 1) {
    u16* C = (u16*)Cv + (long)bz * sC;
#pragma unroll
    for (int i = 0; i < 4; ++i)
#pragma unroll
      for (int j = 0; j < 4; ++j) {
        long base = (long)(m0 + wm + i * 16 + fq * 4) * ldc + (n0 + wn + j * 16 + fr);
#pragma unroll
        for (int r = 0; r < 4; ++r) C[base + (long)r * ldc] = f2b(acc[i][j][r]);
      }
  } else {
    u16* C = (u16*)Cv + (long)bz * sC;
#pragma unroll
    for (int i = 0; i < 4; ++i)
#pragma unroll
      for (int j = 0; j < 4; ++j) {
        ushort4 v = { f2b(acc[i][j][0]), f2b(acc[i][j][1]),
                      f2b(acc[i][j][2]), f2b(acc[i][j][3]) };
        *(ushort4*)(C + (long)(n0 + wn + j * 16 + fr) * ldc + (m0 + wm + i * 16 + fq * 4)) = v;
      }
  }
}

template<int OUTK>
__global__ __launch_bounds__(256) void gemm_mfma(
    const u16* __restrict__ A, const u16* __restrict__ B, void* __restrict__ Cv,
    int K, int lda, int ldb, int ldc, long sA, long sB, long sC)
{
  __shared__ u16 At[3][4096];
  __shared__ u16 Bt[3][4096];
  gemm_body<OUTK>(A, B, Cv, K, lda, ldb, ldc, sA, sB, sC,
                  blockIdx.x, blockIdx.y, blockIdx.z, At, Bt);
}

// ---------------- split-K combine: o = a + b (fp32, float4) ----------------
__global__ __launch_bounds__(256) void add_f32(const float* __restrict__ a,
    const float* __restrict__ b, float* __restrict__ o, long n) {
  long i = ((long)blockIdx.x * 256 + threadIdx.x) * 4;
  if (i >= n) return;
  float4 va = *(const float4*)(a + i);
  float4 vb = *(const float4*)(b + i);
  float4 vo = { va.x + vb.x, va.y + vb.y, va.z + vb.z, va.w + vb.w };
  *(float4*)(o + i) = vo;
}

// ---------------- fused prep: rope_table + casts + transposes ----------------
// One launch replacing 8. Flattened grid, block-uniform section decode:
//   s0 rope_table 256 | s1 cast x 4096 | s2 cast w_kv_b 2048 | s3 T w_q_a 3072
//   s4 T w_kv_a 1152 | s5 T w_q_b 4608 | s6 T w_kv_b+128 1024 | s7 T w_o 4096
__device__ __forceinline__ void cast4(const float* __restrict__ in,
                                      u16* __restrict__ out, int id) {
  long i = ((long)id * 256 + threadIdx.x) * 4;
  float4 v = *(const float4*)(in + i);
  ushort4 o = { f2b(v.x), f2b(v.y), f2b(v.z), f2b(v.w) };
  *(ushort4*)(out + i) = o;
}
__device__ __forceinline__ void t32(const float* __restrict__ in,
    u16* __restrict__ out, int ldi, int ldo, int bx, int by, u16 (*t)[33]) {
  const int i0 = by * 32, j0 = bx * 32;
  const int tx = threadIdx.x & 31, ty = threadIdx.x >> 5;
  for (int r = ty; r < 32; r += 8)
    t[r][tx] = f2b(in[(long)(i0 + r) * ldi + j0 + tx]);
  __syncthreads();
  for (int r = ty; r < 32; r += 8)
    out[(long)(j0 + r) * ldo + i0 + tx] = t[tx][r];
}
__global__ __launch_bounds__(256) void prep_all(
    const float* __restrict__ x, const float* __restrict__ w_q_a,
    const float* __restrict__ w_kv_a, const float* __restrict__ w_q_b,
    const float* __restrict__ w_kv_b, const float* __restrict__ w_o,
    float* __restrict__ tab, u16* __restrict__ xb, u16* __restrict__ wkvbb,
    u16* __restrict__ wabT, u16* __restrict__ wqbT, u16* __restrict__ wuvT,
    u16* __restrict__ woT)
{
  __shared__ u16 t[32][33];
  int id = blockIdx.x;
  if (id < 256) {                                   // s0 rope table
    int s = id * 8 + (threadIdx.x >> 5), j = threadIdx.x & 31;
    double freq = pow(10000.0, -(double)j / 32.0);
    double ang = (double)s * freq;
    tab[s * 64 + j] = (float)cos(ang);
    tab[s * 64 + 32 + j] = (float)sin(ang);
    return;
  }
  id -= 256;
  if (id < 4096) { cast4(x, xb, id); return; }      // s1
  id -= 4096;
  if (id < 2048) { cast4(w_kv_b, wkvbb, id); return; }  // s2
  id -= 2048;
  if (id < 3072) { t32(w_q_a, wabT, 1536, 2048, id % 48, id / 48, t); return; }
  id -= 3072;
  if (id < 1152) { t32(w_kv_a, wabT + 1536 * 2048, 576, 2048, id % 18, id / 18, t); return; }
  id -= 1152;
  if (id < 4608) { t32(w_q_b, wqbT, 3072, 1536, id % 96, id / 96, t); return; }
  id -= 4608;
  if (id < 1024) {                                  // s6 wuvT (batched z=16)
    int z = id >> 6, r6 = id & 63;
    t32(w_kv_b + 128 + (long)z * 256, wuvT + (long)z * 65536, 4096, 512,
        r6 & 3, r6 >> 2, t);
    return;
  }
  id -= 1024;
  t32(w_o, woT, 2048, 2048, id & 63, id >> 6, t);   // s7
}

// ---------------- fused norm phase: rmsnorm(q_a) + build_kfull --------------
// blocks 0..2047: qab row; blocks 2048..4095: kfb row. qacB = split-K second
// partial stream, summed in-pass.
__global__ __launch_bounds__(256) void norm_fused(
    const float* __restrict__ qac, const float* __restrict__ q_ln,
    u16* __restrict__ qab, const float* __restrict__ kv_ln,
    const float* __restrict__ tab, u16* __restrict__ kfb,
    const float* __restrict__ qacB)
{
  __shared__ float red[4];
  const int b = blockIdx.x;
  if (b < 2048) {                                   // rmsnorm q_a -> qab
    const float* row = qac + (long)b * 2176;
    const float* row2 = qacB + (long)b * 2176;
    u16* orow = qab + (long)b * 1536;
    float ss = 0.f;
    for (int i = threadIdx.x; i < 1536; i += 256) {
      float v = row[i] + row2[i]; ss += v * v;
    }
    float tot = block_sum(ss, red);
    float inv = rsqrtf(tot / 1536.0f + 1e-6f);
    for (int i = threadIdx.x; i < 1536; i += 256)
      orow[i] = f2b((row[i] + row2[i]) * inv * q_ln[i]);
  } else {                                          // build_kfull -> kfb
    const int s = b - 2048;
    const float* row = qac + 1536 + (long)s * 2176;
    const float* row2 = qacB + 1536 + (long)s * 2176;
    float ss = 0.f;
    for (int i = threadIdx.x; i < 512; i += 256) {
      float v = row[i] + row2[i]; ss += v * v;
    }
    float tot = block_sum(ss, red);
    float inv = rsqrtf(tot / 512.0f + 1e-6f);
    u16* orow = kfb + (long)s * 576;
    for (int i = threadIdx.x; i < 512; i += 256)
      orow[i] = f2b((row[i] + row2[i]) * inv * kv_ln[i]);
    if (threadIdx.x < 64) {
      int i = threadIdx.x, j = i & 31;
      float c = tab[s * 64 + j], sn = tab[s * 64 + 32 + j];
      float xv = row[512 + i] + row2[512 + i];
      float rv = (i < 32) ? row[512 + i + 32] + row2[512 + i + 32]
                          : row[512 + i - 32] + row2[512 + i - 32];
      float rot = (i < 32) ? -rv : rv;
      orow[512 + i] = f2b(xv * c + rot * sn);
    }
  }
}

// ---------------- fused mid phase: GEMM3 + vallT-GEMM + rope_qpe ------------
// All three depend only on {GEMM2's qb, norm_fused's kfb, prep's weights} and
// write disjoint outputs (qfb[:,:512] per head | vallT | qfb[:,512:576]).
//   blocks [0,1024):    q_full nope = q_nope[h] @ w_uk[h]^T  (dim 4x16x16)
//   blocks [1024,1280): vallT[h] = (ckv_n @ w_uv[h])^T       (dim 1x16x16)
//   blocks [1280,3328): rope_qpe (s = id), block 1280 zeroes ctr[8]
__global__ __launch_bounds__(256) void mid_fused(
    const u16* __restrict__ qb, const u16* __restrict__ wkvbb,
    u16* __restrict__ qfb, const u16* __restrict__ kfb,
    const u16* __restrict__ wuvT, u16* __restrict__ vallT,
    const float* __restrict__ tab, u32* __restrict__ ctr)
{
  __shared__ u16 At[3][4096];
  __shared__ u16 Bt[3][4096];
  int id = blockIdx.x;
  if (id < 1024) {
    gemm_body<1>(qb, wkvbb, qfb, 128, 3072, 4096, 9216, 192, 256, 576,
                 id & 3, (id >> 2) & 15, id >> 6, At, Bt);
    return;
  }
  id -= 1024;
  if (id < 256) {
    gemm_body<2>(kfb, wuvT, vallT, 512, 576, 512, 2048, 0, 65536, 262144,
                 0, id & 15, id >> 4, At, Bt);
    return;
  }
  id -= 256;
  // rope_qpe for s = id
  if (id == 0 && threadIdx.x < 8) ctr[threadIdx.x] = 0;
  const int s = id;
  const int h = threadIdx.x >> 4;
  const int i0 = (threadIdx.x & 15) * 4;
  const u16* src = qb + (long)s * 3072 + h * 192 + 128;
  u16* dst = qfb + (long)s * 9216 + h * 576 + 512;
#pragma unroll
  for (int k = 0; k < 4; ++k) {
    const int i = i0 + k, j = i & 31;
    float c = tab[s * 64 + j], sn = tab[s * 64 + 32 + j];
    float xv = b2f(src[i]);
    float rot = (i < 32) ? -b2f(src[i + 32]) : b2f(src[i - 32]);
    dst[i] = f2b(xv * c + rot * sn);
  }
}

// ---------------- split-K flash attention, XCD-partitioned queue ------------
// 512 persistent blocks (2/CU, all resident). Block b -> group g = b&7
// (XCD-aligned), processes heads {g, g+8} only; V (2x524KB) + K (2.3MB) stay
// L2-resident per XCD. Item = (hh, qt, kc): q-rows [qt*64,+64) of head g+8*hh
// vs K-tiles [4kc, min(4kc+4, ktt)).
// K staging: 9 groups of 64-k per tile, triple-buffered (3 x 16KB), running
// buffer index mod 3 across tiles; ONE vm_barrier<4> per group. LDS 65.5 KiB.
// __launch_bounds__(256,2): 256 regs/wave, ~190-reg demand fits spill-free.
__global__ __launch_bounds__(256, 2) void attn_partial(
    const u16* __restrict__ qfb,   // [2048][16*576]
    const u16* __restrict__ kfb,   // [2048][576]
    const u16* __restrict__ vallT, // [16][128][2048]
    u32* __restrict__ ctr,         // [8]
    u16* __restrict__ pO,          // [1280][64][128]
    float* __restrict__ pS)        // [1280][64][2]
{
  __shared__ u16 Ks[3 * 8192];   // 3 bufs x (2 chunks x [128 rows][32 k])
  __shared__ u16 Ps[4 * 2176];   // per-wave P, 16 rows x 136 stride
  __shared__ u32 cur;

  const int tid = threadIdx.x;
  const int w = tid >> 6, lane = tid & 63;
  const int fr = lane & 15, fq = lane >> 4;
  const float scale = 0.07216878364870323f;  // (DN+DR)^-0.5
  const int grp = (int)(blockIdx.x & 7);     // XCD-aligned head group
  u16* Psw = Ps + w * 2176;

  const int krow0 = (w * 2) * 16 + (lane >> 2);
  const int krow1 = (w * 2 + 1) * 16 + (lane >> 2);
  const int kg0 = (lane & 3) ^ (krow0 & 3);
  const int kg1 = (lane & 3) ^ (krow1 & 3);

  while (true) {
    if (tid == 0) cur = atomicAdd(&ctr[grp], 1u);
    __syncthreads();
    const u32 it = cur;
    if (it >= N_ITEMS_G) break;

    // decode group-local item (qt descending; within qt: kc asc, hh 0..1)
    int rem = (int)it, qt = 31, kc = 0, hh = 0;
    for (int q = 31; q >= 0; --q) {
      int cnt = nkc_of(q) * 2;
      if (rem < cnt) { qt = q; kc = rem >> 1; hh = rem & 1; break; }
      rem -= cnt;
    }
    const int h = grp + hh * 8;
    const u32 gslot = (u32)grp * N_ITEMS_G + it;   // global partial slot
    const int q0 = qt * 64;
    const int ktt = (qt >> 1) + 1;
    const int kt0 = kc * 4, kt1 = min(kt0 + 4, ktt);

    // Q fragments resident (A[m=fr][k=fq*8+j])
    bf16x8 aq[18];
    {
      const u16* qp = qfb + (long)(q0 + w * 16 + fr) * 9216 + h * 576 + fq * 8;
#pragma unroll
      for (int d = 0; d < 18; ++d) aq[d] = *(const bf16x8*)(qp + d * 32);
    }

    float m_run[4], l_run[4];
#pragma unroll
    for (int r = 0; r < 4; ++r) { m_run[r] = -1e30f; l_run[r] = 0.f; }
    f32x4 Oacc[8] = {};
    // per-lane V fragment base: frag(jv,ks) = vlane + k0 + jv*32768 + ks*32
    const u16* vlane = vallT + (long)h * 262144 + (long)fr * 2048 + fq * 8;

    // Stage one 64-k group (2 chunks, 4 GLDS/thread) into buffer gb (0..2).
    auto issueG = [&](int kt, int gk, int gb) {
      const int k0i = kt * 128;
      u16* buf = Ks + gb * 8192;
#pragma unroll
      for (int c = 0; c < 2; ++c) {
        const int d0 = (gk * 2 + c) * 32;
        u16* dst = buf + c * 4096;
        GLDS(kfb + (long)(k0i + krow0) * 576 + d0 + kg0 * 8, dst + (w * 2) * 512);
        GLDS(kfb + (long)(k0i + krow1) * 576 + d0 + kg1 * 8, dst + (w * 2 + 1) * 512);
      }
    };

    issueG(kt0, 0, 0);
    issueG(kt0, 1, 1);

    for (int kt = kt0; kt < kt1; ++kt) {
      const int k0 = kt * 128;
      // group0 of this tile landed block-wide; also WAR-protects buf2.
      vm_barrier<4>();

      f32x4 sc[8] = {};
#pragma unroll
      for (int g = 0; g < 9; ++g) {
        const int gg = g + 2;
        if (gg <= 8) issueG(kt, gg, gg % 3);
        else if (kt + 1 < kt1) issueG(kt + 1, gg - 9, gg % 3);  // 9,10 -> 0,1
        const u16* kb0 = Ks + (g % 3) * 8192;
        __builtin_amdgcn_s_setprio(1);
#pragma unroll
        for (int c = 0; c < 2; ++c) {
          const int d = 2 * g + c;
          const u16* kb = kb0 + c * 4096;
#pragma unroll
          for (int j = 0; j < 8; ++j) {
            const int row = j * 16 + fr;
            bf16x8 b = *(const bf16x8*)(kb + row * 32 + ((fq ^ (row & 3)) * 8));
            sc[j] = MFMA(aq[d], b, sc[j]);
          }
        }
        __builtin_amdgcn_s_setprio(0);
        if (g < 8) vm_barrier<4>();  // next group landed; frees buf[g%3]
      }

      // V ks-group 0 into dual register buffers (L2-resident; latency hidden
      // under softmax). No barrier needed: V loads don't touch LDS.
      const u16* vk = vlane + k0;
      bf16x8 vA[4], vB[4];
#pragma unroll
      for (int q = 0; q < 4; ++q) {
        vA[q] = *(const bf16x8*)(vk + (long)q * 32768);
        vB[q] = *(const bf16x8*)(vk + (long)(q + 4) * 32768);
      }

      // wave-local online softmax
      const bool diag = (kt == ktt - 1);
#pragma unroll
      for (int r = 0; r < 4; ++r) {
        float mx = m_run[r];
#pragma unroll
        for (int j = 0; j < 8; ++j) {
          float s = sc[j][r] * scale;
          if (diag) {
            const int row = q0 + w * 16 + fq * 4 + r;
            const int col = k0 + j * 16 + fr;
            if (col > row) s = -1e30f;
          }
          sc[j][r] = s;
          mx = fmaxf(mx, s);
        }
        mx = fmaxf(mx, __shfl_xor(mx, 1));
        mx = fmaxf(mx, __shfl_xor(mx, 2));
        mx = fmaxf(mx, __shfl_xor(mx, 4));
        mx = fmaxf(mx, __shfl_xor(mx, 8));
        const float alpha = __expf(m_run[r] - mx);
        m_run[r] = mx;
        float sum = 0.f;
#pragma unroll
        for (int j = 0; j < 8; ++j) {
          float p = __expf(sc[j][r] - mx);
          sc[j][r] = p;
          sum += p;
        }
        sum += __shfl_xor(sum, 1);
        sum += __shfl_xor(sum, 2);
        sum += __shfl_xor(sum, 4);
        sum += __shfl_xor(sum, 8);
        l_run[r] = l_run[r] * alpha + sum;
#pragma unroll
        for (int jv = 0; jv < 8; ++jv) Oacc[jv][r] *= alpha;
#pragma unroll
        for (int j = 0; j < 8; ++j)
          Psw[(fq * 4 + r) * 136 + j * 16 + fr] = f2b(sc[j][r]);
      }

      // PV: O += P @ V^T, V fragments ping-ponged from global (no barrier)
#pragma unroll
      for (int ks = 0; ks < 4; ++ks) {
        bf16x8 ap = *(const bf16x8*)(Psw + fr * 136 + ks * 32 + fq * 8);
        __builtin_amdgcn_s_setprio(1);
#pragma unroll
        for (int q = 0; q < 4; ++q) Oacc[q] = MFMA(ap, vA[q], Oacc[q]);
        __builtin_amdgcn_s_setprio(0);
        if (ks < 3) {
#pragma unroll
          for (int q = 0; q < 4; ++q)
            vA[q] = *(const bf16x8*)(vk + (long)q * 32768 + (ks + 1) * 32);
        }
        __builtin_amdgcn_s_setprio(1);
#pragma unroll
        for (int q = 0; q < 4; ++q) Oacc[q + 4] = MFMA(ap, vB[q], Oacc[q + 4]);
        __builtin_amdgcn_s_setprio(0);
        if (ks < 3) {
#pragma unroll
          for (int q = 0; q < 4; ++q)
            vB[q] = *(const bf16x8*)(vk + (long)(q + 4) * 32768 + (ks + 1) * 32);
        }
      }
    }

    // write partial: raw O (bf16) + per-row stats
    const long po = (long)gslot * 8192;
#pragma unroll
    for (int r = 0; r < 4; ++r) {
      const int lr = w * 16 + fq * 4 + r;
      if (fr == 0) {
        pS[((long)gslot * 64 + lr) * 2] = m_run[r];
        pS[((long)gslot * 64 + lr) * 2 + 1] = l_run[r];
      }
#pragma unroll
      for (int jv = 0; jv < 8; ++jv)
        pO[po + (long)lr * 128 + jv * 16 + fr] = f2b(Oacc[jv][r]);
    }
  }
}

// ---------------- combine partials (log-sum-exp weights) ----------------
__global__ __launch_bounds__(256) void attn_reduce(
    const u16* __restrict__ pO, const float* __restrict__ pS,
    u16* __restrict__ ovb)
{
  const int h = blockIdx.x, qt = blockIdx.y;
  const int g = h & 7, hh = h >> 3;
  const int ktt = (qt >> 1) + 1;
  const int nkc = (ktt + 3) >> 2;
  int base = g * N_ITEMS_G;
  for (int q = qt + 1; q < 32; ++q) base += nkc_of(q) * 2;
  const int tid = threadIdx.x;
  const int r = tid >> 2, cq = (tid & 3) * 32;

  float m[4], l[4], wgt[4];
  float M = -1e30f;
  for (int i = 0; i < nkc; ++i) {
    const long slot = base + i * 2 + hh;
    m[i] = pS[(slot * 64 + r) * 2];
    l[i] = pS[(slot * 64 + r) * 2 + 1];
    M = fmaxf(M, m[i]);
  }
  float L = 0.f;
  for (int i = 0; i < nkc; ++i) { wgt[i] = __expf(m[i] - M); L += l[i] * wgt[i]; }
  const float inv = 1.0f / L;

  u16* orow = ovb + (long)(qt * 64 + r) * 2048 + h * 128 + cq;
  for (int c8 = 0; c8 < 32; c8 += 8) {
    float acc[8] = {};
    for (int i = 0; i < nkc; ++i) {
      const long slot = base + i * 2 + hh;
      const u16x8 v = *(const u16x8*)(pO + (slot * 64 + r) * 128 + cq + c8);
#pragma unroll
      for (int e = 0; e < 8; ++e) acc[e] += b2f(v[e]) * wgt[i];
    }
    u16x8 o;
#pragma unroll
    for (int e = 0; e < 8; ++e) o[e] = f2b(acc[e] * inv);
    *(u16x8*)(orow + c8) = o;
  }
}

extern "C" void kernel_launch(void* const* d_in, const int* in_sizes, int n_in,
                              void* d_out, int out_size, void* d_ws, size_t ws_size,
                              hipStream_t stream) {
  const float* x      = (const float*)d_in[0];
  const float* w_q_a  = (const float*)d_in[1];
  const float* q_ln   = (const float*)d_in[2];
  const float* w_q_b  = (const float*)d_in[3];
  const float* w_kv_a = (const float*)d_in[4];
  const float* kv_ln  = (const float*)d_in[5];
  const float* w_kv_b = (const float*)d_in[6];
  const float* w_o    = (const float*)d_in[7];
  float* out = (float*)d_out;

  // ---- fixed workspace (bytes) ----
  char* p = (char*)d_ws;
  float* tab   = (float*)p;  p += 524288;      // 2048*64 f32
  u16* wkvbb   = (u16*)p;    p += 4194304;     // 512*4096
  u16* wuvT    = (u16*)p;    p += 2097152;     // 16*128*512
  u16* woT     = (u16*)p;    p += 8388608;     // 2048*2048
  u16* qfb     = (u16*)p;    p += 37748736;    // 2048*9216
  u16* vallT   = (u16*)p;    p += 8388608;     // 16*128*2048
  u16* kfb     = (u16*)p;    p += 2359296;     // 2048*576
  u16* ovb     = (u16*)p;    p += 8388608;     // 2048*2048
  char* tb = p;
  // phase 1 transient (63.44 MB):
  u16* xb      = (u16*)tb;                     // 2048*2048            (8.39 MB)
  u16* wabT    = (u16*)(tb + 8388608);         // 2176*2048 (qa++kva transposed)
  float* qac   = (float*)(tb + 17301504);      // 2048*2176 f32 (qa | ckv_kpe)
  u16* qab     = (u16*)(tb + 35127296);        // 2048*1536
  u16* wqbT    = (u16*)(tb + 41418752);        // 3072*1536
  u16* qb      = (u16*)(tb + 50855936);        // 2048*3072  (ends 63,438,848)
  // GEMM1 split-K partial lives in the qfb region (17.8 MB <= 37.7 MB):
  // qfb is dead until mid_fused (GEMM3 + rope write it), which runs after
  // norm_fused has consumed the partial. Always-on split, no ws_size gate.
  float* qacB  = (float*)qfb;
  // phase 2 transient (aliases phase 1, used only after it is dead):
  u16* pO      = (u16*)tb;                     // 1280*64*128 bf16 (21 MB)
  float* pS    = (float*)(tb + 20971520);      // 1280*64*2 f32
  u32* ctr     = (u32*)(tb + 21626880);        // 8 group counters
  // phase 3 transient (after attn_reduce; pO/pS/ctr dead):
  float* outP  = (float*)tb;                   // 2 x 2048*2048 f32 (33.5 MB)

  // fused prep: rope table + casts + transposes (one launch, 20352 blocks)
  prep_all<<<dim3(20352), 256, 0, stream>>>(
      x, w_q_a, w_kv_a, w_q_b, w_kv_b, w_o,
      tab, xb, wkvbb, wabT, wqbT, wuvT, woT);

  // fused: [q_a | ckv_kpe] = x @ [w_q_a | w_kv_a]  (f32, ldc 2176)
  // split-K=2 (544 blocks ~ 2/CU); norm_fused sums the two partial streams.
  gemm_mfma<0><<<dim3(17, 16, 2), 256, 0, stream>>>(
      xb, wabT, qac, 1024, 2048, 2048, 2176, 1024, 1024, (long)(qacB - qac));

  // fused rmsnorm(q_a) -> qab  +  build_kfull -> kfb (one launch)
  norm_fused<<<dim3(4096), 256, 0, stream>>>(
      qac, q_ln, qab, kv_ln, tab, kfb, qacB);

  // q = q_a @ w_q_b (bf16 out; 384 blocks = 1.5/CU)
  gemm_mfma<1><<<dim3(24, 16), 256, 0, stream>>>(
      qab, wqbT, qb, 1536, 1536, 1536, 3072, 0, 0, 0);

  // fused mid phase: GEMM3 (q_nope @ w_uk^T -> qfb) + vallT GEMM + rope_qpe
  // (+ ctr zero) — independent ops, one 3328-block launch.
  mid_fused<<<dim3(3328), 256, 0, stream>>>(
      qb, wkvbb, qfb, kfb, wuvT, vallT, tab, ctr);

  // split-K flash attention, XCD-partitioned dynamic queues (512 = 2/CU)
  attn_partial<<<dim3(512), 256, 0, stream>>>(qfb, kfb, vallT, ctr, pO, pS);
  attn_reduce<<<dim3(16, 32), 256, 0, stream>>>(pO, pS, ovb);

  // y = o_v @ w_o: split-K=2 (512 blocks = 2/CU) into fp32 partials + add
  gemm_mfma<0><<<dim3(16, 16, 2), 256, 0, stream>>>(
      ovb, woT, outP, 1024, 2048, 2048, 2048, 1024, 1024, 4194304);
  add_f32<<<4096, 256, 0, stream>>>(outP, outP + 4194304, out, 4194304);
}